// Round 7
// baseline (789.786 us; speedup 1.0000x reference)
//
#include <hip/hip_runtime.h>
#include <float.h>

// Problem constants: B=2, N=4096, K=20, H=384
// Inputs: fp32 arrays (values bf16-quantized by harness). Output: fp32.
#define NPTS_B 4096
#define NPTS 8192            // B*N
#define KNN 20
#define NSAMP (NPTS*KNN)     // 163840

typedef __attribute__((ext_vector_type(8))) short bf16x8;
typedef __attribute__((ext_vector_type(4))) float f32x4;

// -------- bf16 helpers (internal staging only) --------
static __device__ __forceinline__ float bf2f(unsigned short u) {
  return __uint_as_float(((unsigned int)u) << 16);
}
static __device__ __forceinline__ unsigned short f2bf(float f) {
  unsigned int u = __float_as_uint(f);
  u += 0x7fffu + ((u >> 16) & 1u);
  return (unsigned short)(u >> 16);
}
static __device__ __forceinline__ unsigned long long u64min(unsigned long long a,
                                                           unsigned long long b) {
  return a < b ? a : b;
}
static __device__ __forceinline__ unsigned long long shflx64(unsigned long long v, int m) {
  int lo = __shfl_xor((int)(unsigned int)(v & 0xffffffffull), m);
  int hi = __shfl_xor((int)(unsigned int)(v >> 32), m);
  return ((unsigned long long)(unsigned int)hi << 32) | (unsigned int)lo;
}

// ============================================================
// K0: weight prep — W3 -> W3T bf16 [n][k]; W4 -> W4T bf16 [n][k];
// W2 (128x256) -> W2T bf16 [n=256][k=128]. All values bf16-grid -> EXACT.
// ============================================================
__global__ __launch_bounds__(256) void wprep_kernel(const float* __restrict__ W3,
                                                    const float* __restrict__ W4,
                                                    const float* __restrict__ W2,
                                                    unsigned short* __restrict__ W3T,
                                                    unsigned short* __restrict__ W4T,
                                                    unsigned short* __restrict__ W2T) {
  int id = blockIdx.x * 256 + threadIdx.x;
  if (id < 512*512) {
    int n = id >> 9, k = id & 511;
    W3T[id] = f2bf(W3[k*512 + n]);
  } else if (id < 512*512 + 384*512) {
    int id2 = id - 512*512;
    int n = id2 >> 9, k = id2 & 511;
    W4T[id2] = f2bf(W4[k*384 + n]);
  } else {
    int id2 = id - (512*512 + 384*512);   // < 256*128
    int n = id2 >> 7, k = id2 & 127;
    W2T[id2] = f2bf(W2[k*256 + n]);
  }
}

// ============================================================
// K1: KNN (one block per point). u64-packed (d2_bits<<32|j) extract-min,
// incremental cached minima, one barrier per round.
// ============================================================
__global__ __launch_bounds__(256) void knn_kernel(const float* __restrict__ xyz,
                                                  int* __restrict__ idx,
                                                  float* __restrict__ out_xyz) {
#pragma clang fp contract(off)
  int p = blockIdx.x;            // 0..8191
  int base = p & ~4095;          // batch base row
  int tid = threadIdx.x;
  int wv = tid >> 6;
  int ln = tid & 63;
  const float* xb = xyz + (size_t)base * 3;
  float xi0 = xyz[p*3+0], xi1 = xyz[p*3+1], xi2 = xyz[p*3+2];
  float sqi = (xi0*xi0 + xi1*xi1) + xi2*xi2;

  unsigned long long cand[16];
#pragma unroll
  for (int u = 0; u < 16; ++u) {
    int j = tid + (u << 8);
    float a0 = xb[j*3+0], a1 = xb[j*3+1], a2 = xb[j*3+2];
    float sqj = (a0*a0 + a1*a1) + a2*a2;
    float dt  = (xi0*a0 + xi1*a1) + xi2*a2;
    float d2  = (sqi + sqj) - 2.0f*dt;
    cand[u] = ((unsigned long long)__float_as_uint(d2) << 32) | (unsigned int)j;
  }
  unsigned long long myloc;
  {
    unsigned long long t[8];
#pragma unroll
    for (int u = 0; u < 8; ++u) t[u] = u64min(cand[u], cand[u + 8]);
#pragma unroll
    for (int u = 0; u < 4; ++u) t[u] = u64min(t[u], t[u + 4]);
    t[0] = u64min(t[0], t[2]); t[1] = u64min(t[1], t[3]);
    myloc = u64min(t[0], t[1]);
  }
  unsigned long long wmreg = myloc;
#pragma unroll
  for (int off = 1; off < 64; off <<= 1) wmreg = u64min(wmreg, shflx64(wmreg, off));

  __shared__ __align__(16) unsigned long long wbuf[2][4];
  __shared__ int outbuf[20];
  if (ln == 0) wbuf[0][wv] = wmreg;
  __syncthreads();

  for (int r = 0; r < 20; ++r) {
    int cur = r & 1;
    unsigned long long w0 = wbuf[cur][0], w1 = wbuf[cur][1];
    unsigned long long w2 = wbuf[cur][2], w3 = wbuf[cur][3];
    unsigned long long g = u64min(u64min(w0, w1), u64min(w2, w3));
    int wj = (int)(unsigned int)(g & 0xffffffffu);
    if (tid == (wj & 255)) {
      outbuf[r] = base + wj;
      unsigned long long m = ~0ull;
#pragma unroll
      for (int u = 0; u < 16; ++u) {
        if (cand[u] == g) cand[u] = ~0ull;
        m = u64min(m, cand[u]);
      }
      myloc = m;
    }
    if (wv == ((wj >> 6) & 3)) {
      unsigned long long t = myloc;
#pragma unroll
      for (int off = 1; off < 64; off <<= 1) t = u64min(t, shflx64(t, off));
      wmreg = t;
    }
    if (ln == 0) wbuf[cur ^ 1][wv] = wmreg;
    __syncthreads();
  }
  if (tid < 20) idx[p*20 + tid] = outbuf[tid];
  if (tid < 3) out_xyz[p*3 + tid] = xyz[p*3 + tid];   // exact fp32 copy
}

// ============================================================
// K2: BN1 stats via 6-dim edge moments. h1 = e@W1 + b1 is affine in e, so
//   mean_c = b1[c] + w_c.S/N,  var_c = (w_c.M.w_c)/N - (w_c.S/N)^2
// with S = sum(e), M = sum(e e^T) (21 upper-tri). 33 accumulators/thread,
// wave butterfly, 16 bucketed atomics.
// ============================================================
__global__ __launch_bounds__(256) void h1_moments_kernel(const float* __restrict__ xyz,
                                                         const int* __restrict__ idx,
                                                         float* __restrict__ mbuck) {
  int tid = threadIdx.x, blk = blockIdx.x;   // 320 blocks x 512 samples
  float A[33] = {};
#pragma unroll
  for (int u = 0; u < 2; ++u) {
    int s = blk*512 + (u << 8) + tid;
    unsigned int p = (unsigned int)s / 20u;
    int jg = idx[s];
    float c0 = xyz[p*3+0], c1 = xyz[p*3+1], c2 = xyz[p*3+2];
    float e[6];
    e[0] = xyz[jg*3+0] - c0; e[1] = xyz[jg*3+1] - c1; e[2] = xyz[jg*3+2] - c2;
    e[3] = c0; e[4] = c1; e[5] = c2;
    int k = 6;
#pragma unroll
    for (int d = 0; d < 6; ++d) {
      A[d] += e[d];
#pragma unroll
      for (int d2 = d; d2 < 6; ++d2) { A[k] = fmaf(e[d], e[d2], A[k]); ++k; }
    }
  }
#pragma unroll
  for (int off = 1; off < 64; off <<= 1) {
#pragma unroll
    for (int i = 0; i < 33; ++i) A[i] += __shfl_xor(A[i], off);
  }
  if ((tid & 63) == 0) {
    int b = ((blk << 2) | (tid >> 6)) & 15;
    for (int i = 0; i < 33; ++i) atomicAdd(&mbuck[b*64 + i], A[i]);
  }
}

__global__ void bn_prep1(const float* __restrict__ W1, const float* __restrict__ b1,
                         const float* __restrict__ g1, const float* __restrict__ be1,
                         const float* __restrict__ mbuck, float* __restrict__ misc) {
  __shared__ float red[33];
  int tid = threadIdx.x;  // 128
  if (tid < 33) {
    float s = 0.f;
    for (int b = 0; b < 16; ++b) s += mbuck[b*64 + tid];
    red[tid] = s;
  }
  __syncthreads();
  int c = tid;
  float w[6];
#pragma unroll
  for (int d = 0; d < 6; ++d) w[d] = W1[d*128 + c];
  const float inv = 1.0f / (float)NSAMP;
  float t = 0.f;
#pragma unroll
  for (int d = 0; d < 6; ++d) t = fmaf(w[d], red[d], t);
  t *= inv;
  float Q = 0.f;
  int k = 6;
#pragma unroll
  for (int d = 0; d < 6; ++d) {
#pragma unroll
    for (int d2 = d; d2 < 6; ++d2) {
      float coef = (d == d2) ? w[d]*w[d] : 2.f*w[d]*w[d2];
      Q = fmaf(coef, red[k], Q); ++k;
    }
  }
  Q *= inv;
  float var = Q - t*t;
  float mu = b1[c] + t;
  float a = g1[c] / sqrtf(var + 1e-5f);
  misc[c] = a;
  misc[128 + c] = be1[c] - mu*a;
}

// ============================================================
// K4: MFMA h2: per block of 4 points (M=80): edge -> h1 (BN1+ReLU, bf16
// into LDS A-tile) -> h2 = h1 @ W2T via MFMA (N=256, K=128) -> +b2 ->
// h2 bf16 store + fused per-point gmax.
// ============================================================
__global__ __launch_bounds__(256) void h2_kernel(const float* __restrict__ xyz,
                                                 const int* __restrict__ idx,
                                                 const float* __restrict__ W1,
                                                 const float* __restrict__ b1,
                                                 const unsigned short* __restrict__ W2T,
                                                 const float* __restrict__ b2,
                                                 const float* __restrict__ misc,
                                                 unsigned short* __restrict__ h2out,
                                                 unsigned short* __restrict__ gmaxout) {
  int p0 = blockIdx.x << 2;          // 4 points
  int tid = threadIdx.x;
  int w = tid >> 6, lane = tid & 63;
  int lr = lane & 15, lg = lane >> 4;
  __shared__ float e[80][6];
  __shared__ __align__(16) unsigned short As[80][136];
  __shared__ float pool[20][264];

  bf16x8 bfr[4][4];
#pragma unroll
  for (int j = 0; j < 4; ++j)
#pragma unroll
    for (int kk = 0; kk < 4; ++kk)
      bfr[j][kk] = *(const bf16x8*)(W2T + (size_t)(w*64 + j*16 + lr)*128 + kk*32 + lg*8);

  if (tid < 80) {
    int pl = (unsigned int)tid / 20u;
    int p = p0 + pl;
    int jg = idx[p0*20 + tid];
    float xi0 = xyz[p*3+0], xi1 = xyz[p*3+1], xi2 = xyz[p*3+2];
    e[tid][0] = xyz[jg*3+0] - xi0;
    e[tid][1] = xyz[jg*3+1] - xi1;
    e[tid][2] = xyz[jg*3+2] - xi2;
    e[tid][3] = xi0; e[tid][4] = xi1; e[tid][5] = xi2;
  }
  __syncthreads();

  {
    int c = tid & 127, half = tid >> 7;
    float w1v[6];
#pragma unroll
    for (int d = 0; d < 6; ++d) w1v[d] = W1[d*128 + c];
    float b1v = b1[c], a1 = misc[c], d1 = misc[128 + c];
#pragma unroll
    for (int u = 0; u < 40; ++u) {
      int row = (u << 1) | half;
      float v = b1v;
#pragma unroll
      for (int d = 0; d < 6; ++d) v = fmaf(e[row][d], w1v[d], v);
      v = fmaxf(fmaf(a1, v, d1), 0.f);
      As[row][c] = f2bf(v);
    }
  }
  __syncthreads();

  f32x4 acc[5][4] = {};
#pragma unroll
  for (int kk = 0; kk < 4; ++kk) {
    bf16x8 a[5];
#pragma unroll
    for (int i = 0; i < 5; ++i)
      a[i] = *(const bf16x8*)&As[i*16 + lr][kk*32 + lg*8];
#pragma unroll
    for (int i = 0; i < 5; ++i)
#pragma unroll
      for (int j = 0; j < 4; ++j)
        acc[i][j] = __builtin_amdgcn_mfma_f32_16x16x32_bf16(a[i], bfr[j][kk], acc[i][j], 0, 0, 0);
  }

  float b2v[4];
#pragma unroll
  for (int j = 0; j < 4; ++j) b2v[j] = b2[w*64 + j*16 + lr];
#pragma unroll
  for (int i = 0; i < 5; ++i) {
    int rbase = p0*20 + i*16 + lg*4;
#pragma unroll
    for (int j = 0; j < 4; ++j) {
      int col = w*64 + j*16 + lr;
      float v0 = acc[i][j][0] + b2v[j];
      float v1 = acc[i][j][1] + b2v[j];
      float v2 = acc[i][j][2] + b2v[j];
      float v3 = acc[i][j][3] + b2v[j];
      h2out[(size_t)(rbase+0)*256 + col] = f2bf(v0);
      h2out[(size_t)(rbase+1)*256 + col] = f2bf(v1);
      h2out[(size_t)(rbase+2)*256 + col] = f2bf(v2);
      h2out[(size_t)(rbase+3)*256 + col] = f2bf(v3);
      pool[i*4 + lg][col] = fmaxf(fmaxf(v0, v1), fmaxf(v2, v3));
    }
  }
  __syncthreads();
#pragma unroll
  for (int l = 0; l < 4; ++l) {
    int id = tid + (l << 8);        // 0..1023 : 4 points x 256 cols
    int q = id >> 8, col = id & 255;
    float v = pool[q*5][col];
#pragma unroll
    for (int u = 1; u < 5; ++u) v = fmaxf(v, pool[q*5 + u][col]);
    gmaxout[(size_t)(p0 + q)*256 + col] = f2bf(v);
  }
}

// ============================================================
// K5: MFMA GEMM: h3 = [gmax | h2] @ W3 + b3 (163840x512x512), bf16 MFMA.
// 128M x 128N tile, reg-prefetch pipeline, XCD sibling swizzle (the 4
// N-blocks of an M-tile sit 8 apart in blockIdx -> same XCD L2).
// ============================================================
__global__ __launch_bounds__(256) void gemm3_kernel(const unsigned short* __restrict__ h2,
                                                    const unsigned short* __restrict__ gmax,
                                                    const unsigned short* __restrict__ W3T,
                                                    const float* __restrict__ b3,
                                                    unsigned short* __restrict__ h3,
                                                    float* __restrict__ s3buck) {
  int bid = blockIdx.x;               // 5120 = 160 grp * (4 bn * 8 x)
  int grp = bid >> 5, rem = bid & 31;
  int bn = rem >> 3;
  int bm = (grp << 3) | (rem & 7);
  int m0 = bm << 7, n0 = bn << 7;
  int tid = threadIdx.x;
  int lane = tid & 63, w = tid >> 6;
  int mw = w >> 1, nw = w & 1;
  int lr = lane & 15, lg = lane >> 4;
  __shared__ __align__(16) unsigned short As[128][32];
  __shared__ __align__(16) unsigned short Bs[128][32];
  __shared__ float ssum[128], ssq[128];
  f32x4 acc[4][4] = {};

  uint4 aR[2], bR[2];
  // prologue: kc = 0 (A from gmax)
#pragma unroll
  for (int l = 0; l < 2; ++l) {
    int id = tid + (l << 8); int row = id >> 2, kg = id & 3;
    unsigned int pp = (unsigned int)(m0 + row) / 20u;
    aR[l] = *(const uint4*)(gmax + (size_t)pp*256 + (kg << 3));
    bR[l] = *(const uint4*)(W3T + (size_t)(n0 + row)*512 + (kg << 3));
  }

  for (int kc = 0; kc < 512; kc += 32) {
#pragma unroll
    for (int l = 0; l < 2; ++l) {
      int id = tid + (l << 8); int row = id >> 2, kg = id & 3;
      *(uint4*)&As[row][kg << 3] = aR[l];
      *(uint4*)&Bs[row][kg << 3] = bR[l];
    }
    __syncthreads();
    int kn = kc + 32;
    if (kn < 512) {
#pragma unroll
      for (int l = 0; l < 2; ++l) {
        int id = tid + (l << 8); int row = id >> 2, kg = id & 3;
        int grow = m0 + row;
        if (kn < 256) {
          unsigned int pp = (unsigned int)grow / 20u;
          aR[l] = *(const uint4*)(gmax + (size_t)pp*256 + kn + (kg << 3));
        } else {
          aR[l] = *(const uint4*)(h2 + (size_t)grow*256 + (kn - 256) + (kg << 3));
        }
        bR[l] = *(const uint4*)(W3T + (size_t)(n0 + row)*512 + kn + (kg << 3));
      }
    }
    bf16x8 a[4], b[4];
#pragma unroll
    for (int t = 0; t < 4; ++t)
      a[t] = *(const bf16x8*)&As[mw*64 + t*16 + lr][lg << 3];
#pragma unroll
    for (int t = 0; t < 4; ++t)
      b[t] = *(const bf16x8*)&Bs[nw*64 + t*16 + lr][lg << 3];
#pragma unroll
    for (int i = 0; i < 4; ++i)
#pragma unroll
      for (int j = 0; j < 4; ++j)
        acc[i][j] = __builtin_amdgcn_mfma_f32_16x16x32_bf16(a[i], b[j], acc[i][j], 0, 0, 0);
    __syncthreads();
  }

  // epilogue: +b3, bf16 store, fused BN3 stats
  if (tid < 128) { ssum[tid] = 0.f; ssq[tid] = 0.f; }
  __syncthreads();
#pragma unroll
  for (int j = 0; j < 4; ++j) {
    int colL = nw*64 + j*16 + lr;
    int col = n0 + colL;
    float b3v = b3[col];
    float sumv = 0.f, sqv = 0.f;
#pragma unroll
    for (int i = 0; i < 4; ++i) {
      int rbase = m0 + mw*64 + i*16 + lg*4;
#pragma unroll
      for (int r = 0; r < 4; ++r) {
        float v = acc[i][j][r] + b3v;
        h3[(size_t)(rbase + r)*512 + col] = f2bf(v);
        sumv += v; sqv = fmaf(v, v, sqv);
      }
    }
    sumv += __shfl_xor(sumv, 16); sumv += __shfl_xor(sumv, 32);
    sqv  += __shfl_xor(sqv, 16);  sqv  += __shfl_xor(sqv, 32);
    if (lg == 0) {
      atomicAdd(&ssum[colL], sumv);
      atomicAdd(&ssq[colL], sqv);
    }
  }
  __syncthreads();
  if (tid < 128) {
    int bkt = (bid & 63) * 1024;
    atomicAdd(&s3buck[bkt + n0 + tid], ssum[tid]);
    atomicAdd(&s3buck[bkt + 512 + n0 + tid], ssq[tid]);
  }
}

__global__ void bn_prep3(const float* __restrict__ g3, const float* __restrict__ be3,
                         const float* __restrict__ s3buck, float* __restrict__ misc) {
  int c = threadIdx.x;  // 512
  float s = 0.f, q = 0.f;
  for (int b = 0; b < 64; ++b) { s += s3buck[b*1024 + c]; q += s3buck[b*1024 + 512 + c]; }
  const float inv = 1.0f / (float)NSAMP;
  float mu = s * inv;
  float var = q * inv - mu * mu;
  float a = g3[c] / sqrtf(var + 1e-5f);
  misc[256 + c] = a;
  misc[768 + c] = be3[c] - mu * a;
}

// ============================================================
// K7: MFMA GEMM: h4 = relu(a3*h3+d3) @ W4 (+b4), fused max-pool over K=20.
// M=160 (8 points) x N=128. Reg-prefetch pipeline; pool LDS aliases the
// staging buffers (dead after k-loop) -> 24.9 KB LDS; XCD sibling swizzle
// (3 N-blocks of an M-tile 8 apart in blockIdx -> same XCD L2).
// ============================================================
__global__ __launch_bounds__(256) void gemm4_kernel(const unsigned short* __restrict__ h3,
                                                    const unsigned short* __restrict__ W4T,
                                                    const float* __restrict__ b4,
                                                    const float* __restrict__ misc,
                                                    float* __restrict__ outf) {
  int bid = blockIdx.x;             // 3072 = 128 grp * (3 bn * 8 x)
  int grp = bid / 24, rem = bid - grp*24;
  int bn = rem >> 3;
  int bm = (grp << 3) | (rem & 7);
  int m0 = bm * 160, n0 = bn << 7;
  int tid = threadIdx.x;
  int lane = tid & 63, w = tid >> 6;
  int mw = w >> 1, nw = w & 1;
  int lr = lane & 15, lg = lane >> 4;
  __shared__ __align__(16) char smem[24896];
  unsigned short (*As)[32] = (unsigned short (*)[32])smem;           // 10240 B
  unsigned short (*Bs)[32] = (unsigned short (*)[32])(smem + 10240); // 8192 B
  float (*pool)[130] = (float (*)[130])smem;                         // 20800 B (aliases As,Bs)
  float* af = (float*)(smem + 20800);
  float* df = af + 512;
#pragma unroll
  for (int l = 0; l < 2; ++l) {
    int id = tid + (l << 8);
    af[id] = misc[256 + id];
    df[id] = misc[768 + id];
  }
  __syncthreads();
  f32x4 acc[5][4] = {};

  uint4 aR[3], bR[2];
  // prologue: kc = 0
#pragma unroll
  for (int l = 0; l < 3; ++l) {
    int id = tid + (l << 8);
    if (id < 640) { int row = id >> 2, kg = id & 3;
      aR[l] = *(const uint4*)(h3 + (size_t)(m0 + row)*512 + (kg << 3)); }
  }
#pragma unroll
  for (int l = 0; l < 2; ++l) {
    int id = tid + (l << 8); int row = id >> 2, kg = id & 3;
    bR[l] = *(const uint4*)(W4T + (size_t)(n0 + row)*512 + (kg << 3));
  }

  for (int kc = 0; kc < 512; kc += 32) {
    // stage: A with BN3 affine + relu, B raw
#pragma unroll
    for (int l = 0; l < 3; ++l) {
      int id = tid + (l << 8);
      if (id < 640) {
        int row = id >> 2, kg = id & 3;
        int kb = kc + (kg << 3);
        unsigned int o[4];
#pragma unroll
        for (int q = 0; q < 4; ++q) {
          unsigned int u = ((const unsigned int*)&aR[l])[q];
          float lo = bf2f((unsigned short)(u & 0xffffu));
          float hi = bf2f((unsigned short)(u >> 16));
          int k0 = kb + q*2;
          lo = fmaxf(fmaf(af[k0],   lo, df[k0]),   0.f);
          hi = fmaxf(fmaf(af[k0+1], hi, df[k0+1]), 0.f);
          o[q] = (unsigned int)f2bf(lo) | ((unsigned int)f2bf(hi) << 16);
        }
        *(uint4*)&As[row][kg << 3] = *(const uint4*)o;
      }
    }
#pragma unroll
    for (int l = 0; l < 2; ++l) {
      int id = tid + (l << 8); int row = id >> 2, kg = id & 3;
      *(uint4*)&Bs[row][kg << 3] = bR[l];
    }
    __syncthreads();
    int kn = kc + 32;
    if (kn < 512) {
#pragma unroll
      for (int l = 0; l < 3; ++l) {
        int id = tid + (l << 8);
        if (id < 640) { int row = id >> 2, kg = id & 3;
          aR[l] = *(const uint4*)(h3 + (size_t)(m0 + row)*512 + kn + (kg << 3)); }
      }
#pragma unroll
      for (int l = 0; l < 2; ++l) {
        int id = tid + (l << 8); int row = id >> 2, kg = id & 3;
        bR[l] = *(const uint4*)(W4T + (size_t)(n0 + row)*512 + kn + (kg << 3));
      }
    }
    bf16x8 a[5], b[4];
#pragma unroll
    for (int t = 0; t < 5; ++t)
      a[t] = *(const bf16x8*)&As[mw*80 + t*16 + lr][lg << 3];
#pragma unroll
    for (int t = 0; t < 4; ++t)
      b[t] = *(const bf16x8*)&Bs[nw*64 + t*16 + lr][lg << 3];
#pragma unroll
    for (int i = 0; i < 5; ++i)
#pragma unroll
      for (int j = 0; j < 4; ++j)
        acc[i][j] = __builtin_amdgcn_mfma_f32_16x16x32_bf16(a[i], b[j], acc[i][j], 0, 0, 0);
    __syncthreads();
  }

  // fused max-pool (pool aliases staging; all ds_reads drained by barrier)
#pragma unroll
  for (int i = 0; i < 5; ++i)
#pragma unroll
    for (int j = 0; j < 4; ++j) {
      float m = fmaxf(fmaxf(acc[i][j][0], acc[i][j][1]),
                      fmaxf(acc[i][j][2], acc[i][j][3]));
      pool[mw*20 + i*4 + lg][nw*64 + j*16 + lr] = m;
    }
  __syncthreads();
#pragma unroll
  for (int l = 0; l < 4; ++l) {
    int id = tid + (l << 8);          // 0..1023 : 8 points x 128 cols
    int q = id >> 7, c = id & 127;
    int mwq = q >> 2, ql = q & 3;
    float v = pool[mwq*20 + ql*5][c];
#pragma unroll
    for (int u = 1; u < 5; ++u) v = fmaxf(v, pool[mwq*20 + ql*5 + u][c]);
    outf[(size_t)(bm*8 + q)*384 + n0 + c] = v + b4[n0 + c];
  }
}

// ============================================================
// Workspace layout:
//   0x0000000  idx        640 KB
//   0x00A0000  misc       1280 f32
//   0x00A2000  mbuck      16*64 f32 = 4 KB (zeroed)
//   0x00AA000  s3buck     256 KB  (zeroed)
//   0x00F0000  W3T bf16   512 KB
//   0x0170000  W4T bf16   384 KB
//   0x01D0000  W2T bf16   64 KB
//   0x0200000  gmax bf16  4 MB
//   0x0600000  h2   bf16  80 MB
//   0x5600000  h3   bf16  160 MB  -> end 0xF600000
// ============================================================
extern "C" void kernel_launch(void* const* d_in, const int* in_sizes, int n_in,
                              void* d_out, int out_size, void* d_ws, size_t ws_size,
                              hipStream_t stream) {
  const float* xyz = (const float*)d_in[0];
  const float* W1  = (const float*)d_in[1];
  const float* b1  = (const float*)d_in[2];
  const float* g1  = (const float*)d_in[3];
  const float* be1 = (const float*)d_in[4];
  const float* W2  = (const float*)d_in[5];
  const float* b2  = (const float*)d_in[6];
  const float* W3  = (const float*)d_in[7];
  const float* b3  = (const float*)d_in[8];
  const float* g3  = (const float*)d_in[9];
  const float* be3 = (const float*)d_in[10];
  const float* W4  = (const float*)d_in[11];
  const float* b4  = (const float*)d_in[12];

  char* ws = (char*)d_ws;
  int*            idx    = (int*)ws;
  float*          misc   = (float*)(ws + 0xA0000);
  float*          mbuck  = (float*)(ws + 0xA2000);
  float*          s3buck = (float*)(ws + 0xAA000);
  unsigned short* W3T    = (unsigned short*)(ws + 0xF0000);
  unsigned short* W4T    = (unsigned short*)(ws + 0x170000);
  unsigned short* W2T    = (unsigned short*)(ws + 0x1D0000);
  unsigned short* gmax   = (unsigned short*)(ws + 0x200000);
  unsigned short* h2     = (unsigned short*)(ws + 0x600000);
  unsigned short* h3     = (unsigned short*)(ws + 0x5600000ULL);

  float* ofp   = (float*)d_out;
  float* oxyz  = ofp;             // 24576 fp32
  float* ofeat = ofp + 24576;     // 8192*384 fp32

  hipMemsetAsync(ws + 0xA2000, 0, 0x48000, stream);   // zero mbuck + s3buck

  wprep_kernel<<<(512*512 + 384*512 + 256*128)/256, 256, 0, stream>>>(W3, W4, W2, W3T, W4T, W2T);
  knn_kernel<<<NPTS, 256, 0, stream>>>(xyz, idx, oxyz);
  h1_moments_kernel<<<NSAMP/512, 256, 0, stream>>>(xyz, idx, mbuck);
  bn_prep1<<<1, 128, 0, stream>>>(W1, b1, g1, be1, mbuck, misc);
  h2_kernel<<<NPTS/4, 256, 0, stream>>>(xyz, idx, W1, b1, W2T, b2, misc, h2, gmax);
  gemm3_kernel<<<(NSAMP/128)*4, 256, 0, stream>>>(h2, gmax, W3T, b3, h3, s3buck);
  bn_prep3<<<1, 512, 0, stream>>>(g3, be3, s3buck, misc);
  gemm4_kernel<<<(NPTS/8)*3, 256, 0, stream>>>(h3, W4T, b4, misc, ofeat);
}

// Round 8
// 560.679 us; speedup vs baseline: 1.4086x; 1.4086x over previous
//
#include <hip/hip_runtime.h>
#include <float.h>

// Problem constants: B=2, N=4096, K=20, H=384
// Inputs: fp32 arrays (values bf16-quantized by harness). Output: fp32.
#define NPTS_B 4096
#define NPTS 8192            // B*N
#define KNN 20
#define NSAMP (NPTS*KNN)     // 163840

typedef __attribute__((ext_vector_type(8))) short bf16x8;
typedef __attribute__((ext_vector_type(4))) float f32x4;

// -------- bf16 helpers (internal staging only) --------
static __device__ __forceinline__ float bf2f(unsigned short u) {
  return __uint_as_float(((unsigned int)u) << 16);
}
static __device__ __forceinline__ unsigned short f2bf(float f) {
  unsigned int u = __float_as_uint(f);
  u += 0x7fffu + ((u >> 16) & 1u);
  return (unsigned short)(u >> 16);
}
static __device__ __forceinline__ unsigned long long u64min(unsigned long long a,
                                                           unsigned long long b) {
  return a < b ? a : b;
}
static __device__ __forceinline__ unsigned long long shflx64(unsigned long long v, int m) {
  int lo = __shfl_xor((int)(unsigned int)(v & 0xffffffffull), m);
  int hi = __shfl_xor((int)(unsigned int)(v >> 32), m);
  return ((unsigned long long)(unsigned int)hi << 32) | (unsigned int)lo;
}

// ============================================================
// K0: weight prep — W3 -> W3T bf16 [n][k]; W4 -> W4T bf16 [n][k];
// W2 (128x256) -> W2T bf16 [n=256][k=128]. All values bf16-grid -> EXACT.
// ============================================================
__global__ __launch_bounds__(256) void wprep_kernel(const float* __restrict__ W3,
                                                    const float* __restrict__ W4,
                                                    const float* __restrict__ W2,
                                                    unsigned short* __restrict__ W3T,
                                                    unsigned short* __restrict__ W4T,
                                                    unsigned short* __restrict__ W2T) {
  int id = blockIdx.x * 256 + threadIdx.x;
  if (id < 512*512) {
    int n = id >> 9, k = id & 511;
    W3T[id] = f2bf(W3[k*512 + n]);
  } else if (id < 512*512 + 384*512) {
    int id2 = id - 512*512;
    int n = id2 >> 9, k = id2 & 511;
    W4T[id2] = f2bf(W4[k*384 + n]);
  } else {
    int id2 = id - (512*512 + 384*512);   // < 256*128
    int n = id2 >> 7, k = id2 & 127;
    W2T[id2] = f2bf(W2[k*256 + n]);
  }
}

// ============================================================
// K1: KNN (one block per point). u64-packed (d2_bits<<32|j) extract-min,
// incremental cached minima, one barrier per round.
// ============================================================
__global__ __launch_bounds__(256) void knn_kernel(const float* __restrict__ xyz,
                                                  int* __restrict__ idx,
                                                  float* __restrict__ out_xyz) {
#pragma clang fp contract(off)
  int p = blockIdx.x;            // 0..8191
  int base = p & ~4095;          // batch base row
  int tid = threadIdx.x;
  int wv = tid >> 6;
  int ln = tid & 63;
  const float* xb = xyz + (size_t)base * 3;
  float xi0 = xyz[p*3+0], xi1 = xyz[p*3+1], xi2 = xyz[p*3+2];
  float sqi = (xi0*xi0 + xi1*xi1) + xi2*xi2;

  unsigned long long cand[16];
#pragma unroll
  for (int u = 0; u < 16; ++u) {
    int j = tid + (u << 8);
    float a0 = xb[j*3+0], a1 = xb[j*3+1], a2 = xb[j*3+2];
    float sqj = (a0*a0 + a1*a1) + a2*a2;
    float dt  = (xi0*a0 + xi1*a1) + xi2*a2;
    float d2  = (sqi + sqj) - 2.0f*dt;
    cand[u] = ((unsigned long long)__float_as_uint(d2) << 32) | (unsigned int)j;
  }
  unsigned long long myloc;
  {
    unsigned long long t[8];
#pragma unroll
    for (int u = 0; u < 8; ++u) t[u] = u64min(cand[u], cand[u + 8]);
#pragma unroll
    for (int u = 0; u < 4; ++u) t[u] = u64min(t[u], t[u + 4]);
    t[0] = u64min(t[0], t[2]); t[1] = u64min(t[1], t[3]);
    myloc = u64min(t[0], t[1]);
  }
  unsigned long long wmreg = myloc;
#pragma unroll
  for (int off = 1; off < 64; off <<= 1) wmreg = u64min(wmreg, shflx64(wmreg, off));

  __shared__ __align__(16) unsigned long long wbuf[2][4];
  __shared__ int outbuf[20];
  if (ln == 0) wbuf[0][wv] = wmreg;
  __syncthreads();

  for (int r = 0; r < 20; ++r) {
    int cur = r & 1;
    unsigned long long w0 = wbuf[cur][0], w1 = wbuf[cur][1];
    unsigned long long w2 = wbuf[cur][2], w3 = wbuf[cur][3];
    unsigned long long g = u64min(u64min(w0, w1), u64min(w2, w3));
    int wj = (int)(unsigned int)(g & 0xffffffffu);
    if (tid == (wj & 255)) {
      outbuf[r] = base + wj;
      unsigned long long m = ~0ull;
#pragma unroll
      for (int u = 0; u < 16; ++u) {
        if (cand[u] == g) cand[u] = ~0ull;
        m = u64min(m, cand[u]);
      }
      myloc = m;
    }
    if (wv == ((wj >> 6) & 3)) {
      unsigned long long t = myloc;
#pragma unroll
      for (int off = 1; off < 64; off <<= 1) t = u64min(t, shflx64(t, off));
      wmreg = t;
    }
    if (ln == 0) wbuf[cur ^ 1][wv] = wmreg;
    __syncthreads();
  }
  if (tid < 20) idx[p*20 + tid] = outbuf[tid];
  if (tid < 3) out_xyz[p*3 + tid] = xyz[p*3 + tid];   // exact fp32 copy
}

// ============================================================
// K2: BN1 stats via 6-dim edge moments (affine trick):
//   mean_c = b1[c] + w_c.S/N,  var_c = (w_c.M.w_c)/N - (w_c.S/N)^2
// ============================================================
__global__ __launch_bounds__(256) void h1_moments_kernel(const float* __restrict__ xyz,
                                                         const int* __restrict__ idx,
                                                         float* __restrict__ mbuck) {
  int tid = threadIdx.x, blk = blockIdx.x;   // 320 blocks x 512 samples
  float A[33] = {};
#pragma unroll
  for (int u = 0; u < 2; ++u) {
    int s = blk*512 + (u << 8) + tid;
    unsigned int p = (unsigned int)s / 20u;
    int jg = idx[s];
    float c0 = xyz[p*3+0], c1 = xyz[p*3+1], c2 = xyz[p*3+2];
    float e[6];
    e[0] = xyz[jg*3+0] - c0; e[1] = xyz[jg*3+1] - c1; e[2] = xyz[jg*3+2] - c2;
    e[3] = c0; e[4] = c1; e[5] = c2;
    int k = 6;
#pragma unroll
    for (int d = 0; d < 6; ++d) {
      A[d] += e[d];
#pragma unroll
      for (int d2 = d; d2 < 6; ++d2) { A[k] = fmaf(e[d], e[d2], A[k]); ++k; }
    }
  }
#pragma unroll
  for (int off = 1; off < 64; off <<= 1) {
#pragma unroll
    for (int i = 0; i < 33; ++i) A[i] += __shfl_xor(A[i], off);
  }
  if ((tid & 63) == 0) {
    int b = ((blk << 2) | (tid >> 6)) & 15;
    for (int i = 0; i < 33; ++i) atomicAdd(&mbuck[b*64 + i], A[i]);
  }
}

__global__ void bn_prep1(const float* __restrict__ W1, const float* __restrict__ b1,
                         const float* __restrict__ g1, const float* __restrict__ be1,
                         const float* __restrict__ mbuck, float* __restrict__ misc) {
  __shared__ float red[33];
  int tid = threadIdx.x;  // 128
  if (tid < 33) {
    float s = 0.f;
    for (int b = 0; b < 16; ++b) s += mbuck[b*64 + tid];
    red[tid] = s;
  }
  __syncthreads();
  int c = tid;
  float w[6];
#pragma unroll
  for (int d = 0; d < 6; ++d) w[d] = W1[d*128 + c];
  const float inv = 1.0f / (float)NSAMP;
  float t = 0.f;
#pragma unroll
  for (int d = 0; d < 6; ++d) t = fmaf(w[d], red[d], t);
  t *= inv;
  float Q = 0.f;
  int k = 6;
#pragma unroll
  for (int d = 0; d < 6; ++d) {
#pragma unroll
    for (int d2 = d; d2 < 6; ++d2) {
      float coef = (d == d2) ? w[d]*w[d] : 2.f*w[d]*w[d2];
      Q = fmaf(coef, red[k], Q); ++k;
    }
  }
  Q *= inv;
  float var = Q - t*t;
  float mu = b1[c] + t;
  float a = g1[c] / sqrtf(var + 1e-5f);
  misc[c] = a;
  misc[128 + c] = be1[c] - mu*a;
}

// ============================================================
// K4: MFMA h2: per block of 4 points (M=80): edge -> h1 (BN1+ReLU, bf16
// into LDS A-tile) -> h2 = h1 @ W2T via MFMA (N=256, K=128) -> +b2 ->
// h2 bf16 store + fused per-point gmax.
// ============================================================
__global__ __launch_bounds__(256) void h2_kernel(const float* __restrict__ xyz,
                                                 const int* __restrict__ idx,
                                                 const float* __restrict__ W1,
                                                 const float* __restrict__ b1,
                                                 const unsigned short* __restrict__ W2T,
                                                 const float* __restrict__ b2,
                                                 const float* __restrict__ misc,
                                                 unsigned short* __restrict__ h2out,
                                                 unsigned short* __restrict__ gmaxout) {
  int p0 = blockIdx.x << 2;          // 4 points
  int tid = threadIdx.x;
  int w = tid >> 6, lane = tid & 63;
  int lr = lane & 15, lg = lane >> 4;
  __shared__ float e[80][6];
  __shared__ __align__(16) unsigned short As[80][136];
  __shared__ float pool[20][264];

  bf16x8 bfr[4][4];
#pragma unroll
  for (int j = 0; j < 4; ++j)
#pragma unroll
    for (int kk = 0; kk < 4; ++kk)
      bfr[j][kk] = *(const bf16x8*)(W2T + (size_t)(w*64 + j*16 + lr)*128 + kk*32 + lg*8);

  if (tid < 80) {
    int pl = (unsigned int)tid / 20u;
    int p = p0 + pl;
    int jg = idx[p0*20 + tid];
    float xi0 = xyz[p*3+0], xi1 = xyz[p*3+1], xi2 = xyz[p*3+2];
    e[tid][0] = xyz[jg*3+0] - xi0;
    e[tid][1] = xyz[jg*3+1] - xi1;
    e[tid][2] = xyz[jg*3+2] - xi2;
    e[tid][3] = xi0; e[tid][4] = xi1; e[tid][5] = xi2;
  }
  __syncthreads();

  {
    int c = tid & 127, half = tid >> 7;
    float w1v[6];
#pragma unroll
    for (int d = 0; d < 6; ++d) w1v[d] = W1[d*128 + c];
    float b1v = b1[c], a1 = misc[c], d1 = misc[128 + c];
#pragma unroll
    for (int u = 0; u < 40; ++u) {
      int row = (u << 1) | half;
      float v = b1v;
#pragma unroll
      for (int d = 0; d < 6; ++d) v = fmaf(e[row][d], w1v[d], v);
      v = fmaxf(fmaf(a1, v, d1), 0.f);
      As[row][c] = f2bf(v);
    }
  }
  __syncthreads();

  f32x4 acc[5][4] = {};
#pragma unroll
  for (int kk = 0; kk < 4; ++kk) {
    bf16x8 a[5];
#pragma unroll
    for (int i = 0; i < 5; ++i)
      a[i] = *(const bf16x8*)&As[i*16 + lr][kk*32 + lg*8];
#pragma unroll
    for (int i = 0; i < 5; ++i)
#pragma unroll
      for (int j = 0; j < 4; ++j)
        acc[i][j] = __builtin_amdgcn_mfma_f32_16x16x32_bf16(a[i], bfr[j][kk], acc[i][j], 0, 0, 0);
  }

  float b2v[4];
#pragma unroll
  for (int j = 0; j < 4; ++j) b2v[j] = b2[w*64 + j*16 + lr];
#pragma unroll
  for (int i = 0; i < 5; ++i) {
    int rbase = p0*20 + i*16 + lg*4;
#pragma unroll
    for (int j = 0; j < 4; ++j) {
      int col = w*64 + j*16 + lr;
      float v0 = acc[i][j][0] + b2v[j];
      float v1 = acc[i][j][1] + b2v[j];
      float v2 = acc[i][j][2] + b2v[j];
      float v3 = acc[i][j][3] + b2v[j];
      h2out[(size_t)(rbase+0)*256 + col] = f2bf(v0);
      h2out[(size_t)(rbase+1)*256 + col] = f2bf(v1);
      h2out[(size_t)(rbase+2)*256 + col] = f2bf(v2);
      h2out[(size_t)(rbase+3)*256 + col] = f2bf(v3);
      pool[i*4 + lg][col] = fmaxf(fmaxf(v0, v1), fmaxf(v2, v3));
    }
  }
  __syncthreads();
#pragma unroll
  for (int l = 0; l < 4; ++l) {
    int id = tid + (l << 8);        // 0..1023 : 4 points x 256 cols
    int q = id >> 8, col = id & 255;
    float v = pool[q*5][col];
#pragma unroll
    for (int u = 1; u < 5; ++u) v = fmaxf(v, pool[q*5 + u][col]);
    gmaxout[(size_t)(p0 + q)*256 + col] = f2bf(v);
  }
}

// ============================================================
// K5: MFMA GEMM: h3 = [gmax | h2] @ W3 + b3 (163840x512x512), bf16 MFMA.
// ROUND-6 STRUCTURE (reverted): load-then-stage, no reg prefetch, simple
// bid mapping. Prefetch on this 2-barrier loop regressed 2.4x (R7 post-
// mortem: barrier vmcnt(0) drain serializes the prefetch; no VALU cover).
// ============================================================
__global__ __launch_bounds__(256) void gemm3_kernel(const unsigned short* __restrict__ h2,
                                                    const unsigned short* __restrict__ gmax,
                                                    const unsigned short* __restrict__ W3T,
                                                    const float* __restrict__ b3,
                                                    unsigned short* __restrict__ h3,
                                                    float* __restrict__ s3buck) {
  int bid = blockIdx.x;               // 1280 m * 4 n
  int bn = bid & 3, bm = bid >> 2;
  int m0 = bm << 7, n0 = bn << 7;
  int tid = threadIdx.x;
  int lane = tid & 63, w = tid >> 6;
  int mw = w >> 1, nw = w & 1;
  int lr = lane & 15, lg = lane >> 4;
  __shared__ __align__(16) unsigned short As[128][32];
  __shared__ __align__(16) unsigned short Bs[128][32];
  __shared__ float ssum[128], ssq[128];
  f32x4 acc[4][4] = {};

  for (int kc = 0; kc < 512; kc += 32) {
#pragma unroll
    for (int l = 0; l < 2; ++l) {
      int id = tid + (l << 8);        // 0..511 : 128 rows x 4 kgroups
      int row = id >> 2, kg = id & 3;
      int grow = m0 + row;
      const unsigned short* src;
      if (kc < 256) {
        unsigned int pp = (unsigned int)grow / 20u;
        src = gmax + (size_t)pp*256 + kc + (kg << 3);
      } else {
        src = h2 + (size_t)grow*256 + (kc - 256) + (kg << 3);
      }
      *(uint4*)&As[row][kg << 3] = *(const uint4*)src;
    }
#pragma unroll
    for (int l = 0; l < 2; ++l) {
      int id = tid + (l << 8);
      int row = id >> 2, kg = id & 3;
      *(uint4*)&Bs[row][kg << 3] =
          *(const uint4*)(W3T + (size_t)(n0 + row)*512 + kc + (kg << 3));
    }
    __syncthreads();
    bf16x8 a[4], b[4];
#pragma unroll
    for (int t = 0; t < 4; ++t)
      a[t] = *(const bf16x8*)&As[mw*64 + t*16 + lr][lg << 3];
#pragma unroll
    for (int t = 0; t < 4; ++t)
      b[t] = *(const bf16x8*)&Bs[nw*64 + t*16 + lr][lg << 3];
#pragma unroll
    for (int i = 0; i < 4; ++i)
#pragma unroll
      for (int j = 0; j < 4; ++j)
        acc[i][j] = __builtin_amdgcn_mfma_f32_16x16x32_bf16(a[i], b[j], acc[i][j], 0, 0, 0);
    __syncthreads();
  }

  // epilogue: +b3, bf16 store, fused BN3 stats
  if (tid < 128) { ssum[tid] = 0.f; ssq[tid] = 0.f; }
  __syncthreads();
#pragma unroll
  for (int j = 0; j < 4; ++j) {
    int colL = nw*64 + j*16 + lr;
    int col = n0 + colL;
    float b3v = b3[col];
    float sumv = 0.f, sqv = 0.f;
#pragma unroll
    for (int i = 0; i < 4; ++i) {
      int rbase = m0 + mw*64 + i*16 + lg*4;
#pragma unroll
      for (int r = 0; r < 4; ++r) {
        float v = acc[i][j][r] + b3v;
        h3[(size_t)(rbase + r)*512 + col] = f2bf(v);
        sumv += v; sqv = fmaf(v, v, sqv);
      }
    }
    sumv += __shfl_xor(sumv, 16); sumv += __shfl_xor(sumv, 32);
    sqv  += __shfl_xor(sqv, 16);  sqv  += __shfl_xor(sqv, 32);
    if (lg == 0) {
      atomicAdd(&ssum[colL], sumv);
      atomicAdd(&ssq[colL], sqv);
    }
  }
  __syncthreads();
  if (tid < 128) {
    int bkt = (bid & 63) * 1024;
    atomicAdd(&s3buck[bkt + n0 + tid], ssum[tid]);
    atomicAdd(&s3buck[bkt + 512 + n0 + tid], ssq[tid]);
  }
}

__global__ void bn_prep3(const float* __restrict__ g3, const float* __restrict__ be3,
                         const float* __restrict__ s3buck, float* __restrict__ misc) {
  int c = threadIdx.x;  // 512
  float s = 0.f, q = 0.f;
  for (int b = 0; b < 64; ++b) { s += s3buck[b*1024 + c]; q += s3buck[b*1024 + 512 + c]; }
  const float inv = 1.0f / (float)NSAMP;
  float mu = s * inv;
  float var = q * inv - mu * mu;
  float a = g3[c] / sqrtf(var + 1e-5f);
  misc[256 + c] = a;
  misc[768 + c] = be3[c] - mu * a;
}

// ============================================================
// K7: MFMA GEMM: h4 = relu(a3*h3+d3) @ W4 (+b4), fused max-pool over K=20.
// M=160 (8 points) x N=128. Reg-prefetch KEPT here (R7: helped — the BN3
// dequant VALU phase covers the load latency); pool aliases staging LDS;
// XCD sibling swizzle.
// ============================================================
__global__ __launch_bounds__(256) void gemm4_kernel(const unsigned short* __restrict__ h3,
                                                    const unsigned short* __restrict__ W4T,
                                                    const float* __restrict__ b4,
                                                    const float* __restrict__ misc,
                                                    float* __restrict__ outf) {
  int bid = blockIdx.x;             // 3072 = 128 grp * (3 bn * 8 x)
  int grp = bid / 24, rem = bid - grp*24;
  int bn = rem >> 3;
  int bm = (grp << 3) | (rem & 7);
  int m0 = bm * 160, n0 = bn << 7;
  int tid = threadIdx.x;
  int lane = tid & 63, w = tid >> 6;
  int mw = w >> 1, nw = w & 1;
  int lr = lane & 15, lg = lane >> 4;
  __shared__ __align__(16) char smem[24896];
  unsigned short (*As)[32] = (unsigned short (*)[32])smem;           // 10240 B
  unsigned short (*Bs)[32] = (unsigned short (*)[32])(smem + 10240); // 8192 B
  float (*pool)[130] = (float (*)[130])smem;                         // 20800 B (aliases As,Bs)
  float* af = (float*)(smem + 20800);
  float* df = af + 512;
#pragma unroll
  for (int l = 0; l < 2; ++l) {
    int id = tid + (l << 8);
    af[id] = misc[256 + id];
    df[id] = misc[768 + id];
  }
  __syncthreads();
  f32x4 acc[5][4] = {};

  uint4 aR[3], bR[2];
#pragma unroll
  for (int l = 0; l < 3; ++l) {
    int id = tid + (l << 8);
    if (id < 640) { int row = id >> 2, kg = id & 3;
      aR[l] = *(const uint4*)(h3 + (size_t)(m0 + row)*512 + (kg << 3)); }
  }
#pragma unroll
  for (int l = 0; l < 2; ++l) {
    int id = tid + (l << 8); int row = id >> 2, kg = id & 3;
    bR[l] = *(const uint4*)(W4T + (size_t)(n0 + row)*512 + (kg << 3));
  }

  for (int kc = 0; kc < 512; kc += 32) {
#pragma unroll
    for (int l = 0; l < 3; ++l) {
      int id = tid + (l << 8);
      if (id < 640) {
        int row = id >> 2, kg = id & 3;
        int kb = kc + (kg << 3);
        unsigned int o[4];
#pragma unroll
        for (int q = 0; q < 4; ++q) {
          unsigned int u = ((const unsigned int*)&aR[l])[q];
          float lo = bf2f((unsigned short)(u & 0xffffu));
          float hi = bf2f((unsigned short)(u >> 16));
          int k0 = kb + q*2;
          lo = fmaxf(fmaf(af[k0],   lo, df[k0]),   0.f);
          hi = fmaxf(fmaf(af[k0+1], hi, df[k0+1]), 0.f);
          o[q] = (unsigned int)f2bf(lo) | ((unsigned int)f2bf(hi) << 16);
        }
        *(uint4*)&As[row][kg << 3] = *(const uint4*)o;
      }
    }
#pragma unroll
    for (int l = 0; l < 2; ++l) {
      int id = tid + (l << 8); int row = id >> 2, kg = id & 3;
      *(uint4*)&Bs[row][kg << 3] = bR[l];
    }
    __syncthreads();
    int kn = kc + 32;
    if (kn < 512) {
#pragma unroll
      for (int l = 0; l < 3; ++l) {
        int id = tid + (l << 8);
        if (id < 640) { int row = id >> 2, kg = id & 3;
          aR[l] = *(const uint4*)(h3 + (size_t)(m0 + row)*512 + kn + (kg << 3)); }
      }
#pragma unroll
      for (int l = 0; l < 2; ++l) {
        int id = tid + (l << 8); int row = id >> 2, kg = id & 3;
        bR[l] = *(const uint4*)(W4T + (size_t)(n0 + row)*512 + kn + (kg << 3));
      }
    }
    bf16x8 a[5], b[4];
#pragma unroll
    for (int t = 0; t < 5; ++t)
      a[t] = *(const bf16x8*)&As[mw*80 + t*16 + lr][lg << 3];
#pragma unroll
    for (int t = 0; t < 4; ++t)
      b[t] = *(const bf16x8*)&Bs[nw*64 + t*16 + lr][lg << 3];
#pragma unroll
    for (int i = 0; i < 5; ++i)
#pragma unroll
      for (int j = 0; j < 4; ++j)
        acc[i][j] = __builtin_amdgcn_mfma_f32_16x16x32_bf16(a[i], b[j], acc[i][j], 0, 0, 0);
    __syncthreads();
  }

#pragma unroll
  for (int i = 0; i < 5; ++i)
#pragma unroll
    for (int j = 0; j < 4; ++j) {
      float m = fmaxf(fmaxf(acc[i][j][0], acc[i][j][1]),
                      fmaxf(acc[i][j][2], acc[i][j][3]));
      pool[mw*20 + i*4 + lg][nw*64 + j*16 + lr] = m;
    }
  __syncthreads();
#pragma unroll
  for (int l = 0; l < 4; ++l) {
    int id = tid + (l << 8);          // 0..1023 : 8 points x 128 cols
    int q = id >> 7, c = id & 127;
    int mwq = q >> 2, ql = q & 3;
    float v = pool[mwq*20 + ql*5][c];
#pragma unroll
    for (int u = 1; u < 5; ++u) v = fmaxf(v, pool[mwq*20 + ql*5 + u][c]);
    outf[(size_t)(bm*8 + q)*384 + n0 + c] = v + b4[n0 + c];
  }
}

// ============================================================
// Workspace layout:
//   0x0000000  idx        640 KB
//   0x00A0000  misc       1280 f32
//   0x00A2000  mbuck      16*64 f32 = 4 KB (zeroed)
//   0x00AA000  s3buck     256 KB  (zeroed)
//   0x00F0000  W3T bf16   512 KB
//   0x0170000  W4T bf16   384 KB
//   0x01D0000  W2T bf16   64 KB
//   0x0200000  gmax bf16  4 MB
//   0x0600000  h2   bf16  80 MB
//   0x5600000  h3   bf16  160 MB  -> end 0xF600000
// ============================================================
extern "C" void kernel_launch(void* const* d_in, const int* in_sizes, int n_in,
                              void* d_out, int out_size, void* d_ws, size_t ws_size,
                              hipStream_t stream) {
  const float* xyz = (const float*)d_in[0];
  const float* W1  = (const float*)d_in[1];
  const float* b1  = (const float*)d_in[2];
  const float* g1  = (const float*)d_in[3];
  const float* be1 = (const float*)d_in[4];
  const float* W2  = (const float*)d_in[5];
  const float* b2  = (const float*)d_in[6];
  const float* W3  = (const float*)d_in[7];
  const float* b3  = (const float*)d_in[8];
  const float* g3  = (const float*)d_in[9];
  const float* be3 = (const float*)d_in[10];
  const float* W4  = (const float*)d_in[11];
  const float* b4  = (const float*)d_in[12];

  char* ws = (char*)d_ws;
  int*            idx    = (int*)ws;
  float*          misc   = (float*)(ws + 0xA0000);
  float*          mbuck  = (float*)(ws + 0xA2000);
  float*          s3buck = (float*)(ws + 0xAA000);
  unsigned short* W3T    = (unsigned short*)(ws + 0xF0000);
  unsigned short* W4T    = (unsigned short*)(ws + 0x170000);
  unsigned short* W2T    = (unsigned short*)(ws + 0x1D0000);
  unsigned short* gmax   = (unsigned short*)(ws + 0x200000);
  unsigned short* h2     = (unsigned short*)(ws + 0x600000);
  unsigned short* h3     = (unsigned short*)(ws + 0x5600000ULL);

  float* ofp   = (float*)d_out;
  float* oxyz  = ofp;             // 24576 fp32
  float* ofeat = ofp + 24576;     // 8192*384 fp32

  hipMemsetAsync(ws + 0xA2000, 0, 0x48000, stream);   // zero mbuck + s3buck

  wprep_kernel<<<(512*512 + 384*512 + 256*128)/256, 256, 0, stream>>>(W3, W4, W2, W3T, W4T, W2T);
  knn_kernel<<<NPTS, 256, 0, stream>>>(xyz, idx, oxyz);
  h1_moments_kernel<<<NSAMP/512, 256, 0, stream>>>(xyz, idx, mbuck);
  bn_prep1<<<1, 128, 0, stream>>>(W1, b1, g1, be1, mbuck, misc);
  h2_kernel<<<NPTS/4, 256, 0, stream>>>(xyz, idx, W1, b1, W2T, b2, misc, h2, gmax);
  gemm3_kernel<<<(NSAMP/128)*4, 256, 0, stream>>>(h2, gmax, W3T, b3, h3, s3buck);
  bn_prep3<<<1, 512, 0, stream>>>(g3, be3, s3buck, misc);
  gemm4_kernel<<<(NPTS/8)*3, 256, 0, stream>>>(h3, W4T, b4, misc, ofeat);
}

// Round 9
// 552.316 us; speedup vs baseline: 1.4300x; 1.0151x over previous
//
#include <hip/hip_runtime.h>
#include <float.h>

// Problem constants: B=2, N=4096, K=20, H=384
// Inputs: fp32 arrays (values bf16-quantized by harness). Output: fp32.
#define NPTS_B 4096
#define NPTS 8192            // B*N
#define KNN 20
#define NSAMP (NPTS*KNN)     // 163840

typedef __attribute__((ext_vector_type(8))) short bf16x8;
typedef __attribute__((ext_vector_type(4))) float f32x4;

// -------- bf16 helpers (internal staging only) --------
static __device__ __forceinline__ float bf2f(unsigned short u) {
  return __uint_as_float(((unsigned int)u) << 16);
}
static __device__ __forceinline__ unsigned short f2bf(float f) {
  unsigned int u = __float_as_uint(f);
  u += 0x7fffu + ((u >> 16) & 1u);
  return (unsigned short)(u >> 16);
}
static __device__ __forceinline__ unsigned long long u64min(unsigned long long a,
                                                           unsigned long long b) {
  return a < b ? a : b;
}
static __device__ __forceinline__ unsigned long long shflx64(unsigned long long v, int m) {
  int lo = __shfl_xor((int)(unsigned int)(v & 0xffffffffull), m);
  int hi = __shfl_xor((int)(unsigned int)(v >> 32), m);
  return ((unsigned long long)(unsigned int)hi << 32) | (unsigned int)lo;
}

// ============================================================
// K0: weight prep — W3 -> W3T bf16 [n][k]; W4 -> W4T bf16 [n][k];
// W2 (128x256) -> W2T bf16 [n=256][k=128]. All values bf16-grid -> EXACT.
// ============================================================
__global__ __launch_bounds__(256) void wprep_kernel(const float* __restrict__ W3,
                                                    const float* __restrict__ W4,
                                                    const float* __restrict__ W2,
                                                    unsigned short* __restrict__ W3T,
                                                    unsigned short* __restrict__ W4T,
                                                    unsigned short* __restrict__ W2T) {
  int id = blockIdx.x * 256 + threadIdx.x;
  if (id < 512*512) {
    int n = id >> 9, k = id & 511;
    W3T[id] = f2bf(W3[k*512 + n]);
  } else if (id < 512*512 + 384*512) {
    int id2 = id - 512*512;
    int n = id2 >> 9, k = id2 & 511;
    W4T[id2] = f2bf(W4[k*384 + n]);
  } else {
    int id2 = id - (512*512 + 384*512);   // < 256*128
    int n = id2 >> 7, k = id2 & 127;
    W2T[id2] = f2bf(W2[k*256 + n]);
  }
}

// ============================================================
// K1: KNN (one block per point). u64-packed (d2_bits<<32|j) extract-min,
// incremental cached minima, one barrier per round.
// ============================================================
__global__ __launch_bounds__(256) void knn_kernel(const float* __restrict__ xyz,
                                                  int* __restrict__ idx,
                                                  float* __restrict__ out_xyz) {
#pragma clang fp contract(off)
  int p = blockIdx.x;            // 0..8191
  int base = p & ~4095;          // batch base row
  int tid = threadIdx.x;
  int wv = tid >> 6;
  int ln = tid & 63;
  const float* xb = xyz + (size_t)base * 3;
  float xi0 = xyz[p*3+0], xi1 = xyz[p*3+1], xi2 = xyz[p*3+2];
  float sqi = (xi0*xi0 + xi1*xi1) + xi2*xi2;

  unsigned long long cand[16];
#pragma unroll
  for (int u = 0; u < 16; ++u) {
    int j = tid + (u << 8);
    float a0 = xb[j*3+0], a1 = xb[j*3+1], a2 = xb[j*3+2];
    float sqj = (a0*a0 + a1*a1) + a2*a2;
    float dt  = (xi0*a0 + xi1*a1) + xi2*a2;
    float d2  = (sqi + sqj) - 2.0f*dt;
    cand[u] = ((unsigned long long)__float_as_uint(d2) << 32) | (unsigned int)j;
  }
  unsigned long long myloc;
  {
    unsigned long long t[8];
#pragma unroll
    for (int u = 0; u < 8; ++u) t[u] = u64min(cand[u], cand[u + 8]);
#pragma unroll
    for (int u = 0; u < 4; ++u) t[u] = u64min(t[u], t[u + 4]);
    t[0] = u64min(t[0], t[2]); t[1] = u64min(t[1], t[3]);
    myloc = u64min(t[0], t[1]);
  }
  unsigned long long wmreg = myloc;
#pragma unroll
  for (int off = 1; off < 64; off <<= 1) wmreg = u64min(wmreg, shflx64(wmreg, off));

  __shared__ __align__(16) unsigned long long wbuf[2][4];
  __shared__ int outbuf[20];
  if (ln == 0) wbuf[0][wv] = wmreg;
  __syncthreads();

  for (int r = 0; r < 20; ++r) {
    int cur = r & 1;
    unsigned long long w0 = wbuf[cur][0], w1 = wbuf[cur][1];
    unsigned long long w2 = wbuf[cur][2], w3 = wbuf[cur][3];
    unsigned long long g = u64min(u64min(w0, w1), u64min(w2, w3));
    int wj = (int)(unsigned int)(g & 0xffffffffu);
    if (tid == (wj & 255)) {
      outbuf[r] = base + wj;
      unsigned long long m = ~0ull;
#pragma unroll
      for (int u = 0; u < 16; ++u) {
        if (cand[u] == g) cand[u] = ~0ull;
        m = u64min(m, cand[u]);
      }
      myloc = m;
    }
    if (wv == ((wj >> 6) & 3)) {
      unsigned long long t = myloc;
#pragma unroll
      for (int off = 1; off < 64; off <<= 1) t = u64min(t, shflx64(t, off));
      wmreg = t;
    }
    if (ln == 0) wbuf[cur ^ 1][wv] = wmreg;
    __syncthreads();
  }
  if (tid < 20) idx[p*20 + tid] = outbuf[tid];
  if (tid < 3) out_xyz[p*3 + tid] = xyz[p*3 + tid];   // exact fp32 copy
}

// ============================================================
// K2: BN1 stats via 6-dim edge moments (affine trick):
//   mean_c = b1[c] + w_c.S/N,  var_c = (w_c.M.w_c)/N - (w_c.S/N)^2
// ============================================================
__global__ __launch_bounds__(256) void h1_moments_kernel(const float* __restrict__ xyz,
                                                         const int* __restrict__ idx,
                                                         float* __restrict__ mbuck) {
  int tid = threadIdx.x, blk = blockIdx.x;   // 320 blocks x 512 samples
  float A[33] = {};
#pragma unroll
  for (int u = 0; u < 2; ++u) {
    int s = blk*512 + (u << 8) + tid;
    unsigned int p = (unsigned int)s / 20u;
    int jg = idx[s];
    float c0 = xyz[p*3+0], c1 = xyz[p*3+1], c2 = xyz[p*3+2];
    float e[6];
    e[0] = xyz[jg*3+0] - c0; e[1] = xyz[jg*3+1] - c1; e[2] = xyz[jg*3+2] - c2;
    e[3] = c0; e[4] = c1; e[5] = c2;
    int k = 6;
#pragma unroll
    for (int d = 0; d < 6; ++d) {
      A[d] += e[d];
#pragma unroll
      for (int d2 = d; d2 < 6; ++d2) { A[k] = fmaf(e[d], e[d2], A[k]); ++k; }
    }
  }
#pragma unroll
  for (int off = 1; off < 64; off <<= 1) {
#pragma unroll
    for (int i = 0; i < 33; ++i) A[i] += __shfl_xor(A[i], off);
  }
  if ((tid & 63) == 0) {
    int b = ((blk << 2) | (tid >> 6)) & 15;
    for (int i = 0; i < 33; ++i) atomicAdd(&mbuck[b*64 + i], A[i]);
  }
}

__global__ void bn_prep1(const float* __restrict__ W1, const float* __restrict__ b1,
                         const float* __restrict__ g1, const float* __restrict__ be1,
                         const float* __restrict__ mbuck, float* __restrict__ misc) {
  __shared__ float red[33];
  int tid = threadIdx.x;  // 128
  if (tid < 33) {
    float s = 0.f;
    for (int b = 0; b < 16; ++b) s += mbuck[b*64 + tid];
    red[tid] = s;
  }
  __syncthreads();
  int c = tid;
  float w[6];
#pragma unroll
  for (int d = 0; d < 6; ++d) w[d] = W1[d*128 + c];
  const float inv = 1.0f / (float)NSAMP;
  float t = 0.f;
#pragma unroll
  for (int d = 0; d < 6; ++d) t = fmaf(w[d], red[d], t);
  t *= inv;
  float Q = 0.f;
  int k = 6;
#pragma unroll
  for (int d = 0; d < 6; ++d) {
#pragma unroll
    for (int d2 = d; d2 < 6; ++d2) {
      float coef = (d == d2) ? w[d]*w[d] : 2.f*w[d]*w[d2];
      Q = fmaf(coef, red[k], Q); ++k;
    }
  }
  Q *= inv;
  float var = Q - t*t;
  float mu = b1[c] + t;
  float a = g1[c] / sqrtf(var + 1e-5f);
  misc[c] = a;
  misc[128 + c] = be1[c] - mu*a;
}

// ============================================================
// K4: MFMA h2: per block of 4 points (M=80): edge -> h1 (BN1+ReLU, bf16
// into LDS A-tile) -> h2 = h1 @ W2T via MFMA (N=256, K=128) -> +b2 ->
// h2 bf16 store + fused per-point gmax.
// ============================================================
__global__ __launch_bounds__(256) void h2_kernel(const float* __restrict__ xyz,
                                                 const int* __restrict__ idx,
                                                 const float* __restrict__ W1,
                                                 const float* __restrict__ b1,
                                                 const unsigned short* __restrict__ W2T,
                                                 const float* __restrict__ b2,
                                                 const float* __restrict__ misc,
                                                 unsigned short* __restrict__ h2out,
                                                 unsigned short* __restrict__ gmaxout) {
  int p0 = blockIdx.x << 2;          // 4 points
  int tid = threadIdx.x;
  int w = tid >> 6, lane = tid & 63;
  int lr = lane & 15, lg = lane >> 4;
  __shared__ float e[80][6];
  __shared__ __align__(16) unsigned short As[80][136];
  __shared__ float pool[20][264];

  bf16x8 bfr[4][4];
#pragma unroll
  for (int j = 0; j < 4; ++j)
#pragma unroll
    for (int kk = 0; kk < 4; ++kk)
      bfr[j][kk] = *(const bf16x8*)(W2T + (size_t)(w*64 + j*16 + lr)*128 + kk*32 + lg*8);

  if (tid < 80) {
    int pl = (unsigned int)tid / 20u;
    int p = p0 + pl;
    int jg = idx[p0*20 + tid];
    float xi0 = xyz[p*3+0], xi1 = xyz[p*3+1], xi2 = xyz[p*3+2];
    e[tid][0] = xyz[jg*3+0] - xi0;
    e[tid][1] = xyz[jg*3+1] - xi1;
    e[tid][2] = xyz[jg*3+2] - xi2;
    e[tid][3] = xi0; e[tid][4] = xi1; e[tid][5] = xi2;
  }
  __syncthreads();

  {
    int c = tid & 127, half = tid >> 7;
    float w1v[6];
#pragma unroll
    for (int d = 0; d < 6; ++d) w1v[d] = W1[d*128 + c];
    float b1v = b1[c], a1 = misc[c], d1 = misc[128 + c];
#pragma unroll
    for (int u = 0; u < 40; ++u) {
      int row = (u << 1) | half;
      float v = b1v;
#pragma unroll
      for (int d = 0; d < 6; ++d) v = fmaf(e[row][d], w1v[d], v);
      v = fmaxf(fmaf(a1, v, d1), 0.f);
      As[row][c] = f2bf(v);
    }
  }
  __syncthreads();

  f32x4 acc[5][4] = {};
#pragma unroll
  for (int kk = 0; kk < 4; ++kk) {
    bf16x8 a[5];
#pragma unroll
    for (int i = 0; i < 5; ++i)
      a[i] = *(const bf16x8*)&As[i*16 + lr][kk*32 + lg*8];
#pragma unroll
    for (int i = 0; i < 5; ++i)
#pragma unroll
      for (int j = 0; j < 4; ++j)
        acc[i][j] = __builtin_amdgcn_mfma_f32_16x16x32_bf16(a[i], bfr[j][kk], acc[i][j], 0, 0, 0);
  }

  float b2v[4];
#pragma unroll
  for (int j = 0; j < 4; ++j) b2v[j] = b2[w*64 + j*16 + lr];
#pragma unroll
  for (int i = 0; i < 5; ++i) {
    int rbase = p0*20 + i*16 + lg*4;
#pragma unroll
    for (int j = 0; j < 4; ++j) {
      int col = w*64 + j*16 + lr;
      float v0 = acc[i][j][0] + b2v[j];
      float v1 = acc[i][j][1] + b2v[j];
      float v2 = acc[i][j][2] + b2v[j];
      float v3 = acc[i][j][3] + b2v[j];
      h2out[(size_t)(rbase+0)*256 + col] = f2bf(v0);
      h2out[(size_t)(rbase+1)*256 + col] = f2bf(v1);
      h2out[(size_t)(rbase+2)*256 + col] = f2bf(v2);
      h2out[(size_t)(rbase+3)*256 + col] = f2bf(v3);
      pool[i*4 + lg][col] = fmaxf(fmaxf(v0, v1), fmaxf(v2, v3));
    }
  }
  __syncthreads();
#pragma unroll
  for (int l = 0; l < 4; ++l) {
    int id = tid + (l << 8);        // 0..1023 : 4 points x 256 cols
    int q = id >> 8, col = id & 255;
    float v = pool[q*5][col];
#pragma unroll
    for (int u = 1; u < 5; ++u) v = fmaxf(v, pool[q*5 + u][col]);
    gmaxout[(size_t)(p0 + q)*256 + col] = f2bf(v);
  }
}

// ============================================================
// K5: MFMA GEMM: h3 = [gmax | h2] @ W3 + b3 (163840x512x512), bf16 MFMA.
// R6 structure: load-then-stage, no reg prefetch (prefetch regressed 2.4x).
// ============================================================
__global__ __launch_bounds__(256) void gemm3_kernel(const unsigned short* __restrict__ h2,
                                                    const unsigned short* __restrict__ gmax,
                                                    const unsigned short* __restrict__ W3T,
                                                    const float* __restrict__ b3,
                                                    unsigned short* __restrict__ h3,
                                                    float* __restrict__ s3buck) {
  int bid = blockIdx.x;               // 1280 m * 4 n
  int bn = bid & 3, bm = bid >> 2;
  int m0 = bm << 7, n0 = bn << 7;
  int tid = threadIdx.x;
  int lane = tid & 63, w = tid >> 6;
  int mw = w >> 1, nw = w & 1;
  int lr = lane & 15, lg = lane >> 4;
  __shared__ __align__(16) unsigned short As[128][32];
  __shared__ __align__(16) unsigned short Bs[128][32];
  __shared__ float ssum[128], ssq[128];
  f32x4 acc[4][4] = {};

  for (int kc = 0; kc < 512; kc += 32) {
#pragma unroll
    for (int l = 0; l < 2; ++l) {
      int id = tid + (l << 8);        // 0..511 : 128 rows x 4 kgroups
      int row = id >> 2, kg = id & 3;
      int grow = m0 + row;
      const unsigned short* src;
      if (kc < 256) {
        unsigned int pp = (unsigned int)grow / 20u;
        src = gmax + (size_t)pp*256 + kc + (kg << 3);
      } else {
        src = h2 + (size_t)grow*256 + (kc - 256) + (kg << 3);
      }
      *(uint4*)&As[row][kg << 3] = *(const uint4*)src;
    }
#pragma unroll
    for (int l = 0; l < 2; ++l) {
      int id = tid + (l << 8);
      int row = id >> 2, kg = id & 3;
      *(uint4*)&Bs[row][kg << 3] =
          *(const uint4*)(W3T + (size_t)(n0 + row)*512 + kc + (kg << 3));
    }
    __syncthreads();
    bf16x8 a[4], b[4];
#pragma unroll
    for (int t = 0; t < 4; ++t)
      a[t] = *(const bf16x8*)&As[mw*64 + t*16 + lr][lg << 3];
#pragma unroll
    for (int t = 0; t < 4; ++t)
      b[t] = *(const bf16x8*)&Bs[nw*64 + t*16 + lr][lg << 3];
#pragma unroll
    for (int i = 0; i < 4; ++i)
#pragma unroll
      for (int j = 0; j < 4; ++j)
        acc[i][j] = __builtin_amdgcn_mfma_f32_16x16x32_bf16(a[i], b[j], acc[i][j], 0, 0, 0);
    __syncthreads();
  }

  // epilogue: +b3, bf16 store, fused BN3 stats
  if (tid < 128) { ssum[tid] = 0.f; ssq[tid] = 0.f; }
  __syncthreads();
#pragma unroll
  for (int j = 0; j < 4; ++j) {
    int colL = nw*64 + j*16 + lr;
    int col = n0 + colL;
    float b3v = b3[col];
    float sumv = 0.f, sqv = 0.f;
#pragma unroll
    for (int i = 0; i < 4; ++i) {
      int rbase = m0 + mw*64 + i*16 + lg*4;
#pragma unroll
      for (int r = 0; r < 4; ++r) {
        float v = acc[i][j][r] + b3v;
        h3[(size_t)(rbase + r)*512 + col] = f2bf(v);
        sumv += v; sqv = fmaf(v, v, sqv);
      }
    }
    sumv += __shfl_xor(sumv, 16); sumv += __shfl_xor(sumv, 32);
    sqv  += __shfl_xor(sqv, 16);  sqv  += __shfl_xor(sqv, 32);
    if (lg == 0) {
      atomicAdd(&ssum[colL], sumv);
      atomicAdd(&ssq[colL], sqv);
    }
  }
  __syncthreads();
  if (tid < 128) {
    int bkt = (bid & 63) * 1024;
    atomicAdd(&s3buck[bkt + n0 + tid], ssum[tid]);
    atomicAdd(&s3buck[bkt + 512 + n0 + tid], ssq[tid]);
  }
}

__global__ void bn_prep3(const float* __restrict__ g3, const float* __restrict__ be3,
                         const float* __restrict__ s3buck, float* __restrict__ misc) {
  int c = threadIdx.x;  // 512
  float s = 0.f, q = 0.f;
  for (int b = 0; b < 64; ++b) { s += s3buck[b*1024 + c]; q += s3buck[b*1024 + 512 + c]; }
  const float inv = 1.0f / (float)NSAMP;
  float mu = s * inv;
  float var = q * inv - mu * mu;
  float a = g3[c] / sqrtf(var + 1e-5f);
  misc[256 + c] = a;
  misc[768 + c] = be3[c] - mu * a;
}

// ============================================================
// K7: MFMA GEMM: h4 = relu(a3*h3+d3) @ W4 (+b4), fused max-pool over K=20.
// R9: FULL-WIDTH N=384 per block (M=80 = 4 points) — each h3 element is
// dequanted exactly ONCE (was 3x across N-blocks; R8 PMC showed dequant
// VALU ~2x the MFMA time). 4 waves, each 80rows x 96cols = 5x6 frags.
// A reg-prefetch kept (dequant VALU covers load latency). W4T (384 KB)
// is L2-resident for all blocks. Pool aliases dead staging LDS.
// ============================================================
__global__ __launch_bounds__(256) void gemm4_kernel(const unsigned short* __restrict__ h3,
                                                    const unsigned short* __restrict__ W4T,
                                                    const float* __restrict__ b4,
                                                    const float* __restrict__ misc,
                                                    float* __restrict__ outf) {
  int bm = blockIdx.x;              // 2048 blocks: 4 points each
  int m0 = bm * 80;
  int tid = threadIdx.x;
  int lane = tid & 63, w = tid >> 6;     // w = column wave 0..3
  int lr = lane & 15, lg = lane >> 4;
  __shared__ __align__(16) char smem[35456];
  unsigned short (*As)[32] = (unsigned short (*)[32])smem;            // 80*64  = 5120 B
  unsigned short (*Bs)[32] = (unsigned short (*)[32])(smem + 5120);   // 384*64 = 24576 B
  float (*pool)[392] = (float (*)[392])smem;                          // 20*392*4 = 31360 B (alias)
  float* af = (float*)(smem + 31360);                                 // 512 f32
  float* df = af + 512;                                               // 512 f32
#pragma unroll
  for (int l = 0; l < 2; ++l) {
    int id = tid + (l << 8);
    af[id] = misc[256 + id];
    df[id] = misc[768 + id];
  }
  __syncthreads();
  f32x4 acc[5][6] = {};

  // A prefetch (80 rows x 4 kgroups = 320 uint4; round0 full, round1 tid<64)
  uint4 aR[2];
  {
    int row = tid >> 2, kg = tid & 3;
    aR[0] = *(const uint4*)(h3 + (size_t)(m0 + row)*512 + (kg << 3));
    if (tid < 64) {
      int id = 256 + tid; int row1 = id >> 2, kg1 = id & 3;
      aR[1] = *(const uint4*)(h3 + (size_t)(m0 + row1)*512 + (kg1 << 3));
    }
  }

  for (int kc = 0; kc < 512; kc += 32) {
    // --- stage A: dequant BN3 affine + relu, repack bf16 ---
#pragma unroll
    for (int l = 0; l < 2; ++l) {
      int id = tid + (l << 8);
      if (l == 0 || tid < 64) {
        int row = id >> 2, kg = id & 3;
        int kb = kc + (kg << 3);
        unsigned int o[4];
#pragma unroll
        for (int q = 0; q < 4; ++q) {
          unsigned int u = ((const unsigned int*)&aR[l])[q];
          float lo = bf2f((unsigned short)(u & 0xffffu));
          float hi = bf2f((unsigned short)(u >> 16));
          int k0 = kb + q*2;
          lo = fmaxf(fmaf(af[k0],   lo, df[k0]),   0.f);
          hi = fmaxf(fmaf(af[k0+1], hi, df[k0+1]), 0.f);
          o[q] = (unsigned int)f2bf(lo) | ((unsigned int)f2bf(hi) << 16);
        }
        *(uint4*)&As[row][kg << 3] = *(const uint4*)o;
      }
    }
    // --- stage B: raw copy (384 rows x 4 kgroups = 1536 uint4, 6 rounds) ---
#pragma unroll
    for (int l = 0; l < 6; ++l) {
      int id = tid + (l << 8);
      int row = id >> 2, kg = id & 3;
      *(uint4*)&Bs[row][kg << 3] =
          *(const uint4*)(W4T + (size_t)row*512 + kc + (kg << 3));
    }
    __syncthreads();
    // --- prefetch next A ---
    int kn = kc + 32;
    if (kn < 512) {
      int row = tid >> 2, kg = tid & 3;
      aR[0] = *(const uint4*)(h3 + (size_t)(m0 + row)*512 + kn + (kg << 3));
      if (tid < 64) {
        int id = 256 + tid; int row1 = id >> 2, kg1 = id & 3;
        aR[1] = *(const uint4*)(h3 + (size_t)(m0 + row1)*512 + kn + (kg1 << 3));
      }
    }
    // --- fragments + MFMA ---
    bf16x8 a[5], b[6];
#pragma unroll
    for (int t = 0; t < 5; ++t)
      a[t] = *(const bf16x8*)&As[t*16 + lr][lg << 3];
#pragma unroll
    for (int t = 0; t < 6; ++t)
      b[t] = *(const bf16x8*)&Bs[w*96 + t*16 + lr][lg << 3];
#pragma unroll
    for (int i = 0; i < 5; ++i)
#pragma unroll
      for (int j = 0; j < 6; ++j)
        acc[i][j] = __builtin_amdgcn_mfma_f32_16x16x32_bf16(a[i], b[j], acc[i][j], 0, 0, 0);
    __syncthreads();
  }

  // fused max-pool: per-lane reg-max (4 rows, point-pure since 4|20)
#pragma unroll
  for (int i = 0; i < 5; ++i)
#pragma unroll
    for (int j = 0; j < 6; ++j) {
      float m = fmaxf(fmaxf(acc[i][j][0], acc[i][j][1]),
                      fmaxf(acc[i][j][2], acc[i][j][3]));
      pool[i*4 + lg][w*96 + j*16 + lr] = m;
    }
  __syncthreads();
#pragma unroll
  for (int q = 0; q < 4; ++q) {
#pragma unroll
    for (int l = 0; l < 2; ++l) {
      int c = tid + (l << 8);
      if (c < 384) {
        float v = pool[q*5][c];
#pragma unroll
        for (int u = 1; u < 5; ++u) v = fmaxf(v, pool[q*5 + u][c]);
        outf[(size_t)(bm*4 + q)*384 + c] = v + b4[c];
      }
    }
  }
}

// ============================================================
// Workspace layout:
//   0x0000000  idx        640 KB
//   0x00A0000  misc       1280 f32
//   0x00A2000  mbuck      16*64 f32 = 4 KB (zeroed)
//   0x00AA000  s3buck     256 KB  (zeroed)
//   0x00F0000  W3T bf16   512 KB
//   0x0170000  W4T bf16   384 KB
//   0x01D0000  W2T bf16   64 KB
//   0x0200000  gmax bf16  4 MB
//   0x0600000  h2   bf16  80 MB
//   0x5600000  h3   bf16  160 MB  -> end 0xF600000
// ============================================================
extern "C" void kernel_launch(void* const* d_in, const int* in_sizes, int n_in,
                              void* d_out, int out_size, void* d_ws, size_t ws_size,
                              hipStream_t stream) {
  const float* xyz = (const float*)d_in[0];
  const float* W1  = (const float*)d_in[1];
  const float* b1  = (const float*)d_in[2];
  const float* g1  = (const float*)d_in[3];
  const float* be1 = (const float*)d_in[4];
  const float* W2  = (const float*)d_in[5];
  const float* b2  = (const float*)d_in[6];
  const float* W3  = (const float*)d_in[7];
  const float* b3  = (const float*)d_in[8];
  const float* g3  = (const float*)d_in[9];
  const float* be3 = (const float*)d_in[10];
  const float* W4  = (const float*)d_in[11];
  const float* b4  = (const float*)d_in[12];

  char* ws = (char*)d_ws;
  int*            idx    = (int*)ws;
  float*          misc   = (float*)(ws + 0xA0000);
  float*          mbuck  = (float*)(ws + 0xA2000);
  float*          s3buck = (float*)(ws + 0xAA000);
  unsigned short* W3T    = (unsigned short*)(ws + 0xF0000);
  unsigned short* W4T    = (unsigned short*)(ws + 0x170000);
  unsigned short* W2T    = (unsigned short*)(ws + 0x1D0000);
  unsigned short* gmax   = (unsigned short*)(ws + 0x200000);
  unsigned short* h2     = (unsigned short*)(ws + 0x600000);
  unsigned short* h3     = (unsigned short*)(ws + 0x5600000ULL);

  float* ofp   = (float*)d_out;
  float* oxyz  = ofp;             // 24576 fp32
  float* ofeat = ofp + 24576;     // 8192*384 fp32

  hipMemsetAsync(ws + 0xA2000, 0, 0x48000, stream);   // zero mbuck + s3buck

  wprep_kernel<<<(512*512 + 384*512 + 256*128)/256, 256, 0, stream>>>(W3, W4, W2, W3T, W4T, W2T);
  knn_kernel<<<NPTS, 256, 0, stream>>>(xyz, idx, oxyz);
  h1_moments_kernel<<<NSAMP/512, 256, 0, stream>>>(xyz, idx, mbuck);
  bn_prep1<<<1, 128, 0, stream>>>(W1, b1, g1, be1, mbuck, misc);
  h2_kernel<<<NPTS/4, 256, 0, stream>>>(xyz, idx, W1, b1, W2T, b2, misc, h2, gmax);
  gemm3_kernel<<<(NSAMP/128)*4, 256, 0, stream>>>(h2, gmax, W3T, b3, h3, s3buck);
  bn_prep3<<<1, 512, 0, stream>>>(g3, be3, s3buck, misc);
  gemm4_kernel<<<NPTS/4, 256, 0, stream>>>(h3, W4T, b4, misc, ofeat);
}

// Round 10
// 539.079 us; speedup vs baseline: 1.4651x; 1.0246x over previous
//
#include <hip/hip_runtime.h>
#include <float.h>

// Problem constants: B=2, N=4096, K=20, H=384
// Inputs: fp32 arrays (values bf16-quantized by harness). Output: fp32.
#define NPTS_B 4096
#define NPTS 8192            // B*N
#define KNN 20
#define NSAMP (NPTS*KNN)     // 163840

typedef __attribute__((ext_vector_type(8))) short bf16x8;
typedef __attribute__((ext_vector_type(4))) float f32x4;

// -------- bf16 helpers (internal staging only) --------
static __device__ __forceinline__ float bf2f(unsigned short u) {
  return __uint_as_float(((unsigned int)u) << 16);
}
static __device__ __forceinline__ unsigned short f2bf(float f) {
  unsigned int u = __float_as_uint(f);
  u += 0x7fffu + ((u >> 16) & 1u);
  return (unsigned short)(u >> 16);
}
static __device__ __forceinline__ unsigned long long u64min(unsigned long long a,
                                                           unsigned long long b) {
  return a < b ? a : b;
}
static __device__ __forceinline__ unsigned long long shflx64(unsigned long long v, int m) {
  int lo = __shfl_xor((int)(unsigned int)(v & 0xffffffffull), m);
  int hi = __shfl_xor((int)(unsigned int)(v >> 32), m);
  return ((unsigned long long)(unsigned int)hi << 32) | (unsigned int)lo;
}
// async global->LDS 16B: wave-uniform LDS base + lane*16 (our staging layout
// satisfies this: dest byte addr == id*16, id = tid + round*256).
static __device__ __forceinline__ void gl_lds16(const void* g, void* l) {
  __builtin_amdgcn_global_load_lds(
      (const __attribute__((address_space(1))) unsigned int*)g,
      (__attribute__((address_space(3))) unsigned int*)l, 16, 0, 0);
}

// ============================================================
// K0: weight prep — W3 -> W3T bf16 [n][k]; W4 -> W4T bf16 [n][k];
// W2 (128x256) -> W2T bf16 [n=256][k=128]. All values bf16-grid -> EXACT.
// ============================================================
__global__ __launch_bounds__(256) void wprep_kernel(const float* __restrict__ W3,
                                                    const float* __restrict__ W4,
                                                    const float* __restrict__ W2,
                                                    unsigned short* __restrict__ W3T,
                                                    unsigned short* __restrict__ W4T,
                                                    unsigned short* __restrict__ W2T) {
  int id = blockIdx.x * 256 + threadIdx.x;
  if (id < 512*512) {
    int n = id >> 9, k = id & 511;
    W3T[id] = f2bf(W3[k*512 + n]);
  } else if (id < 512*512 + 384*512) {
    int id2 = id - 512*512;
    int n = id2 >> 9, k = id2 & 511;
    W4T[id2] = f2bf(W4[k*384 + n]);
  } else {
    int id2 = id - (512*512 + 384*512);   // < 256*128
    int n = id2 >> 7, k = id2 & 127;
    W2T[id2] = f2bf(W2[k*256 + n]);
  }
}

// ============================================================
// K1: KNN (one block per point). u64-packed (d2_bits<<32|j) extract-min,
// incremental cached minima, one barrier per round.
// ============================================================
__global__ __launch_bounds__(256) void knn_kernel(const float* __restrict__ xyz,
                                                  int* __restrict__ idx,
                                                  float* __restrict__ out_xyz) {
#pragma clang fp contract(off)
  int p = blockIdx.x;            // 0..8191
  int base = p & ~4095;          // batch base row
  int tid = threadIdx.x;
  int wv = tid >> 6;
  int ln = tid & 63;
  const float* xb = xyz + (size_t)base * 3;
  float xi0 = xyz[p*3+0], xi1 = xyz[p*3+1], xi2 = xyz[p*3+2];
  float sqi = (xi0*xi0 + xi1*xi1) + xi2*xi2;

  unsigned long long cand[16];
#pragma unroll
  for (int u = 0; u < 16; ++u) {
    int j = tid + (u << 8);
    float a0 = xb[j*3+0], a1 = xb[j*3+1], a2 = xb[j*3+2];
    float sqj = (a0*a0 + a1*a1) + a2*a2;
    float dt  = (xi0*a0 + xi1*a1) + xi2*a2;
    float d2  = (sqi + sqj) - 2.0f*dt;
    cand[u] = ((unsigned long long)__float_as_uint(d2) << 32) | (unsigned int)j;
  }
  unsigned long long myloc;
  {
    unsigned long long t[8];
#pragma unroll
    for (int u = 0; u < 8; ++u) t[u] = u64min(cand[u], cand[u + 8]);
#pragma unroll
    for (int u = 0; u < 4; ++u) t[u] = u64min(t[u], t[u + 4]);
    t[0] = u64min(t[0], t[2]); t[1] = u64min(t[1], t[3]);
    myloc = u64min(t[0], t[1]);
  }
  unsigned long long wmreg = myloc;
#pragma unroll
  for (int off = 1; off < 64; off <<= 1) wmreg = u64min(wmreg, shflx64(wmreg, off));

  __shared__ __align__(16) unsigned long long wbuf[2][4];
  __shared__ int outbuf[20];
  if (ln == 0) wbuf[0][wv] = wmreg;
  __syncthreads();

  for (int r = 0; r < 20; ++r) {
    int cur = r & 1;
    unsigned long long w0 = wbuf[cur][0], w1 = wbuf[cur][1];
    unsigned long long w2 = wbuf[cur][2], w3 = wbuf[cur][3];
    unsigned long long g = u64min(u64min(w0, w1), u64min(w2, w3));
    int wj = (int)(unsigned int)(g & 0xffffffffu);
    if (tid == (wj & 255)) {
      outbuf[r] = base + wj;
      unsigned long long m = ~0ull;
#pragma unroll
      for (int u = 0; u < 16; ++u) {
        if (cand[u] == g) cand[u] = ~0ull;
        m = u64min(m, cand[u]);
      }
      myloc = m;
    }
    if (wv == ((wj >> 6) & 3)) {
      unsigned long long t = myloc;
#pragma unroll
      for (int off = 1; off < 64; off <<= 1) t = u64min(t, shflx64(t, off));
      wmreg = t;
    }
    if (ln == 0) wbuf[cur ^ 1][wv] = wmreg;
    __syncthreads();
  }
  if (tid < 20) idx[p*20 + tid] = outbuf[tid];
  if (tid < 3) out_xyz[p*3 + tid] = xyz[p*3 + tid];   // exact fp32 copy
}

// ============================================================
// K2: BN1 stats via 6-dim edge moments (affine trick):
//   mean_c = b1[c] + w_c.S/N,  var_c = (w_c.M.w_c)/N - (w_c.S/N)^2
// ============================================================
__global__ __launch_bounds__(256) void h1_moments_kernel(const float* __restrict__ xyz,
                                                         const int* __restrict__ idx,
                                                         float* __restrict__ mbuck) {
  int tid = threadIdx.x, blk = blockIdx.x;   // 320 blocks x 512 samples
  float A[33] = {};
#pragma unroll
  for (int u = 0; u < 2; ++u) {
    int s = blk*512 + (u << 8) + tid;
    unsigned int p = (unsigned int)s / 20u;
    int jg = idx[s];
    float c0 = xyz[p*3+0], c1 = xyz[p*3+1], c2 = xyz[p*3+2];
    float e[6];
    e[0] = xyz[jg*3+0] - c0; e[1] = xyz[jg*3+1] - c1; e[2] = xyz[jg*3+2] - c2;
    e[3] = c0; e[4] = c1; e[5] = c2;
    int k = 6;
#pragma unroll
    for (int d = 0; d < 6; ++d) {
      A[d] += e[d];
#pragma unroll
      for (int d2 = d; d2 < 6; ++d2) { A[k] = fmaf(e[d], e[d2], A[k]); ++k; }
    }
  }
#pragma unroll
  for (int off = 1; off < 64; off <<= 1) {
#pragma unroll
    for (int i = 0; i < 33; ++i) A[i] += __shfl_xor(A[i], off);
  }
  if ((tid & 63) == 0) {
    int b = ((blk << 2) | (tid >> 6)) & 15;
    for (int i = 0; i < 33; ++i) atomicAdd(&mbuck[b*64 + i], A[i]);
  }
}

__global__ void bn_prep1(const float* __restrict__ W1, const float* __restrict__ b1,
                         const float* __restrict__ g1, const float* __restrict__ be1,
                         const float* __restrict__ mbuck, float* __restrict__ misc) {
  __shared__ float red[33];
  int tid = threadIdx.x;  // 128
  if (tid < 33) {
    float s = 0.f;
    for (int b = 0; b < 16; ++b) s += mbuck[b*64 + tid];
    red[tid] = s;
  }
  __syncthreads();
  int c = tid;
  float w[6];
#pragma unroll
  for (int d = 0; d < 6; ++d) w[d] = W1[d*128 + c];
  const float inv = 1.0f / (float)NSAMP;
  float t = 0.f;
#pragma unroll
  for (int d = 0; d < 6; ++d) t = fmaf(w[d], red[d], t);
  t *= inv;
  float Q = 0.f;
  int k = 6;
#pragma unroll
  for (int d = 0; d < 6; ++d) {
#pragma unroll
    for (int d2 = d; d2 < 6; ++d2) {
      float coef = (d == d2) ? w[d]*w[d] : 2.f*w[d]*w[d2];
      Q = fmaf(coef, red[k], Q); ++k;
    }
  }
  Q *= inv;
  float var = Q - t*t;
  float mu = b1[c] + t;
  float a = g1[c] / sqrtf(var + 1e-5f);
  misc[c] = a;
  misc[128 + c] = be1[c] - mu*a;
}

// ============================================================
// K4: MFMA h2: per block of 4 points (M=80): edge -> h1 (BN1+ReLU, bf16
// into LDS A-tile) -> h2 = h1 @ W2T via MFMA (N=256, K=128) -> +b2 ->
// h2 bf16 store + fused per-point gmax.
// ============================================================
__global__ __launch_bounds__(256) void h2_kernel(const float* __restrict__ xyz,
                                                 const int* __restrict__ idx,
                                                 const float* __restrict__ W1,
                                                 const float* __restrict__ b1,
                                                 const unsigned short* __restrict__ W2T,
                                                 const float* __restrict__ b2,
                                                 const float* __restrict__ misc,
                                                 unsigned short* __restrict__ h2out,
                                                 unsigned short* __restrict__ gmaxout) {
  int p0 = blockIdx.x << 2;          // 4 points
  int tid = threadIdx.x;
  int w = tid >> 6, lane = tid & 63;
  int lr = lane & 15, lg = lane >> 4;
  __shared__ float e[80][6];
  __shared__ __align__(16) unsigned short As[80][136];
  __shared__ float pool[20][264];

  bf16x8 bfr[4][4];
#pragma unroll
  for (int j = 0; j < 4; ++j)
#pragma unroll
    for (int kk = 0; kk < 4; ++kk)
      bfr[j][kk] = *(const bf16x8*)(W2T + (size_t)(w*64 + j*16 + lr)*128 + kk*32 + lg*8);

  if (tid < 80) {
    int pl = (unsigned int)tid / 20u;
    int p = p0 + pl;
    int jg = idx[p0*20 + tid];
    float xi0 = xyz[p*3+0], xi1 = xyz[p*3+1], xi2 = xyz[p*3+2];
    e[tid][0] = xyz[jg*3+0] - xi0;
    e[tid][1] = xyz[jg*3+1] - xi1;
    e[tid][2] = xyz[jg*3+2] - xi2;
    e[tid][3] = xi0; e[tid][4] = xi1; e[tid][5] = xi2;
  }
  __syncthreads();

  {
    int c = tid & 127, half = tid >> 7;
    float w1v[6];
#pragma unroll
    for (int d = 0; d < 6; ++d) w1v[d] = W1[d*128 + c];
    float b1v = b1[c], a1 = misc[c], d1 = misc[128 + c];
#pragma unroll
    for (int u = 0; u < 40; ++u) {
      int row = (u << 1) | half;
      float v = b1v;
#pragma unroll
      for (int d = 0; d < 6; ++d) v = fmaf(e[row][d], w1v[d], v);
      v = fmaxf(fmaf(a1, v, d1), 0.f);
      As[row][c] = f2bf(v);
    }
  }
  __syncthreads();

  f32x4 acc[5][4] = {};
#pragma unroll
  for (int kk = 0; kk < 4; ++kk) {
    bf16x8 a[5];
#pragma unroll
    for (int i = 0; i < 5; ++i)
      a[i] = *(const bf16x8*)&As[i*16 + lr][kk*32 + lg*8];
#pragma unroll
    for (int i = 0; i < 5; ++i)
#pragma unroll
      for (int j = 0; j < 4; ++j)
        acc[i][j] = __builtin_amdgcn_mfma_f32_16x16x32_bf16(a[i], bfr[j][kk], acc[i][j], 0, 0, 0);
  }

  float b2v[4];
#pragma unroll
  for (int j = 0; j < 4; ++j) b2v[j] = b2[w*64 + j*16 + lr];
#pragma unroll
  for (int i = 0; i < 5; ++i) {
    int rbase = p0*20 + i*16 + lg*4;
#pragma unroll
    for (int j = 0; j < 4; ++j) {
      int col = w*64 + j*16 + lr;
      float v0 = acc[i][j][0] + b2v[j];
      float v1 = acc[i][j][1] + b2v[j];
      float v2 = acc[i][j][2] + b2v[j];
      float v3 = acc[i][j][3] + b2v[j];
      h2out[(size_t)(rbase+0)*256 + col] = f2bf(v0);
      h2out[(size_t)(rbase+1)*256 + col] = f2bf(v1);
      h2out[(size_t)(rbase+2)*256 + col] = f2bf(v2);
      h2out[(size_t)(rbase+3)*256 + col] = f2bf(v3);
      pool[i*4 + lg][col] = fmaxf(fmaxf(v0, v1), fmaxf(v2, v3));
    }
  }
  __syncthreads();
#pragma unroll
  for (int l = 0; l < 4; ++l) {
    int id = tid + (l << 8);        // 0..1023 : 4 points x 256 cols
    int q = id >> 8, col = id & 255;
    float v = pool[q*5][col];
#pragma unroll
    for (int u = 1; u < 5; ++u) v = fmaxf(v, pool[q*5 + u][col]);
    gmaxout[(size_t)(p0 + q)*256 + col] = f2bf(v);
  }
}

// ============================================================
// K5: MFMA GEMM: h3 = [gmax | h2] @ W3 + b3 (163840x512x512), bf16 MFMA.
// R10: staging via __builtin_amdgcn_global_load_lds width=16 (m97 lever:
// no VGPR round-trip, no staging VALU). Dest addr = id*16 == wave base +
// lane*16, satisfying the wave-uniform constraint. 2-barrier structure.
// ============================================================
__global__ __launch_bounds__(256) void gemm3_kernel(const unsigned short* __restrict__ h2,
                                                    const unsigned short* __restrict__ gmax,
                                                    const unsigned short* __restrict__ W3T,
                                                    const float* __restrict__ b3,
                                                    unsigned short* __restrict__ h3,
                                                    float* __restrict__ s3buck) {
  int bid = blockIdx.x;               // 1280 m * 4 n
  int bn = bid & 3, bm = bid >> 2;
  int m0 = bm << 7, n0 = bn << 7;
  int tid = threadIdx.x;
  int lane = tid & 63, w = tid >> 6;
  int mw = w >> 1, nw = w & 1;
  int lr = lane & 15, lg = lane >> 4;
  __shared__ __align__(16) unsigned short As[128][32];
  __shared__ __align__(16) unsigned short Bs[128][32];
  __shared__ float ssum[128], ssq[128];
  f32x4 acc[4][4] = {};

  // pre-compute per-thread staging coords (row = id>>2, kg = id&3)
  int r0 = tid >> 2,          kg0 = tid & 3;
  int r1 = (tid + 256) >> 2,  kg1 = tid & 3;       // (id&3) same for id=tid+256
  unsigned int pp0 = (unsigned int)(m0 + r0) / 20u;
  unsigned int pp1 = (unsigned int)(m0 + r1) / 20u;

  for (int kc = 0; kc < 512; kc += 32) {
    if (kc < 256) {
      gl_lds16(gmax + (size_t)pp0*256 + kc + (kg0 << 3), &As[r0][kg0 << 3]);
      gl_lds16(gmax + (size_t)pp1*256 + kc + (kg1 << 3), &As[r1][kg1 << 3]);
    } else {
      gl_lds16(h2 + (size_t)(m0 + r0)*256 + (kc - 256) + (kg0 << 3), &As[r0][kg0 << 3]);
      gl_lds16(h2 + (size_t)(m0 + r1)*256 + (kc - 256) + (kg1 << 3), &As[r1][kg1 << 3]);
    }
    gl_lds16(W3T + (size_t)(n0 + r0)*512 + kc + (kg0 << 3), &Bs[r0][kg0 << 3]);
    gl_lds16(W3T + (size_t)(n0 + r1)*512 + kc + (kg1 << 3), &Bs[r1][kg1 << 3]);
    __syncthreads();
    bf16x8 a[4], b[4];
#pragma unroll
    for (int t = 0; t < 4; ++t)
      a[t] = *(const bf16x8*)&As[mw*64 + t*16 + lr][lg << 3];
#pragma unroll
    for (int t = 0; t < 4; ++t)
      b[t] = *(const bf16x8*)&Bs[nw*64 + t*16 + lr][lg << 3];
#pragma unroll
    for (int i = 0; i < 4; ++i)
#pragma unroll
      for (int j = 0; j < 4; ++j)
        acc[i][j] = __builtin_amdgcn_mfma_f32_16x16x32_bf16(a[i], b[j], acc[i][j], 0, 0, 0);
    __syncthreads();
  }

  // epilogue: +b3, bf16 store, fused BN3 stats
  if (tid < 128) { ssum[tid] = 0.f; ssq[tid] = 0.f; }
  __syncthreads();
#pragma unroll
  for (int j = 0; j < 4; ++j) {
    int colL = nw*64 + j*16 + lr;
    int col = n0 + colL;
    float b3v = b3[col];
    float sumv = 0.f, sqv = 0.f;
#pragma unroll
    for (int i = 0; i < 4; ++i) {
      int rbase = m0 + mw*64 + i*16 + lg*4;
#pragma unroll
      for (int r = 0; r < 4; ++r) {
        float v = acc[i][j][r] + b3v;
        h3[(size_t)(rbase + r)*512 + col] = f2bf(v);
        sumv += v; sqv = fmaf(v, v, sqv);
      }
    }
    sumv += __shfl_xor(sumv, 16); sumv += __shfl_xor(sumv, 32);
    sqv  += __shfl_xor(sqv, 16);  sqv  += __shfl_xor(sqv, 32);
    if (lg == 0) {
      atomicAdd(&ssum[colL], sumv);
      atomicAdd(&ssq[colL], sqv);
    }
  }
  __syncthreads();
  if (tid < 128) {
    int bkt = (bid & 63) * 1024;
    atomicAdd(&s3buck[bkt + n0 + tid], ssum[tid]);
    atomicAdd(&s3buck[bkt + 512 + n0 + tid], ssq[tid]);
  }
}

__global__ void bn_prep3(const float* __restrict__ g3, const float* __restrict__ be3,
                         const float* __restrict__ s3buck, float* __restrict__ misc) {
  int c = threadIdx.x;  // 512
  float s = 0.f, q = 0.f;
  for (int b = 0; b < 64; ++b) { s += s3buck[b*1024 + c]; q += s3buck[b*1024 + 512 + c]; }
  const float inv = 1.0f / (float)NSAMP;
  float mu = s * inv;
  float var = q * inv - mu * mu;
  float a = g3[c] / sqrtf(var + 1e-5f);
  misc[256 + c] = a;
  misc[768 + c] = be3[c] - mu * a;
}

// ============================================================
// K7: MFMA GEMM: h4 = relu(a3*h3+d3) @ W4 (+b4), fused max-pool over K=20.
// Full-width N=384 (M=80 = 4 points, dequant once). A: reg-prefetch +
// dequant (VALU covers latency). B: global_load_lds async copy (R10).
// ============================================================
__global__ __launch_bounds__(256) void gemm4_kernel(const unsigned short* __restrict__ h3,
                                                    const unsigned short* __restrict__ W4T,
                                                    const float* __restrict__ b4,
                                                    const float* __restrict__ misc,
                                                    float* __restrict__ outf) {
  int bm = blockIdx.x;              // 2048 blocks: 4 points each
  int m0 = bm * 80;
  int tid = threadIdx.x;
  int lane = tid & 63, w = tid >> 6;     // w = column wave 0..3
  int lr = lane & 15, lg = lane >> 4;
  __shared__ __align__(16) char smem[35456];
  unsigned short (*As)[32] = (unsigned short (*)[32])smem;            // 80*64  = 5120 B
  unsigned short (*Bs)[32] = (unsigned short (*)[32])(smem + 5120);   // 384*64 = 24576 B
  float (*pool)[392] = (float (*)[392])smem;                          // 31360 B (alias)
  float* af = (float*)(smem + 31360);                                 // 512 f32
  float* df = af + 512;                                               // 512 f32
#pragma unroll
  for (int l = 0; l < 2; ++l) {
    int id = tid + (l << 8);
    af[id] = misc[256 + id];
    df[id] = misc[768 + id];
  }
  __syncthreads();
  f32x4 acc[5][6] = {};

  // A prefetch (80 rows x 4 kgroups = 320 uint4; round0 full, round1 tid<64)
  uint4 aR[2];
  {
    int row = tid >> 2, kg = tid & 3;
    aR[0] = *(const uint4*)(h3 + (size_t)(m0 + row)*512 + (kg << 3));
    if (tid < 64) {
      int id = 256 + tid; int row1 = id >> 2, kg1 = id & 3;
      aR[1] = *(const uint4*)(h3 + (size_t)(m0 + row1)*512 + (kg1 << 3));
    }
  }

  for (int kc = 0; kc < 512; kc += 32) {
    // --- stage B: async global->LDS (W4T L2-hot), 6 rounds ---
#pragma unroll
    for (int l = 0; l < 6; ++l) {
      int id = tid + (l << 8);
      int row = id >> 2, kg = id & 3;
      gl_lds16(W4T + (size_t)row*512 + kc + (kg << 3), &Bs[row][kg << 3]);
    }
    // --- stage A: dequant BN3 affine + relu, repack bf16 (covers B latency) ---
#pragma unroll
    for (int l = 0; l < 2; ++l) {
      int id = tid + (l << 8);
      if (l == 0 || tid < 64) {
        int row = id >> 2, kg = id & 3;
        int kb = kc + (kg << 3);
        unsigned int o[4];
#pragma unroll
        for (int q = 0; q < 4; ++q) {
          unsigned int u = ((const unsigned int*)&aR[l])[q];
          float lo = bf2f((unsigned short)(u & 0xffffu));
          float hi = bf2f((unsigned short)(u >> 16));
          int k0 = kb + q*2;
          lo = fmaxf(fmaf(af[k0],   lo, df[k0]),   0.f);
          hi = fmaxf(fmaf(af[k0+1], hi, df[k0+1]), 0.f);
          o[q] = (unsigned int)f2bf(lo) | ((unsigned int)f2bf(hi) << 16);
        }
        *(uint4*)&As[row][kg << 3] = *(const uint4*)o;
      }
    }
    __syncthreads();
    // --- prefetch next A ---
    int kn = kc + 32;
    if (kn < 512) {
      int row = tid >> 2, kg = tid & 3;
      aR[0] = *(const uint4*)(h3 + (size_t)(m0 + row)*512 + kn + (kg << 3));
      if (tid < 64) {
        int id = 256 + tid; int row1 = id >> 2, kg1 = id & 3;
        aR[1] = *(const uint4*)(h3 + (size_t)(m0 + row1)*512 + kn + (kg1 << 3));
      }
    }
    // --- fragments + MFMA ---
    bf16x8 a[5], b[6];
#pragma unroll
    for (int t = 0; t < 5; ++t)
      a[t] = *(const bf16x8*)&As[t*16 + lr][lg << 3];
#pragma unroll
    for (int t = 0; t < 6; ++t)
      b[t] = *(const bf16x8*)&Bs[w*96 + t*16 + lr][lg << 3];
#pragma unroll
    for (int i = 0; i < 5; ++i)
#pragma unroll
      for (int j = 0; j < 6; ++j)
        acc[i][j] = __builtin_amdgcn_mfma_f32_16x16x32_bf16(a[i], b[j], acc[i][j], 0, 0, 0);
    __syncthreads();
  }

  // fused max-pool: per-lane reg-max (4 rows, point-pure since 4|20)
#pragma unroll
  for (int i = 0; i < 5; ++i)
#pragma unroll
    for (int j = 0; j < 6; ++j) {
      float m = fmaxf(fmaxf(acc[i][j][0], acc[i][j][1]),
                      fmaxf(acc[i][j][2], acc[i][j][3]));
      pool[i*4 + lg][w*96 + j*16 + lr] = m;
    }
  __syncthreads();
#pragma unroll
  for (int q = 0; q < 4; ++q) {
#pragma unroll
    for (int l = 0; l < 2; ++l) {
      int c = tid + (l << 8);
      if (c < 384) {
        float v = pool[q*5][c];
#pragma unroll
        for (int u = 1; u < 5; ++u) v = fmaxf(v, pool[q*5 + u][c]);
        outf[(size_t)(bm*4 + q)*384 + c] = v + b4[c];
      }
    }
  }
}

// ============================================================
// Workspace layout:
//   0x0000000  idx        640 KB
//   0x00A0000  misc       1280 f32
//   0x00A2000  mbuck      16*64 f32 = 4 KB (zeroed)
//   0x00AA000  s3buck     256 KB  (zeroed)
//   0x00F0000  W3T bf16   512 KB
//   0x0170000  W4T bf16   384 KB
//   0x01D0000  W2T bf16   64 KB
//   0x0200000  gmax bf16  4 MB
//   0x0600000  h2   bf16  80 MB
//   0x5600000  h3   bf16  160 MB  -> end 0xF600000
// ============================================================
extern "C" void kernel_launch(void* const* d_in, const int* in_sizes, int n_in,
                              void* d_out, int out_size, void* d_ws, size_t ws_size,
                              hipStream_t stream) {
  const float* xyz = (const float*)d_in[0];
  const float* W1  = (const float*)d_in[1];
  const float* b1  = (const float*)d_in[2];
  const float* g1  = (const float*)d_in[3];
  const float* be1 = (const float*)d_in[4];
  const float* W2  = (const float*)d_in[5];
  const float* b2  = (const float*)d_in[6];
  const float* W3  = (const float*)d_in[7];
  const float* b3  = (const float*)d_in[8];
  const float* g3  = (const float*)d_in[9];
  const float* be3 = (const float*)d_in[10];
  const float* W4  = (const float*)d_in[11];
  const float* b4  = (const float*)d_in[12];

  char* ws = (char*)d_ws;
  int*            idx    = (int*)ws;
  float*          misc   = (float*)(ws + 0xA0000);
  float*          mbuck  = (float*)(ws + 0xA2000);
  float*          s3buck = (float*)(ws + 0xAA000);
  unsigned short* W3T    = (unsigned short*)(ws + 0xF0000);
  unsigned short* W4T    = (unsigned short*)(ws + 0x170000);
  unsigned short* W2T    = (unsigned short*)(ws + 0x1D0000);
  unsigned short* gmax   = (unsigned short*)(ws + 0x200000);
  unsigned short* h2     = (unsigned short*)(ws + 0x600000);
  unsigned short* h3     = (unsigned short*)(ws + 0x5600000ULL);

  float* ofp   = (float*)d_out;
  float* oxyz  = ofp;             // 24576 fp32
  float* ofeat = ofp + 24576;     // 8192*384 fp32

  hipMemsetAsync(ws + 0xA2000, 0, 0x48000, stream);   // zero mbuck + s3buck

  wprep_kernel<<<(512*512 + 384*512 + 256*128)/256, 256, 0, stream>>>(W3, W4, W2, W3T, W4T, W2T);
  knn_kernel<<<NPTS, 256, 0, stream>>>(xyz, idx, oxyz);
  h1_moments_kernel<<<NSAMP/512, 256, 0, stream>>>(xyz, idx, mbuck);
  bn_prep1<<<1, 128, 0, stream>>>(W1, b1, g1, be1, mbuck, misc);
  h2_kernel<<<NPTS/4, 256, 0, stream>>>(xyz, idx, W1, b1, W2T, b2, misc, h2, gmax);
  gemm3_kernel<<<(NSAMP/128)*4, 256, 0, stream>>>(h2, gmax, W3T, b3, h3, s3buck);
  bn_prep3<<<1, 512, 0, stream>>>(g3, be3, s3buck, misc);
  gemm4_kernel<<<NPTS/4, 256, 0, stream>>>(h3, W4T, b4, misc, ofeat);
}

// Round 11
// 465.536 us; speedup vs baseline: 1.6965x; 1.1580x over previous
//
#include <hip/hip_runtime.h>
#include <float.h>

// Problem constants: B=2, N=4096, K=20, H=384
// Inputs: fp32 arrays (values bf16-quantized by harness). Output: fp32.
#define NPTS_B 4096
#define NPTS 8192            // B*N
#define KNN 20
#define NSAMP (NPTS*KNN)     // 163840

typedef __attribute__((ext_vector_type(8))) short bf16x8;
typedef __attribute__((ext_vector_type(4))) float f32x4;

// -------- bf16 helpers (internal staging only) --------
static __device__ __forceinline__ float bf2f(unsigned short u) {
  return __uint_as_float(((unsigned int)u) << 16);
}
static __device__ __forceinline__ unsigned short f2bf(float f) {
  unsigned int u = __float_as_uint(f);
  u += 0x7fffu + ((u >> 16) & 1u);
  return (unsigned short)(u >> 16);
}
static __device__ __forceinline__ unsigned long long u64min(unsigned long long a,
                                                           unsigned long long b) {
  return a < b ? a : b;
}
static __device__ __forceinline__ unsigned long long shflx64(unsigned long long v, int m) {
  int lo = __shfl_xor((int)(unsigned int)(v & 0xffffffffull), m);
  int hi = __shfl_xor((int)(unsigned int)(v >> 32), m);
  return ((unsigned long long)(unsigned int)hi << 32) | (unsigned int)lo;
}
// async global->LDS 16B: wave-uniform LDS base + lane*16.
static __device__ __forceinline__ void gl_lds16(const void* g, void* l) {
  __builtin_amdgcn_global_load_lds(
      (const __attribute__((address_space(1))) unsigned int*)g,
      (__attribute__((address_space(3))) unsigned int*)l, 16, 0, 0);
}

// ============================================================
// K0: weight prep — W3 -> W3T bf16 [n][k]; W4 -> W4T bf16 [n][k];
// W2 (128x256) -> W2T bf16 [n=256][k=128]. All values bf16-grid -> EXACT.
// ============================================================
__global__ __launch_bounds__(256) void wprep_kernel(const float* __restrict__ W3,
                                                    const float* __restrict__ W4,
                                                    const float* __restrict__ W2,
                                                    unsigned short* __restrict__ W3T,
                                                    unsigned short* __restrict__ W4T,
                                                    unsigned short* __restrict__ W2T) {
  int id = blockIdx.x * 256 + threadIdx.x;
  if (id < 512*512) {
    int n = id >> 9, k = id & 511;
    W3T[id] = f2bf(W3[k*512 + n]);
  } else if (id < 512*512 + 384*512) {
    int id2 = id - 512*512;
    int n = id2 >> 9, k = id2 & 511;
    W4T[id2] = f2bf(W4[k*384 + n]);
  } else {
    int id2 = id - (512*512 + 384*512);   // < 256*128
    int n = id2 >> 7, k = id2 & 127;
    W2T[id2] = f2bf(W2[k*256 + n]);
  }
}

// ============================================================
// K1: KNN (one block per point). u64-packed (d2_bits<<32|j) extract-min,
// incremental cached minima, one barrier per round.
// ============================================================
__global__ __launch_bounds__(256) void knn_kernel(const float* __restrict__ xyz,
                                                  int* __restrict__ idx,
                                                  float* __restrict__ out_xyz) {
#pragma clang fp contract(off)
  int p = blockIdx.x;            // 0..8191
  int base = p & ~4095;          // batch base row
  int tid = threadIdx.x;
  int wv = tid >> 6;
  int ln = tid & 63;
  const float* xb = xyz + (size_t)base * 3;
  float xi0 = xyz[p*3+0], xi1 = xyz[p*3+1], xi2 = xyz[p*3+2];
  float sqi = (xi0*xi0 + xi1*xi1) + xi2*xi2;

  unsigned long long cand[16];
#pragma unroll
  for (int u = 0; u < 16; ++u) {
    int j = tid + (u << 8);
    float a0 = xb[j*3+0], a1 = xb[j*3+1], a2 = xb[j*3+2];
    float sqj = (a0*a0 + a1*a1) + a2*a2;
    float dt  = (xi0*a0 + xi1*a1) + xi2*a2;
    float d2  = (sqi + sqj) - 2.0f*dt;
    cand[u] = ((unsigned long long)__float_as_uint(d2) << 32) | (unsigned int)j;
  }
  unsigned long long myloc;
  {
    unsigned long long t[8];
#pragma unroll
    for (int u = 0; u < 8; ++u) t[u] = u64min(cand[u], cand[u + 8]);
#pragma unroll
    for (int u = 0; u < 4; ++u) t[u] = u64min(t[u], t[u + 4]);
    t[0] = u64min(t[0], t[2]); t[1] = u64min(t[1], t[3]);
    myloc = u64min(t[0], t[1]);
  }
  unsigned long long wmreg = myloc;
#pragma unroll
  for (int off = 1; off < 64; off <<= 1) wmreg = u64min(wmreg, shflx64(wmreg, off));

  __shared__ __align__(16) unsigned long long wbuf[2][4];
  __shared__ int outbuf[20];
  if (ln == 0) wbuf[0][wv] = wmreg;
  __syncthreads();

  for (int r = 0; r < 20; ++r) {
    int cur = r & 1;
    unsigned long long w0 = wbuf[cur][0], w1 = wbuf[cur][1];
    unsigned long long w2 = wbuf[cur][2], w3 = wbuf[cur][3];
    unsigned long long g = u64min(u64min(w0, w1), u64min(w2, w3));
    int wj = (int)(unsigned int)(g & 0xffffffffu);
    if (tid == (wj & 255)) {
      outbuf[r] = base + wj;
      unsigned long long m = ~0ull;
#pragma unroll
      for (int u = 0; u < 16; ++u) {
        if (cand[u] == g) cand[u] = ~0ull;
        m = u64min(m, cand[u]);
      }
      myloc = m;
    }
    if (wv == ((wj >> 6) & 3)) {
      unsigned long long t = myloc;
#pragma unroll
      for (int off = 1; off < 64; off <<= 1) t = u64min(t, shflx64(t, off));
      wmreg = t;
    }
    if (ln == 0) wbuf[cur ^ 1][wv] = wmreg;
    __syncthreads();
  }
  if (tid < 20) idx[p*20 + tid] = outbuf[tid];
  if (tid < 3) out_xyz[p*3 + tid] = xyz[p*3 + tid];   // exact fp32 copy
}

// ============================================================
// K2: BN1 stats via 6-dim edge moments (affine trick).
// ============================================================
__global__ __launch_bounds__(256) void h1_moments_kernel(const float* __restrict__ xyz,
                                                         const int* __restrict__ idx,
                                                         float* __restrict__ mbuck) {
  int tid = threadIdx.x, blk = blockIdx.x;   // 320 blocks x 512 samples
  float A[33] = {};
#pragma unroll
  for (int u = 0; u < 2; ++u) {
    int s = blk*512 + (u << 8) + tid;
    unsigned int p = (unsigned int)s / 20u;
    int jg = idx[s];
    float c0 = xyz[p*3+0], c1 = xyz[p*3+1], c2 = xyz[p*3+2];
    float e[6];
    e[0] = xyz[jg*3+0] - c0; e[1] = xyz[jg*3+1] - c1; e[2] = xyz[jg*3+2] - c2;
    e[3] = c0; e[4] = c1; e[5] = c2;
    int k = 6;
#pragma unroll
    for (int d = 0; d < 6; ++d) {
      A[d] += e[d];
#pragma unroll
      for (int d2 = d; d2 < 6; ++d2) { A[k] = fmaf(e[d], e[d2], A[k]); ++k; }
    }
  }
#pragma unroll
  for (int off = 1; off < 64; off <<= 1) {
#pragma unroll
    for (int i = 0; i < 33; ++i) A[i] += __shfl_xor(A[i], off);
  }
  if ((tid & 63) == 0) {
    int b = ((blk << 2) | (tid >> 6)) & 15;
    for (int i = 0; i < 33; ++i) atomicAdd(&mbuck[b*64 + i], A[i]);
  }
}

__global__ void bn_prep1(const float* __restrict__ W1, const float* __restrict__ b1,
                         const float* __restrict__ g1, const float* __restrict__ be1,
                         const float* __restrict__ mbuck, float* __restrict__ misc) {
  __shared__ float red[33];
  int tid = threadIdx.x;  // 128
  if (tid < 33) {
    float s = 0.f;
    for (int b = 0; b < 16; ++b) s += mbuck[b*64 + tid];
    red[tid] = s;
  }
  __syncthreads();
  int c = tid;
  float w[6];
#pragma unroll
  for (int d = 0; d < 6; ++d) w[d] = W1[d*128 + c];
  const float inv = 1.0f / (float)NSAMP;
  float t = 0.f;
#pragma unroll
  for (int d = 0; d < 6; ++d) t = fmaf(w[d], red[d], t);
  t *= inv;
  float Q = 0.f;
  int k = 6;
#pragma unroll
  for (int d = 0; d < 6; ++d) {
#pragma unroll
    for (int d2 = d; d2 < 6; ++d2) {
      float coef = (d == d2) ? w[d]*w[d] : 2.f*w[d]*w[d2];
      Q = fmaf(coef, red[k], Q); ++k;
    }
  }
  Q *= inv;
  float var = Q - t*t;
  float mu = b1[c] + t;
  float a = g1[c] / sqrtf(var + 1e-5f);
  misc[c] = a;
  misc[128 + c] = be1[c] - mu*a;
}

// ============================================================
// K4: MFMA h2: per block of 4 points (M=80): edge -> h1 (BN1+ReLU, bf16
// into LDS A-tile) -> h2 = h1 @ W2T via MFMA (N=256, K=128) -> +b2 ->
// h2 bf16 store + fused per-point gmax.
// ============================================================
__global__ __launch_bounds__(256) void h2_kernel(const float* __restrict__ xyz,
                                                 const int* __restrict__ idx,
                                                 const float* __restrict__ W1,
                                                 const float* __restrict__ b1,
                                                 const unsigned short* __restrict__ W2T,
                                                 const float* __restrict__ b2,
                                                 const float* __restrict__ misc,
                                                 unsigned short* __restrict__ h2out,
                                                 unsigned short* __restrict__ gmaxout) {
  int p0 = blockIdx.x << 2;          // 4 points
  int tid = threadIdx.x;
  int w = tid >> 6, lane = tid & 63;
  int lr = lane & 15, lg = lane >> 4;
  __shared__ float e[80][6];
  __shared__ __align__(16) unsigned short As[80][136];
  __shared__ float pool[20][264];

  bf16x8 bfr[4][4];
#pragma unroll
  for (int j = 0; j < 4; ++j)
#pragma unroll
    for (int kk = 0; kk < 4; ++kk)
      bfr[j][kk] = *(const bf16x8*)(W2T + (size_t)(w*64 + j*16 + lr)*128 + kk*32 + lg*8);

  if (tid < 80) {
    int pl = (unsigned int)tid / 20u;
    int p = p0 + pl;
    int jg = idx[p0*20 + tid];
    float xi0 = xyz[p*3+0], xi1 = xyz[p*3+1], xi2 = xyz[p*3+2];
    e[tid][0] = xyz[jg*3+0] - xi0;
    e[tid][1] = xyz[jg*3+1] - xi1;
    e[tid][2] = xyz[jg*3+2] - xi2;
    e[tid][3] = xi0; e[tid][4] = xi1; e[tid][5] = xi2;
  }
  __syncthreads();

  {
    int c = tid & 127, half = tid >> 7;
    float w1v[6];
#pragma unroll
    for (int d = 0; d < 6; ++d) w1v[d] = W1[d*128 + c];
    float b1v = b1[c], a1 = misc[c], d1 = misc[128 + c];
#pragma unroll
    for (int u = 0; u < 40; ++u) {
      int row = (u << 1) | half;
      float v = b1v;
#pragma unroll
      for (int d = 0; d < 6; ++d) v = fmaf(e[row][d], w1v[d], v);
      v = fmaxf(fmaf(a1, v, d1), 0.f);
      As[row][c] = f2bf(v);
    }
  }
  __syncthreads();

  f32x4 acc[5][4] = {};
#pragma unroll
  for (int kk = 0; kk < 4; ++kk) {
    bf16x8 a[5];
#pragma unroll
    for (int i = 0; i < 5; ++i)
      a[i] = *(const bf16x8*)&As[i*16 + lr][kk*32 + lg*8];
#pragma unroll
    for (int i = 0; i < 5; ++i)
#pragma unroll
      for (int j = 0; j < 4; ++j)
        acc[i][j] = __builtin_amdgcn_mfma_f32_16x16x32_bf16(a[i], bfr[j][kk], acc[i][j], 0, 0, 0);
  }

  float b2v[4];
#pragma unroll
  for (int j = 0; j < 4; ++j) b2v[j] = b2[w*64 + j*16 + lr];
#pragma unroll
  for (int i = 0; i < 5; ++i) {
    int rbase = p0*20 + i*16 + lg*4;
#pragma unroll
    for (int j = 0; j < 4; ++j) {
      int col = w*64 + j*16 + lr;
      float v0 = acc[i][j][0] + b2v[j];
      float v1 = acc[i][j][1] + b2v[j];
      float v2 = acc[i][j][2] + b2v[j];
      float v3 = acc[i][j][3] + b2v[j];
      h2out[(size_t)(rbase+0)*256 + col] = f2bf(v0);
      h2out[(size_t)(rbase+1)*256 + col] = f2bf(v1);
      h2out[(size_t)(rbase+2)*256 + col] = f2bf(v2);
      h2out[(size_t)(rbase+3)*256 + col] = f2bf(v3);
      pool[i*4 + lg][col] = fmaxf(fmaxf(v0, v1), fmaxf(v2, v3));
    }
  }
  __syncthreads();
#pragma unroll
  for (int l = 0; l < 4; ++l) {
    int id = tid + (l << 8);        // 0..1023 : 4 points x 256 cols
    int q = id >> 8, col = id & 255;
    float v = pool[q*5][col];
#pragma unroll
    for (int u = 1; u < 5; ++u) v = fmaxf(v, pool[q*5 + u][col]);
    gmaxout[(size_t)(p0 + q)*256 + col] = f2bf(v);
  }
}

// ============================================================
// K5: MFMA GEMM: h3 = [gmax | h2] @ W3 + b3 (163840x512x512), bf16 MFMA.
// Staging via global_load_lds width=16 (R10 win). 2-barrier structure.
// ============================================================
__global__ __launch_bounds__(256) void gemm3_kernel(const unsigned short* __restrict__ h2,
                                                    const unsigned short* __restrict__ gmax,
                                                    const unsigned short* __restrict__ W3T,
                                                    const float* __restrict__ b3,
                                                    unsigned short* __restrict__ h3,
                                                    float* __restrict__ s3buck) {
  int bid = blockIdx.x;               // 1280 m * 4 n
  int bn = bid & 3, bm = bid >> 2;
  int m0 = bm << 7, n0 = bn << 7;
  int tid = threadIdx.x;
  int lane = tid & 63, w = tid >> 6;
  int mw = w >> 1, nw = w & 1;
  int lr = lane & 15, lg = lane >> 4;
  __shared__ __align__(16) unsigned short As[128][32];
  __shared__ __align__(16) unsigned short Bs[128][32];
  __shared__ float ssum[128], ssq[128];
  f32x4 acc[4][4] = {};

  int r0 = tid >> 2,          kg0 = tid & 3;
  int r1 = (tid + 256) >> 2,  kg1 = tid & 3;
  unsigned int pp0 = (unsigned int)(m0 + r0) / 20u;
  unsigned int pp1 = (unsigned int)(m0 + r1) / 20u;

  for (int kc = 0; kc < 512; kc += 32) {
    if (kc < 256) {
      gl_lds16(gmax + (size_t)pp0*256 + kc + (kg0 << 3), &As[r0][kg0 << 3]);
      gl_lds16(gmax + (size_t)pp1*256 + kc + (kg1 << 3), &As[r1][kg1 << 3]);
    } else {
      gl_lds16(h2 + (size_t)(m0 + r0)*256 + (kc - 256) + (kg0 << 3), &As[r0][kg0 << 3]);
      gl_lds16(h2 + (size_t)(m0 + r1)*256 + (kc - 256) + (kg1 << 3), &As[r1][kg1 << 3]);
    }
    gl_lds16(W3T + (size_t)(n0 + r0)*512 + kc + (kg0 << 3), &Bs[r0][kg0 << 3]);
    gl_lds16(W3T + (size_t)(n0 + r1)*512 + kc + (kg1 << 3), &Bs[r1][kg1 << 3]);
    __syncthreads();
    bf16x8 a[4], b[4];
#pragma unroll
    for (int t = 0; t < 4; ++t)
      a[t] = *(const bf16x8*)&As[mw*64 + t*16 + lr][lg << 3];
#pragma unroll
    for (int t = 0; t < 4; ++t)
      b[t] = *(const bf16x8*)&Bs[nw*64 + t*16 + lr][lg << 3];
#pragma unroll
    for (int i = 0; i < 4; ++i)
#pragma unroll
      for (int j = 0; j < 4; ++j)
        acc[i][j] = __builtin_amdgcn_mfma_f32_16x16x32_bf16(a[i], b[j], acc[i][j], 0, 0, 0);
    __syncthreads();
  }

  if (tid < 128) { ssum[tid] = 0.f; ssq[tid] = 0.f; }
  __syncthreads();
#pragma unroll
  for (int j = 0; j < 4; ++j) {
    int colL = nw*64 + j*16 + lr;
    int col = n0 + colL;
    float b3v = b3[col];
    float sumv = 0.f, sqv = 0.f;
#pragma unroll
    for (int i = 0; i < 4; ++i) {
      int rbase = m0 + mw*64 + i*16 + lg*4;
#pragma unroll
      for (int r = 0; r < 4; ++r) {
        float v = acc[i][j][r] + b3v;
        h3[(size_t)(rbase + r)*512 + col] = f2bf(v);
        sumv += v; sqv = fmaf(v, v, sqv);
      }
    }
    sumv += __shfl_xor(sumv, 16); sumv += __shfl_xor(sumv, 32);
    sqv  += __shfl_xor(sqv, 16);  sqv  += __shfl_xor(sqv, 32);
    if (lg == 0) {
      atomicAdd(&ssum[colL], sumv);
      atomicAdd(&ssq[colL], sqv);
    }
  }
  __syncthreads();
  if (tid < 128) {
    int bkt = (bid & 63) * 1024;
    atomicAdd(&s3buck[bkt + n0 + tid], ssum[tid]);
    atomicAdd(&s3buck[bkt + 512 + n0 + tid], ssq[tid]);
  }
}

__global__ void bn_prep3(const float* __restrict__ g3, const float* __restrict__ be3,
                         const float* __restrict__ s3buck, float* __restrict__ misc) {
  int c = threadIdx.x;  // 512
  float s = 0.f, q = 0.f;
  for (int b = 0; b < 64; ++b) { s += s3buck[b*1024 + c]; q += s3buck[b*1024 + 512 + c]; }
  const float inv = 1.0f / (float)NSAMP;
  float mu = s * inv;
  float var = q * inv - mu * mu;
  float a = g3[c] / sqrtf(var + 1e-5f);
  misc[256 + c] = a;
  misc[768 + c] = be3[c] - mu * a;
}

// ============================================================
// K7: MFMA GEMM: h4 = relu(a3*h3+d3) @ W4 (+b4), fused max-pool over K=20.
// R11: 512 threads / 8 waves (R10 PMC: Occupancy 10.8%, VGPR 140 — the
// 4-wave/30-frag layout was register-starved). Wave w = cols w*48..+47,
// acc 5x3 frags = 60 VGPRs. M=80 (4 points, dequant once), N=384 full.
// A: reg-prefetch + dequant; B: global_load_lds. Pool aliases staging.
// ============================================================
__global__ __launch_bounds__(512) void gemm4_kernel(const unsigned short* __restrict__ h3,
                                                    const unsigned short* __restrict__ W4T,
                                                    const float* __restrict__ b4,
                                                    const float* __restrict__ misc,
                                                    float* __restrict__ outf) {
  int bm = blockIdx.x;              // 2048 blocks: 4 points each
  int m0 = bm * 80;
  int tid = threadIdx.x;
  int lane = tid & 63, w = tid >> 6;     // w = column wave 0..7
  int lr = lane & 15, lg = lane >> 4;
  __shared__ __align__(16) char smem[35456];
  unsigned short (*As)[32] = (unsigned short (*)[32])smem;            // 80*64  = 5120 B
  unsigned short (*Bs)[32] = (unsigned short (*)[32])(smem + 5120);   // 384*64 = 24576 B
  float (*pool)[392] = (float (*)[392])smem;                          // 31360 B (alias)
  float* af = (float*)(smem + 31360);                                 // 512 f32
  float* df = af + 512;                                               // 512 f32
  if (tid < 512) {
    af[tid] = misc[256 + tid];
    df[tid] = misc[768 + tid];
  }
  __syncthreads();
  f32x4 acc[5][3] = {};

  // A prefetch: 320 uint4 over 512 threads (tid < 320)
  uint4 aR;
  int arow = tid >> 2, akg = tid & 3;
  if (tid < 320)
    aR = *(const uint4*)(h3 + (size_t)(m0 + arow)*512 + (akg << 3));

  for (int kc = 0; kc < 512; kc += 32) {
    // --- stage B: async global->LDS, 3 rounds of 512 x 16B ---
#pragma unroll
    for (int l = 0; l < 3; ++l) {
      int id = tid + (l << 9);
      int row = id >> 2, kg = id & 3;
      gl_lds16(W4T + (size_t)row*512 + kc + (kg << 3), &Bs[row][kg << 3]);
    }
    // --- stage A: dequant BN3 affine + relu, repack bf16 ---
    if (tid < 320) {
      int kb = kc + (akg << 3);
      unsigned int o[4];
#pragma unroll
      for (int q = 0; q < 4; ++q) {
        unsigned int u = ((const unsigned int*)&aR)[q];
        float lo = bf2f((unsigned short)(u & 0xffffu));
        float hi = bf2f((unsigned short)(u >> 16));
        int k0 = kb + q*2;
        lo = fmaxf(fmaf(af[k0],   lo, df[k0]),   0.f);
        hi = fmaxf(fmaf(af[k0+1], hi, df[k0+1]), 0.f);
        o[q] = (unsigned int)f2bf(lo) | ((unsigned int)f2bf(hi) << 16);
      }
      *(uint4*)&As[arow][akg << 3] = *(const uint4*)o;
    }
    __syncthreads();
    // --- prefetch next A ---
    int kn = kc + 32;
    if (kn < 512 && tid < 320)
      aR = *(const uint4*)(h3 + (size_t)(m0 + arow)*512 + kn + (akg << 3));
    // --- fragments + MFMA ---
    bf16x8 a[5], b[3];
#pragma unroll
    for (int t = 0; t < 5; ++t)
      a[t] = *(const bf16x8*)&As[t*16 + lr][lg << 3];
#pragma unroll
    for (int t = 0; t < 3; ++t)
      b[t] = *(const bf16x8*)&Bs[w*48 + t*16 + lr][lg << 3];
#pragma unroll
    for (int i = 0; i < 5; ++i)
#pragma unroll
      for (int j = 0; j < 3; ++j)
        acc[i][j] = __builtin_amdgcn_mfma_f32_16x16x32_bf16(a[i], b[j], acc[i][j], 0, 0, 0);
    __syncthreads();
  }

  // fused max-pool: per-lane reg-max (4 rows, point-pure since 4|20)
#pragma unroll
  for (int i = 0; i < 5; ++i)
#pragma unroll
    for (int j = 0; j < 3; ++j) {
      float m = fmaxf(fmaxf(acc[i][j][0], acc[i][j][1]),
                      fmaxf(acc[i][j][2], acc[i][j][3]));
      pool[i*4 + lg][w*48 + j*16 + lr] = m;
    }
  __syncthreads();
#pragma unroll
  for (int l = 0; l < 3; ++l) {
    int id = tid + (l << 9);            // 0..1535 : 4 points x 384 cols
    int q = id / 384, c = id - q*384;
    float v = pool[q*5][c];
#pragma unroll
    for (int u = 1; u < 5; ++u) v = fmaxf(v, pool[q*5 + u][c]);
    outf[(size_t)(bm*4 + q)*384 + c] = v + b4[c];
  }
}

// ============================================================
// Workspace layout:
//   0x0000000  idx        640 KB
//   0x00A0000  misc       1280 f32
//   0x00A2000  mbuck      16*64 f32 = 4 KB (zeroed)
//   0x00AA000  s3buck     256 KB  (zeroed)
//   0x00F0000  W3T bf16   512 KB
//   0x0170000  W4T bf16   384 KB
//   0x01D0000  W2T bf16   64 KB
//   0x0200000  gmax bf16  4 MB
//   0x0600000  h2   bf16  80 MB
//   0x5600000  h3   bf16  160 MB  -> end 0xF600000
// ============================================================
extern "C" void kernel_launch(void* const* d_in, const int* in_sizes, int n_in,
                              void* d_out, int out_size, void* d_ws, size_t ws_size,
                              hipStream_t stream) {
  const float* xyz = (const float*)d_in[0];
  const float* W1  = (const float*)d_in[1];
  const float* b1  = (const float*)d_in[2];
  const float* g1  = (const float*)d_in[3];
  const float* be1 = (const float*)d_in[4];
  const float* W2  = (const float*)d_in[5];
  const float* b2  = (const float*)d_in[6];
  const float* W3  = (const float*)d_in[7];
  const float* b3  = (const float*)d_in[8];
  const float* g3  = (const float*)d_in[9];
  const float* be3 = (const float*)d_in[10];
  const float* W4  = (const float*)d_in[11];
  const float* b4  = (const float*)d_in[12];

  char* ws = (char*)d_ws;
  int*            idx    = (int*)ws;
  float*          misc   = (float*)(ws + 0xA0000);
  float*          mbuck  = (float*)(ws + 0xA2000);
  float*          s3buck = (float*)(ws + 0xAA000);
  unsigned short* W3T    = (unsigned short*)(ws + 0xF0000);
  unsigned short* W4T    = (unsigned short*)(ws + 0x170000);
  unsigned short* W2T    = (unsigned short*)(ws + 0x1D0000);
  unsigned short* gmax   = (unsigned short*)(ws + 0x200000);
  unsigned short* h2     = (unsigned short*)(ws + 0x600000);
  unsigned short* h3     = (unsigned short*)(ws + 0x5600000ULL);

  float* ofp   = (float*)d_out;
  float* oxyz  = ofp;             // 24576 fp32
  float* ofeat = ofp + 24576;     // 8192*384 fp32

  hipMemsetAsync(ws + 0xA2000, 0, 0x48000, stream);   // zero mbuck + s3buck

  wprep_kernel<<<(512*512 + 384*512 + 256*128)/256, 256, 0, stream>>>(W3, W4, W2, W3T, W4T, W2T);
  knn_kernel<<<NPTS, 256, 0, stream>>>(xyz, idx, oxyz);
  h1_moments_kernel<<<NSAMP/512, 256, 0, stream>>>(xyz, idx, mbuck);
  bn_prep1<<<1, 128, 0, stream>>>(W1, b1, g1, be1, mbuck, misc);
  h2_kernel<<<NPTS/4, 256, 0, stream>>>(xyz, idx, W1, b1, W2T, b2, misc, h2, gmax);
  gemm3_kernel<<<(NSAMP/128)*4, 256, 0, stream>>>(h2, gmax, W3T, b3, h3, s3buck);
  bn_prep3<<<1, 512, 0, stream>>>(g3, be3, s3buck, misc);
  gemm4_kernel<<<NPTS/4, 512, 0, stream>>>(h3, W4T, b4, misc, ofeat);
}

// Round 12
// 448.369 us; speedup vs baseline: 1.7615x; 1.0383x over previous
//
#include <hip/hip_runtime.h>
#include <float.h>

// Problem constants: B=2, N=4096, K=20, H=384
// Inputs: fp32 arrays (values bf16-quantized by harness). Output: fp32.
#define NPTS_B 4096
#define NPTS 8192            // B*N
#define KNN 20
#define NSAMP (NPTS*KNN)     // 163840

typedef __attribute__((ext_vector_type(8))) short bf16x8;
typedef __attribute__((ext_vector_type(4))) float f32x4;

// -------- bf16 helpers (internal staging only) --------
static __device__ __forceinline__ float bf2f(unsigned short u) {
  return __uint_as_float(((unsigned int)u) << 16);
}
static __device__ __forceinline__ unsigned short f2bf(float f) {
  unsigned int u = __float_as_uint(f);
  u += 0x7fffu + ((u >> 16) & 1u);
  return (unsigned short)(u >> 16);
}
static __device__ __forceinline__ unsigned long long u64min(unsigned long long a,
                                                           unsigned long long b) {
  return a < b ? a : b;
}
static __device__ __forceinline__ unsigned long long shflx64(unsigned long long v, int m) {
  int lo = __shfl_xor((int)(unsigned int)(v & 0xffffffffull), m);
  int hi = __shfl_xor((int)(unsigned int)(v >> 32), m);
  return ((unsigned long long)(unsigned int)hi << 32) | (unsigned int)lo;
}
// async global->LDS 16B: wave-uniform LDS base + lane*16.
static __device__ __forceinline__ void gl_lds16(const void* g, void* l) {
  __builtin_amdgcn_global_load_lds(
      (const __attribute__((address_space(1))) unsigned int*)g,
      (__attribute__((address_space(3))) unsigned int*)l, 16, 0, 0);
}

// ============================================================
// K0: weight prep — W3 -> W3T bf16 [n][k]; W4 -> W4T bf16 [n][k];
// W2 (128x256) -> W2T bf16 [n=256][k=128]. All values bf16-grid -> EXACT.
// ============================================================
__global__ __launch_bounds__(256) void wprep_kernel(const float* __restrict__ W3,
                                                    const float* __restrict__ W4,
                                                    const float* __restrict__ W2,
                                                    unsigned short* __restrict__ W3T,
                                                    unsigned short* __restrict__ W4T,
                                                    unsigned short* __restrict__ W2T) {
  int id = blockIdx.x * 256 + threadIdx.x;
  if (id < 512*512) {
    int n = id >> 9, k = id & 511;
    W3T[id] = f2bf(W3[k*512 + n]);
  } else if (id < 512*512 + 384*512) {
    int id2 = id - 512*512;
    int n = id2 >> 9, k = id2 & 511;
    W4T[id2] = f2bf(W4[k*384 + n]);
  } else {
    int id2 = id - (512*512 + 384*512);   // < 256*128
    int n = id2 >> 7, k = id2 & 127;
    W2T[id2] = f2bf(W2[k*256 + n]);
  }
}

// ============================================================
// K1: KNN (one block per point). u64-packed (d2_bits<<32|j) extract-min,
// incremental cached minima, one barrier per round.
// ============================================================
__global__ __launch_bounds__(256) void knn_kernel(const float* __restrict__ xyz,
                                                  int* __restrict__ idx,
                                                  float* __restrict__ out_xyz) {
#pragma clang fp contract(off)
  int p = blockIdx.x;            // 0..8191
  int base = p & ~4095;          // batch base row
  int tid = threadIdx.x;
  int wv = tid >> 6;
  int ln = tid & 63;
  const float* xb = xyz + (size_t)base * 3;
  float xi0 = xyz[p*3+0], xi1 = xyz[p*3+1], xi2 = xyz[p*3+2];
  float sqi = (xi0*xi0 + xi1*xi1) + xi2*xi2;

  unsigned long long cand[16];
#pragma unroll
  for (int u = 0; u < 16; ++u) {
    int j = tid + (u << 8);
    float a0 = xb[j*3+0], a1 = xb[j*3+1], a2 = xb[j*3+2];
    float sqj = (a0*a0 + a1*a1) + a2*a2;
    float dt  = (xi0*a0 + xi1*a1) + xi2*a2;
    float d2  = (sqi + sqj) - 2.0f*dt;
    cand[u] = ((unsigned long long)__float_as_uint(d2) << 32) | (unsigned int)j;
  }
  unsigned long long myloc;
  {
    unsigned long long t[8];
#pragma unroll
    for (int u = 0; u < 8; ++u) t[u] = u64min(cand[u], cand[u + 8]);
#pragma unroll
    for (int u = 0; u < 4; ++u) t[u] = u64min(t[u], t[u + 4]);
    t[0] = u64min(t[0], t[2]); t[1] = u64min(t[1], t[3]);
    myloc = u64min(t[0], t[1]);
  }
  unsigned long long wmreg = myloc;
#pragma unroll
  for (int off = 1; off < 64; off <<= 1) wmreg = u64min(wmreg, shflx64(wmreg, off));

  __shared__ __align__(16) unsigned long long wbuf[2][4];
  __shared__ int outbuf[20];
  if (ln == 0) wbuf[0][wv] = wmreg;
  __syncthreads();

  for (int r = 0; r < 20; ++r) {
    int cur = r & 1;
    unsigned long long w0 = wbuf[cur][0], w1 = wbuf[cur][1];
    unsigned long long w2 = wbuf[cur][2], w3 = wbuf[cur][3];
    unsigned long long g = u64min(u64min(w0, w1), u64min(w2, w3));
    int wj = (int)(unsigned int)(g & 0xffffffffu);
    if (tid == (wj & 255)) {
      outbuf[r] = base + wj;
      unsigned long long m = ~0ull;
#pragma unroll
      for (int u = 0; u < 16; ++u) {
        if (cand[u] == g) cand[u] = ~0ull;
        m = u64min(m, cand[u]);
      }
      myloc = m;
    }
    if (wv == ((wj >> 6) & 3)) {
      unsigned long long t = myloc;
#pragma unroll
      for (int off = 1; off < 64; off <<= 1) t = u64min(t, shflx64(t, off));
      wmreg = t;
    }
    if (ln == 0) wbuf[cur ^ 1][wv] = wmreg;
    __syncthreads();
  }
  if (tid < 20) idx[p*20 + tid] = outbuf[tid];
  if (tid < 3) out_xyz[p*3 + tid] = xyz[p*3 + tid];   // exact fp32 copy
}

// ============================================================
// K2: BN1 stats via 6-dim edge moments (affine trick).
// ============================================================
__global__ __launch_bounds__(256) void h1_moments_kernel(const float* __restrict__ xyz,
                                                         const int* __restrict__ idx,
                                                         float* __restrict__ mbuck) {
  int tid = threadIdx.x, blk = blockIdx.x;   // 320 blocks x 512 samples
  float A[33] = {};
#pragma unroll
  for (int u = 0; u < 2; ++u) {
    int s = blk*512 + (u << 8) + tid;
    unsigned int p = (unsigned int)s / 20u;
    int jg = idx[s];
    float c0 = xyz[p*3+0], c1 = xyz[p*3+1], c2 = xyz[p*3+2];
    float e[6];
    e[0] = xyz[jg*3+0] - c0; e[1] = xyz[jg*3+1] - c1; e[2] = xyz[jg*3+2] - c2;
    e[3] = c0; e[4] = c1; e[5] = c2;
    int k = 6;
#pragma unroll
    for (int d = 0; d < 6; ++d) {
      A[d] += e[d];
#pragma unroll
      for (int d2 = d; d2 < 6; ++d2) { A[k] = fmaf(e[d], e[d2], A[k]); ++k; }
    }
  }
#pragma unroll
  for (int off = 1; off < 64; off <<= 1) {
#pragma unroll
    for (int i = 0; i < 33; ++i) A[i] += __shfl_xor(A[i], off);
  }
  if ((tid & 63) == 0) {
    int b = ((blk << 2) | (tid >> 6)) & 15;
    for (int i = 0; i < 33; ++i) atomicAdd(&mbuck[b*64 + i], A[i]);
  }
}

__global__ void bn_prep1(const float* __restrict__ W1, const float* __restrict__ b1,
                         const float* __restrict__ g1, const float* __restrict__ be1,
                         const float* __restrict__ mbuck, float* __restrict__ misc) {
  __shared__ float red[33];
  int tid = threadIdx.x;  // 128
  if (tid < 33) {
    float s = 0.f;
    for (int b = 0; b < 16; ++b) s += mbuck[b*64 + tid];
    red[tid] = s;
  }
  __syncthreads();
  int c = tid;
  float w[6];
#pragma unroll
  for (int d = 0; d < 6; ++d) w[d] = W1[d*128 + c];
  const float inv = 1.0f / (float)NSAMP;
  float t = 0.f;
#pragma unroll
  for (int d = 0; d < 6; ++d) t = fmaf(w[d], red[d], t);
  t *= inv;
  float Q = 0.f;
  int k = 6;
#pragma unroll
  for (int d = 0; d < 6; ++d) {
#pragma unroll
    for (int d2 = d; d2 < 6; ++d2) {
      float coef = (d == d2) ? w[d]*w[d] : 2.f*w[d]*w[d2];
      Q = fmaf(coef, red[k], Q); ++k;
    }
  }
  Q *= inv;
  float var = Q - t*t;
  float mu = b1[c] + t;
  float a = g1[c] / sqrtf(var + 1e-5f);
  misc[c] = a;
  misc[128 + c] = be1[c] - mu*a;
}

// ============================================================
// K4: MFMA h2: per block of 4 points (M=80): edge -> h1 (BN1+ReLU, bf16
// into LDS A-tile) -> h2 = h1 @ W2T via MFMA (N=256, K=128) -> +b2 ->
// h2 bf16 store + fused per-point gmax.
// ============================================================
__global__ __launch_bounds__(256) void h2_kernel(const float* __restrict__ xyz,
                                                 const int* __restrict__ idx,
                                                 const float* __restrict__ W1,
                                                 const float* __restrict__ b1,
                                                 const unsigned short* __restrict__ W2T,
                                                 const float* __restrict__ b2,
                                                 const float* __restrict__ misc,
                                                 unsigned short* __restrict__ h2out,
                                                 unsigned short* __restrict__ gmaxout) {
  int p0 = blockIdx.x << 2;          // 4 points
  int tid = threadIdx.x;
  int w = tid >> 6, lane = tid & 63;
  int lr = lane & 15, lg = lane >> 4;
  __shared__ float e[80][6];
  __shared__ __align__(16) unsigned short As[80][136];
  __shared__ float pool[20][264];

  bf16x8 bfr[4][4];
#pragma unroll
  for (int j = 0; j < 4; ++j)
#pragma unroll
    for (int kk = 0; kk < 4; ++kk)
      bfr[j][kk] = *(const bf16x8*)(W2T + (size_t)(w*64 + j*16 + lr)*128 + kk*32 + lg*8);

  if (tid < 80) {
    int pl = (unsigned int)tid / 20u;
    int p = p0 + pl;
    int jg = idx[p0*20 + tid];
    float xi0 = xyz[p*3+0], xi1 = xyz[p*3+1], xi2 = xyz[p*3+2];
    e[tid][0] = xyz[jg*3+0] - xi0;
    e[tid][1] = xyz[jg*3+1] - xi1;
    e[tid][2] = xyz[jg*3+2] - xi2;
    e[tid][3] = xi0; e[tid][4] = xi1; e[tid][5] = xi2;
  }
  __syncthreads();

  {
    int c = tid & 127, half = tid >> 7;
    float w1v[6];
#pragma unroll
    for (int d = 0; d < 6; ++d) w1v[d] = W1[d*128 + c];
    float b1v = b1[c], a1 = misc[c], d1 = misc[128 + c];
#pragma unroll
    for (int u = 0; u < 40; ++u) {
      int row = (u << 1) | half;
      float v = b1v;
#pragma unroll
      for (int d = 0; d < 6; ++d) v = fmaf(e[row][d], w1v[d], v);
      v = fmaxf(fmaf(a1, v, d1), 0.f);
      As[row][c] = f2bf(v);
    }
  }
  __syncthreads();

  f32x4 acc[5][4] = {};
#pragma unroll
  for (int kk = 0; kk < 4; ++kk) {
    bf16x8 a[5];
#pragma unroll
    for (int i = 0; i < 5; ++i)
      a[i] = *(const bf16x8*)&As[i*16 + lr][kk*32 + lg*8];
#pragma unroll
    for (int i = 0; i < 5; ++i)
#pragma unroll
      for (int j = 0; j < 4; ++j)
        acc[i][j] = __builtin_amdgcn_mfma_f32_16x16x32_bf16(a[i], bfr[j][kk], acc[i][j], 0, 0, 0);
  }

  float b2v[4];
#pragma unroll
  for (int j = 0; j < 4; ++j) b2v[j] = b2[w*64 + j*16 + lr];
#pragma unroll
  for (int i = 0; i < 5; ++i) {
    int rbase = p0*20 + i*16 + lg*4;
#pragma unroll
    for (int j = 0; j < 4; ++j) {
      int col = w*64 + j*16 + lr;
      float v0 = acc[i][j][0] + b2v[j];
      float v1 = acc[i][j][1] + b2v[j];
      float v2 = acc[i][j][2] + b2v[j];
      float v3 = acc[i][j][3] + b2v[j];
      h2out[(size_t)(rbase+0)*256 + col] = f2bf(v0);
      h2out[(size_t)(rbase+1)*256 + col] = f2bf(v1);
      h2out[(size_t)(rbase+2)*256 + col] = f2bf(v2);
      h2out[(size_t)(rbase+3)*256 + col] = f2bf(v3);
      pool[i*4 + lg][col] = fmaxf(fmaxf(v0, v1), fmaxf(v2, v3));
    }
  }
  __syncthreads();
#pragma unroll
  for (int l = 0; l < 4; ++l) {
    int id = tid + (l << 8);        // 0..1023 : 4 points x 256 cols
    int q = id >> 8, col = id & 255;
    float v = pool[q*5][col];
#pragma unroll
    for (int u = 1; u < 5; ++u) v = fmaxf(v, pool[q*5 + u][col]);
    gmaxout[(size_t)(p0 + q)*256 + col] = f2bf(v);
  }
}

// ============================================================
// K5: MFMA GEMM: h3 = [gmax | h2] @ W3 + b3 (163840x512x512), bf16 MFMA.
// R12: BK=64 (32 MFMA per barrier drain) + XOR k-chunk swizzle.
// LDS slot (row,kgs) holds source chunk kg = kgs ^ ((row>>1)&7); DMA dest
// stays id*16 (wave-uniform+lane*16 OK, source addr is per-lane free).
// Fragment chunk for k-half h: (h*4+lg) ^ (lr>>1) -> 2-way banks (free).
// ============================================================
__global__ __launch_bounds__(256) void gemm3_kernel(const unsigned short* __restrict__ h2,
                                                    const unsigned short* __restrict__ gmax,
                                                    const unsigned short* __restrict__ W3T,
                                                    const float* __restrict__ b3,
                                                    unsigned short* __restrict__ h3,
                                                    float* __restrict__ s3buck) {
  int bid = blockIdx.x;               // 1280 m * 4 n
  int bn = bid & 3, bm = bid >> 2;
  int m0 = bm << 7, n0 = bn << 7;
  int tid = threadIdx.x;
  int lane = tid & 63, w = tid >> 6;
  int mw = w >> 1, nw = w & 1;
  int lr = lane & 15, lg = lane >> 4;
  __shared__ __align__(16) unsigned short As[128][64];
  __shared__ __align__(16) unsigned short Bs[128][64];
  __shared__ float ssum[128], ssq[128];
  f32x4 acc[4][4] = {};

  // staging coords: 4 rounds, id = tid + l*256; row=id>>3, kgs=id&7,
  // source kg = kgs ^ ((row>>1)&7) = kgs ^ ((id>>4)&7)
  int rS[4], kgS[4], ksS[4];
  unsigned int ppS[4];
#pragma unroll
  for (int l = 0; l < 4; ++l) {
    int id = tid + (l << 8);
    rS[l] = id >> 3;
    ksS[l] = id & 7;
    kgS[l] = ksS[l] ^ ((id >> 4) & 7);
    ppS[l] = (unsigned int)(m0 + rS[l]) / 20u;
  }
  int swz = lr >> 1;

  for (int kc = 0; kc < 512; kc += 64) {
    if (kc < 256) {
#pragma unroll
      for (int l = 0; l < 4; ++l)
        gl_lds16(gmax + (size_t)ppS[l]*256 + kc + (kgS[l] << 3), &As[rS[l]][ksS[l] << 3]);
    } else {
#pragma unroll
      for (int l = 0; l < 4; ++l)
        gl_lds16(h2 + (size_t)(m0 + rS[l])*256 + (kc - 256) + (kgS[l] << 3), &As[rS[l]][ksS[l] << 3]);
    }
#pragma unroll
    for (int l = 0; l < 4; ++l)
      gl_lds16(W3T + (size_t)(n0 + rS[l])*512 + kc + (kgS[l] << 3), &Bs[rS[l]][ksS[l] << 3]);
    __syncthreads();
#pragma unroll
    for (int h = 0; h < 2; ++h) {
      int ch = ((h << 2) | lg) ^ swz;
      bf16x8 a[4], b[4];
#pragma unroll
      for (int t = 0; t < 4; ++t)
        a[t] = *(const bf16x8*)&As[mw*64 + t*16 + lr][ch << 3];
#pragma unroll
      for (int t = 0; t < 4; ++t)
        b[t] = *(const bf16x8*)&Bs[nw*64 + t*16 + lr][ch << 3];
#pragma unroll
      for (int i = 0; i < 4; ++i)
#pragma unroll
        for (int j = 0; j < 4; ++j)
          acc[i][j] = __builtin_amdgcn_mfma_f32_16x16x32_bf16(a[i], b[j], acc[i][j], 0, 0, 0);
    }
    __syncthreads();
  }

  if (tid < 128) { ssum[tid] = 0.f; ssq[tid] = 0.f; }
  __syncthreads();
#pragma unroll
  for (int j = 0; j < 4; ++j) {
    int colL = nw*64 + j*16 + lr;
    int col = n0 + colL;
    float b3v = b3[col];
    float sumv = 0.f, sqv = 0.f;
#pragma unroll
    for (int i = 0; i < 4; ++i) {
      int rbase = m0 + mw*64 + i*16 + lg*4;
#pragma unroll
      for (int r = 0; r < 4; ++r) {
        float v = acc[i][j][r] + b3v;
        h3[(size_t)(rbase + r)*512 + col] = f2bf(v);
        sumv += v; sqv = fmaf(v, v, sqv);
      }
    }
    sumv += __shfl_xor(sumv, 16); sumv += __shfl_xor(sumv, 32);
    sqv  += __shfl_xor(sqv, 16);  sqv  += __shfl_xor(sqv, 32);
    if (lg == 0) {
      atomicAdd(&ssum[colL], sumv);
      atomicAdd(&ssq[colL], sqv);
    }
  }
  __syncthreads();
  if (tid < 128) {
    int bkt = (bid & 63) * 1024;
    atomicAdd(&s3buck[bkt + n0 + tid], ssum[tid]);
    atomicAdd(&s3buck[bkt + 512 + n0 + tid], ssq[tid]);
  }
}

__global__ void bn_prep3(const float* __restrict__ g3, const float* __restrict__ be3,
                         const float* __restrict__ s3buck, float* __restrict__ misc) {
  int c = threadIdx.x;  // 512
  float s = 0.f, q = 0.f;
  for (int b = 0; b < 64; ++b) { s += s3buck[b*1024 + c]; q += s3buck[b*1024 + 512 + c]; }
  const float inv = 1.0f / (float)NSAMP;
  float mu = s * inv;
  float var = q * inv - mu * mu;
  float a = g3[c] / sqrtf(var + 1e-5f);
  misc[256 + c] = a;
  misc[768 + c] = be3[c] - mu * a;
}

// ============================================================
// K7: MFMA GEMM: h4 = relu(a3*h3+d3) @ W4 (+b4), fused max-pool over K=20.
// 512 thr / 8 waves (R11 win). R12: Bs XOR swizzle (kgs = kg^((row>>1)&3)),
// As padded to stride 40 (2-way banks) — kills the 6.3e6 conflicts.
// ============================================================
__global__ __launch_bounds__(512) void gemm4_kernel(const unsigned short* __restrict__ h3,
                                                    const unsigned short* __restrict__ W4T,
                                                    const float* __restrict__ b4,
                                                    const float* __restrict__ misc,
                                                    float* __restrict__ outf) {
  int bm = blockIdx.x;              // 2048 blocks: 4 points each
  int m0 = bm * 80;
  int tid = threadIdx.x;
  int lane = tid & 63, w = tid >> 6;     // w = column wave 0..7
  int lr = lane & 15, lg = lane >> 4;
  __shared__ __align__(16) char smem[35072];
  unsigned short (*As)[40] = (unsigned short (*)[40])smem;            // 80*80  = 6400 B (padded)
  unsigned short (*Bs)[32] = (unsigned short (*)[32])(smem + 6400);   // 384*64 = 24576 B
  float (*pool)[392] = (float (*)[392])smem;                          // 31360 B (alias; af/df dead by then? no—)
  float* af = (float*)(smem + 30976);                                 // 512 f32
  float* df = af + 512;                                               // 512 f32  -> ends 35072
  if (tid < 512) {
    af[tid] = misc[256 + tid];
    df[tid] = misc[768 + tid];
  }
  __syncthreads();
  f32x4 acc[5][3] = {};

  // A prefetch: 320 uint4 over 512 threads (tid < 320)
  uint4 aR;
  int arow = tid >> 2, akg = tid & 3;
  if (tid < 320)
    aR = *(const uint4*)(h3 + (size_t)(m0 + arow)*512 + (akg << 3));
  int swz4 = (lr >> 1) & 3;

  for (int kc = 0; kc < 512; kc += 32) {
    // --- stage B: async global->LDS with XOR swizzle, 3 rounds ---
#pragma unroll
    for (int l = 0; l < 3; ++l) {
      int id = tid + (l << 9);
      int row = id >> 2, kgs = id & 3;
      int kg = kgs ^ ((row >> 1) & 3);
      gl_lds16(W4T + (size_t)row*512 + kc + (kg << 3), &Bs[row][kgs << 3]);
    }
    // --- stage A: dequant BN3 affine + relu, repack bf16 ---
    if (tid < 320) {
      int kb = kc + (akg << 3);
      unsigned int o[4];
#pragma unroll
      for (int q = 0; q < 4; ++q) {
        unsigned int u = ((const unsigned int*)&aR)[q];
        float lo = bf2f((unsigned short)(u & 0xffffu));
        float hi = bf2f((unsigned short)(u >> 16));
        int k0 = kb + q*2;
        lo = fmaxf(fmaf(af[k0],   lo, df[k0]),   0.f);
        hi = fmaxf(fmaf(af[k0+1], hi, df[k0+1]), 0.f);
        o[q] = (unsigned int)f2bf(lo) | ((unsigned int)f2bf(hi) << 16);
      }
      *(uint4*)&As[arow][akg << 3] = *(const uint4*)o;
    }
    __syncthreads();
    // --- prefetch next A ---
    int kn = kc + 32;
    if (kn < 512 && tid < 320)
      aR = *(const uint4*)(h3 + (size_t)(m0 + arow)*512 + kn + (akg << 3));
    // --- fragments + MFMA ---
    bf16x8 a[5], b[3];
#pragma unroll
    for (int t = 0; t < 5; ++t)
      a[t] = *(const bf16x8*)&As[t*16 + lr][lg << 3];
#pragma unroll
    for (int t = 0; t < 3; ++t)
      b[t] = *(const bf16x8*)&Bs[w*48 + t*16 + lr][(lg ^ swz4) << 3];
#pragma unroll
    for (int i = 0; i < 5; ++i)
#pragma unroll
      for (int j = 0; j < 3; ++j)
        acc[i][j] = __builtin_amdgcn_mfma_f32_16x16x32_bf16(a[i], b[j], acc[i][j], 0, 0, 0);
    __syncthreads();
  }

  // fused max-pool: per-lane reg-max (4 rows, point-pure since 4|20)
  // pool aliases As/Bs/af/df — all dead after the loop's final barrier.
#pragma unroll
  for (int i = 0; i < 5; ++i)
#pragma unroll
    for (int j = 0; j < 3; ++j) {
      float m = fmaxf(fmaxf(acc[i][j][0], acc[i][j][1]),
                      fmaxf(acc[i][j][2], acc[i][j][3]));
      pool[i*4 + lg][w*48 + j*16 + lr] = m;
    }
  __syncthreads();
#pragma unroll
  for (int l = 0; l < 3; ++l) {
    int id = tid + (l << 9);            // 0..1535 : 4 points x 384 cols
    int q = id / 384, c = id - q*384;
    float v = pool[q*5][c];
#pragma unroll
    for (int u = 1; u < 5; ++u) v = fmaxf(v, pool[q*5 + u][c]);
    outf[(size_t)(bm*4 + q)*384 + c] = v + b4[c];
  }
}

// ============================================================
// Workspace layout:
//   0x0000000  idx        640 KB
//   0x00A0000  misc       1280 f32
//   0x00A2000  mbuck      16*64 f32 = 4 KB (zeroed)
//   0x00AA000  s3buck     256 KB  (zeroed)
//   0x00F0000  W3T bf16   512 KB
//   0x0170000  W4T bf16   384 KB
//   0x01D0000  W2T bf16   64 KB
//   0x0200000  gmax bf16  4 MB
//   0x0600000  h2   bf16  80 MB
//   0x5600000  h3   bf16  160 MB  -> end 0xF600000
// ============================================================
extern "C" void kernel_launch(void* const* d_in, const int* in_sizes, int n_in,
                              void* d_out, int out_size, void* d_ws, size_t ws_size,
                              hipStream_t stream) {
  const float* xyz = (const float*)d_in[0];
  const float* W1  = (const float*)d_in[1];
  const float* b1  = (const float*)d_in[2];
  const float* g1  = (const float*)d_in[3];
  const float* be1 = (const float*)d_in[4];
  const float* W2  = (const float*)d_in[5];
  const float* b2  = (const float*)d_in[6];
  const float* W3  = (const float*)d_in[7];
  const float* b3  = (const float*)d_in[8];
  const float* g3  = (const float*)d_in[9];
  const float* be3 = (const float*)d_in[10];
  const float* W4  = (const float*)d_in[11];
  const float* b4  = (const float*)d_in[12];

  char* ws = (char*)d_ws;
  int*            idx    = (int*)ws;
  float*          misc   = (float*)(ws + 0xA0000);
  float*          mbuck  = (float*)(ws + 0xA2000);
  float*          s3buck = (float*)(ws + 0xAA000);
  unsigned short* W3T    = (unsigned short*)(ws + 0xF0000);
  unsigned short* W4T    = (unsigned short*)(ws + 0x170000);
  unsigned short* W2T    = (unsigned short*)(ws + 0x1D0000);
  unsigned short* gmax   = (unsigned short*)(ws + 0x200000);
  unsigned short* h2     = (unsigned short*)(ws + 0x600000);
  unsigned short* h3     = (unsigned short*)(ws + 0x5600000ULL);

  float* ofp   = (float*)d_out;
  float* oxyz  = ofp;             // 24576 fp32
  float* ofeat = ofp + 24576;     // 8192*384 fp32

  hipMemsetAsync(ws + 0xA2000, 0, 0x48000, stream);   // zero mbuck + s3buck

  wprep_kernel<<<(512*512 + 384*512 + 256*128)/256, 256, 0, stream>>>(W3, W4, W2, W3T, W4T, W2T);
  knn_kernel<<<NPTS, 256, 0, stream>>>(xyz, idx, oxyz);
  h1_moments_kernel<<<NSAMP/512, 256, 0, stream>>>(xyz, idx, mbuck);
  bn_prep1<<<1, 128, 0, stream>>>(W1, b1, g1, be1, mbuck, misc);
  h2_kernel<<<NPTS/4, 256, 0, stream>>>(xyz, idx, W1, b1, W2T, b2, misc, h2, gmax);
  gemm3_kernel<<<(NSAMP/128)*4, 256, 0, stream>>>(h2, gmax, W3T, b3, h3, s3buck);
  bn_prep3<<<1, 512, 0, stream>>>(g3, be3, s3buck, misc);
  gemm4_kernel<<<NPTS/4, 512, 0, stream>>>(h3, W4T, b4, misc, ofeat);
}

// Round 13
// 442.074 us; speedup vs baseline: 1.7865x; 1.0142x over previous
//
#include <hip/hip_runtime.h>
#include <float.h>

// Problem constants: B=2, N=4096, K=20, H=384
// Inputs: fp32 arrays (values bf16-quantized by harness). Output: fp32.
#define NPTS_B 4096
#define NPTS 8192            // B*N
#define KNN 20
#define NSAMP (NPTS*KNN)     // 163840

typedef __attribute__((ext_vector_type(8))) short bf16x8;
typedef __attribute__((ext_vector_type(4))) float f32x4;

// -------- bf16 helpers (internal staging only) --------
static __device__ __forceinline__ float bf2f(unsigned short u) {
  return __uint_as_float(((unsigned int)u) << 16);
}
static __device__ __forceinline__ unsigned short f2bf(float f) {
  unsigned int u = __float_as_uint(f);
  u += 0x7fffu + ((u >> 16) & 1u);
  return (unsigned short)(u >> 16);
}
static __device__ __forceinline__ unsigned long long u64min(unsigned long long a,
                                                           unsigned long long b) {
  return a < b ? a : b;
}
static __device__ __forceinline__ unsigned long long shflx64(unsigned long long v, int m) {
  int lo = __shfl_xor((int)(unsigned int)(v & 0xffffffffull), m);
  int hi = __shfl_xor((int)(unsigned int)(v >> 32), m);
  return ((unsigned long long)(unsigned int)hi << 32) | (unsigned int)lo;
}
// async global->LDS 16B: wave-uniform LDS base + lane*16.
static __device__ __forceinline__ void gl_lds16(const void* g, void* l) {
  __builtin_amdgcn_global_load_lds(
      (const __attribute__((address_space(1))) unsigned int*)g,
      (__attribute__((address_space(3))) unsigned int*)l, 16, 0, 0);
}

// ============================================================
// K0: weight prep — W3 -> W3T bf16 [n][k]; W4 -> W4T bf16 [n][k];
// W2 (128x256) -> W2T bf16 [n=256][k=128]. All values bf16-grid -> EXACT.
// ============================================================
__global__ __launch_bounds__(256) void wprep_kernel(const float* __restrict__ W3,
                                                    const float* __restrict__ W4,
                                                    const float* __restrict__ W2,
                                                    unsigned short* __restrict__ W3T,
                                                    unsigned short* __restrict__ W4T,
                                                    unsigned short* __restrict__ W2T) {
  int id = blockIdx.x * 256 + threadIdx.x;
  if (id < 512*512) {
    int n = id >> 9, k = id & 511;
    W3T[id] = f2bf(W3[k*512 + n]);
  } else if (id < 512*512 + 384*512) {
    int id2 = id - 512*512;
    int n = id2 >> 9, k = id2 & 511;
    W4T[id2] = f2bf(W4[k*384 + n]);
  } else {
    int id2 = id - (512*512 + 384*512);   // < 256*128
    int n = id2 >> 7, k = id2 & 127;
    W2T[id2] = f2bf(W2[k*256 + n]);
  }
}

// ============================================================
// K1: KNN (one block per point). u64-packed (d2_bits<<32|j) extract-min,
// incremental cached minima, one barrier per round.
// ============================================================
__global__ __launch_bounds__(256) void knn_kernel(const float* __restrict__ xyz,
                                                  int* __restrict__ idx,
                                                  float* __restrict__ out_xyz) {
#pragma clang fp contract(off)
  int p = blockIdx.x;            // 0..8191
  int base = p & ~4095;          // batch base row
  int tid = threadIdx.x;
  int wv = tid >> 6;
  int ln = tid & 63;
  const float* xb = xyz + (size_t)base * 3;
  float xi0 = xyz[p*3+0], xi1 = xyz[p*3+1], xi2 = xyz[p*3+2];
  float sqi = (xi0*xi0 + xi1*xi1) + xi2*xi2;

  unsigned long long cand[16];
#pragma unroll
  for (int u = 0; u < 16; ++u) {
    int j = tid + (u << 8);
    float a0 = xb[j*3+0], a1 = xb[j*3+1], a2 = xb[j*3+2];
    float sqj = (a0*a0 + a1*a1) + a2*a2;
    float dt  = (xi0*a0 + xi1*a1) + xi2*a2;
    float d2  = (sqi + sqj) - 2.0f*dt;
    cand[u] = ((unsigned long long)__float_as_uint(d2) << 32) | (unsigned int)j;
  }
  unsigned long long myloc;
  {
    unsigned long long t[8];
#pragma unroll
    for (int u = 0; u < 8; ++u) t[u] = u64min(cand[u], cand[u + 8]);
#pragma unroll
    for (int u = 0; u < 4; ++u) t[u] = u64min(t[u], t[u + 4]);
    t[0] = u64min(t[0], t[2]); t[1] = u64min(t[1], t[3]);
    myloc = u64min(t[0], t[1]);
  }
  unsigned long long wmreg = myloc;
#pragma unroll
  for (int off = 1; off < 64; off <<= 1) wmreg = u64min(wmreg, shflx64(wmreg, off));

  __shared__ __align__(16) unsigned long long wbuf[2][4];
  __shared__ int outbuf[20];
  if (ln == 0) wbuf[0][wv] = wmreg;
  __syncthreads();

  for (int r = 0; r < 20; ++r) {
    int cur = r & 1;
    unsigned long long w0 = wbuf[cur][0], w1 = wbuf[cur][1];
    unsigned long long w2 = wbuf[cur][2], w3 = wbuf[cur][3];
    unsigned long long g = u64min(u64min(w0, w1), u64min(w2, w3));
    int wj = (int)(unsigned int)(g & 0xffffffffu);
    if (tid == (wj & 255)) {
      outbuf[r] = base + wj;
      unsigned long long m = ~0ull;
#pragma unroll
      for (int u = 0; u < 16; ++u) {
        if (cand[u] == g) cand[u] = ~0ull;
        m = u64min(m, cand[u]);
      }
      myloc = m;
    }
    if (wv == ((wj >> 6) & 3)) {
      unsigned long long t = myloc;
#pragma unroll
      for (int off = 1; off < 64; off <<= 1) t = u64min(t, shflx64(t, off));
      wmreg = t;
    }
    if (ln == 0) wbuf[cur ^ 1][wv] = wmreg;
    __syncthreads();
  }
  if (tid < 20) idx[p*20 + tid] = outbuf[tid];
  if (tid < 3) out_xyz[p*3 + tid] = xyz[p*3 + tid];   // exact fp32 copy
}

// ============================================================
// K2: BN1 stats via 6-dim edge moments (affine trick).
// ============================================================
__global__ __launch_bounds__(256) void h1_moments_kernel(const float* __restrict__ xyz,
                                                         const int* __restrict__ idx,
                                                         float* __restrict__ mbuck) {
  int tid = threadIdx.x, blk = blockIdx.x;   // 320 blocks x 512 samples
  float A[33] = {};
#pragma unroll
  for (int u = 0; u < 2; ++u) {
    int s = blk*512 + (u << 8) + tid;
    unsigned int p = (unsigned int)s / 20u;
    int jg = idx[s];
    float c0 = xyz[p*3+0], c1 = xyz[p*3+1], c2 = xyz[p*3+2];
    float e[6];
    e[0] = xyz[jg*3+0] - c0; e[1] = xyz[jg*3+1] - c1; e[2] = xyz[jg*3+2] - c2;
    e[3] = c0; e[4] = c1; e[5] = c2;
    int k = 6;
#pragma unroll
    for (int d = 0; d < 6; ++d) {
      A[d] += e[d];
#pragma unroll
      for (int d2 = d; d2 < 6; ++d2) { A[k] = fmaf(e[d], e[d2], A[k]); ++k; }
    }
  }
#pragma unroll
  for (int off = 1; off < 64; off <<= 1) {
#pragma unroll
    for (int i = 0; i < 33; ++i) A[i] += __shfl_xor(A[i], off);
  }
  if ((tid & 63) == 0) {
    int b = ((blk << 2) | (tid >> 6)) & 15;
    for (int i = 0; i < 33; ++i) atomicAdd(&mbuck[b*64 + i], A[i]);
  }
}

__global__ void bn_prep1(const float* __restrict__ W1, const float* __restrict__ b1,
                         const float* __restrict__ g1, const float* __restrict__ be1,
                         const float* __restrict__ mbuck, float* __restrict__ misc) {
  __shared__ float red[33];
  int tid = threadIdx.x;  // 128
  if (tid < 33) {
    float s = 0.f;
    for (int b = 0; b < 16; ++b) s += mbuck[b*64 + tid];
    red[tid] = s;
  }
  __syncthreads();
  int c = tid;
  float w[6];
#pragma unroll
  for (int d = 0; d < 6; ++d) w[d] = W1[d*128 + c];
  const float inv = 1.0f / (float)NSAMP;
  float t = 0.f;
#pragma unroll
  for (int d = 0; d < 6; ++d) t = fmaf(w[d], red[d], t);
  t *= inv;
  float Q = 0.f;
  int k = 6;
#pragma unroll
  for (int d = 0; d < 6; ++d) {
#pragma unroll
    for (int d2 = d; d2 < 6; ++d2) {
      float coef = (d == d2) ? w[d]*w[d] : 2.f*w[d]*w[d2];
      Q = fmaf(coef, red[k], Q); ++k;
    }
  }
  Q *= inv;
  float var = Q - t*t;
  float mu = b1[c] + t;
  float a = g1[c] / sqrtf(var + 1e-5f);
  misc[c] = a;
  misc[128 + c] = be1[c] - mu*a;
}

// ============================================================
// K4: MFMA h2: per block of 4 points (M=80): edge -> h1 (BN1+ReLU, bf16
// into LDS A-tile) -> h2 = h1 @ W2T via MFMA (N=256, K=128) -> +b2 ->
// h2 bf16 store + fused per-point gmax.
// ============================================================
__global__ __launch_bounds__(256) void h2_kernel(const float* __restrict__ xyz,
                                                 const int* __restrict__ idx,
                                                 const float* __restrict__ W1,
                                                 const float* __restrict__ b1,
                                                 const unsigned short* __restrict__ W2T,
                                                 const float* __restrict__ b2,
                                                 const float* __restrict__ misc,
                                                 unsigned short* __restrict__ h2out,
                                                 unsigned short* __restrict__ gmaxout) {
  int p0 = blockIdx.x << 2;          // 4 points
  int tid = threadIdx.x;
  int w = tid >> 6, lane = tid & 63;
  int lr = lane & 15, lg = lane >> 4;
  __shared__ float e[80][6];
  __shared__ __align__(16) unsigned short As[80][136];
  __shared__ float pool[20][264];

  bf16x8 bfr[4][4];
#pragma unroll
  for (int j = 0; j < 4; ++j)
#pragma unroll
    for (int kk = 0; kk < 4; ++kk)
      bfr[j][kk] = *(const bf16x8*)(W2T + (size_t)(w*64 + j*16 + lr)*128 + kk*32 + lg*8);

  if (tid < 80) {
    int pl = (unsigned int)tid / 20u;
    int p = p0 + pl;
    int jg = idx[p0*20 + tid];
    float xi0 = xyz[p*3+0], xi1 = xyz[p*3+1], xi2 = xyz[p*3+2];
    e[tid][0] = xyz[jg*3+0] - xi0;
    e[tid][1] = xyz[jg*3+1] - xi1;
    e[tid][2] = xyz[jg*3+2] - xi2;
    e[tid][3] = xi0; e[tid][4] = xi1; e[tid][5] = xi2;
  }
  __syncthreads();

  {
    int c = tid & 127, half = tid >> 7;
    float w1v[6];
#pragma unroll
    for (int d = 0; d < 6; ++d) w1v[d] = W1[d*128 + c];
    float b1v = b1[c], a1 = misc[c], d1 = misc[128 + c];
#pragma unroll
    for (int u = 0; u < 40; ++u) {
      int row = (u << 1) | half;
      float v = b1v;
#pragma unroll
      for (int d = 0; d < 6; ++d) v = fmaf(e[row][d], w1v[d], v);
      v = fmaxf(fmaf(a1, v, d1), 0.f);
      As[row][c] = f2bf(v);
    }
  }
  __syncthreads();

  f32x4 acc[5][4] = {};
#pragma unroll
  for (int kk = 0; kk < 4; ++kk) {
    bf16x8 a[5];
#pragma unroll
    for (int i = 0; i < 5; ++i)
      a[i] = *(const bf16x8*)&As[i*16 + lr][kk*32 + lg*8];
#pragma unroll
    for (int i = 0; i < 5; ++i)
#pragma unroll
      for (int j = 0; j < 4; ++j)
        acc[i][j] = __builtin_amdgcn_mfma_f32_16x16x32_bf16(a[i], bfr[j][kk], acc[i][j], 0, 0, 0);
  }

  float b2v[4];
#pragma unroll
  for (int j = 0; j < 4; ++j) b2v[j] = b2[w*64 + j*16 + lr];
#pragma unroll
  for (int i = 0; i < 5; ++i) {
    int rbase = p0*20 + i*16 + lg*4;
#pragma unroll
    for (int j = 0; j < 4; ++j) {
      int col = w*64 + j*16 + lr;
      float v0 = acc[i][j][0] + b2v[j];
      float v1 = acc[i][j][1] + b2v[j];
      float v2 = acc[i][j][2] + b2v[j];
      float v3 = acc[i][j][3] + b2v[j];
      h2out[(size_t)(rbase+0)*256 + col] = f2bf(v0);
      h2out[(size_t)(rbase+1)*256 + col] = f2bf(v1);
      h2out[(size_t)(rbase+2)*256 + col] = f2bf(v2);
      h2out[(size_t)(rbase+3)*256 + col] = f2bf(v3);
      pool[i*4 + lg][col] = fmaxf(fmaxf(v0, v1), fmaxf(v2, v3));
    }
  }
  __syncthreads();
#pragma unroll
  for (int l = 0; l < 4; ++l) {
    int id = tid + (l << 8);        // 0..1023 : 4 points x 256 cols
    int q = id >> 8, col = id & 255;
    float v = pool[q*5][col];
#pragma unroll
    for (int u = 1; u < 5; ++u) v = fmaxf(v, pool[q*5 + u][col]);
    gmaxout[(size_t)(p0 + q)*256 + col] = f2bf(v);
  }
}

// ============================================================
// K5: MFMA GEMM: h3 = [gmax | h2] @ W3 + b3 (163840x512x512), bf16 MFMA.
// R13: FACTORED gmax-half. gmax@W3[0:256] was computed 20x redundantly
// (all 20 rows of a point share gmax). Per block: Phase 1 computes
// P = gmax[pbase..pbase+7] @ W3a for this n-tile (16 MFMAs/wave, fp32 in
// LDS); Phase 2 runs K=256..511 with h2-only A (no /20 in hot path);
// epilogue adds P[row/20-pbase][col] + b3. Per-wave MFMA 256 -> 144.
// BK=64 + XOR k-chunk swizzle (R12, conflicts=0) retained.
// Note: P A-tile reads gmax rows pbase..pbase+15; rows 8-15 are garbage
// but D-rows are independent and reads stay inside ws (h2 follows gmax).
// ============================================================
__global__ __launch_bounds__(256) void gemm3_kernel(const unsigned short* __restrict__ h2,
                                                    const unsigned short* __restrict__ gmax,
                                                    const unsigned short* __restrict__ W3T,
                                                    const float* __restrict__ b3,
                                                    unsigned short* __restrict__ h3,
                                                    float* __restrict__ s3buck) {
  int bid = blockIdx.x;               // 1280 m * 4 n
  int bn = bid & 3, bm = bid >> 2;
  int m0 = bm << 7, n0 = bn << 7;
  unsigned int pbase = (unsigned int)m0 / 20u;
  int tid = threadIdx.x;
  int lane = tid & 63, w = tid >> 6;
  int mw = w >> 1, nw = w & 1;
  int lr = lane & 15, lg = lane >> 4;
  __shared__ __align__(16) unsigned short As[128][64];
  __shared__ __align__(16) unsigned short Bs[128][64];
  __shared__ float Plds[8][132];
  __shared__ float ssum[128], ssq[128];

  // staging coords: id = tid + l*256; row=id>>3, kgs=id&7,
  // source kg = kgs ^ ((row>>1)&7) = kgs ^ ((id>>4)&7)
  int rS[4], kgS[4], ksS[4];
#pragma unroll
  for (int l = 0; l < 4; ++l) {
    int id = tid + (l << 8);
    rS[l] = id >> 3;
    ksS[l] = id & 7;
    kgS[l] = ksS[l] ^ ((id >> 4) & 7);
  }
  int swz = lr >> 1;

  // ---- Phase 1: P = gmax(16 rows, 8 valid) @ W3a, cols n0..n0+127 ----
  f32x4 accP[2] = {};
  int par = tid >> 3, paks = tid & 7;           // tid<128: 16 rows x 8 chunks
  int pakg = paks ^ ((tid >> 4) & 7);
  for (int kc = 0; kc < 256; kc += 64) {
    if (tid < 128)
      gl_lds16(gmax + (size_t)(pbase + par)*256 + kc + (pakg << 3), &As[par][paks << 3]);
#pragma unroll
    for (int l = 0; l < 4; ++l)
      gl_lds16(W3T + (size_t)(n0 + rS[l])*512 + kc + (kgS[l] << 3), &Bs[rS[l]][ksS[l] << 3]);
    __syncthreads();
#pragma unroll
    for (int h = 0; h < 2; ++h) {
      int ch = ((h << 2) | lg) ^ swz;
      bf16x8 a = *(const bf16x8*)&As[lr][ch << 3];
#pragma unroll
      for (int j2 = 0; j2 < 2; ++j2) {
        bf16x8 b = *(const bf16x8*)&Bs[w*32 + j2*16 + lr][ch << 3];
        accP[j2] = __builtin_amdgcn_mfma_f32_16x16x32_bf16(a, b, accP[j2], 0, 0, 0);
      }
    }
    __syncthreads();
  }
  if (lg < 2) {                                  // rows 0..7 valid
#pragma unroll
    for (int j2 = 0; j2 < 2; ++j2)
#pragma unroll
      for (int r = 0; r < 4; ++r)
        Plds[lg*4 + r][w*32 + j2*16 + lr] = accP[j2][r];
  }

  // ---- Phase 2: h3-partial = h2 @ W3b (K = 256..511) ----
  f32x4 acc[4][4] = {};
  for (int kc = 0; kc < 256; kc += 64) {
#pragma unroll
    for (int l = 0; l < 4; ++l)
      gl_lds16(h2 + (size_t)(m0 + rS[l])*256 + kc + (kgS[l] << 3), &As[rS[l]][ksS[l] << 3]);
#pragma unroll
    for (int l = 0; l < 4; ++l)
      gl_lds16(W3T + (size_t)(n0 + rS[l])*512 + (kc + 256) + (kgS[l] << 3), &Bs[rS[l]][ksS[l] << 3]);
    __syncthreads();
#pragma unroll
    for (int h = 0; h < 2; ++h) {
      int ch = ((h << 2) | lg) ^ swz;
      bf16x8 a[4], b[4];
#pragma unroll
      for (int t = 0; t < 4; ++t)
        a[t] = *(const bf16x8*)&As[mw*64 + t*16 + lr][ch << 3];
#pragma unroll
      for (int t = 0; t < 4; ++t)
        b[t] = *(const bf16x8*)&Bs[nw*64 + t*16 + lr][ch << 3];
#pragma unroll
      for (int i = 0; i < 4; ++i)
#pragma unroll
        for (int j = 0; j < 4; ++j)
          acc[i][j] = __builtin_amdgcn_mfma_f32_16x16x32_bf16(a[i], b[j], acc[i][j], 0, 0, 0);
    }
    __syncthreads();
  }

  // epilogue: v = acc + b3[col] + P[row/20 - pbase][colL]; bf16 store; stats
  if (tid < 128) { ssum[tid] = 0.f; ssq[tid] = 0.f; }
  __syncthreads();
  unsigned int prow[4][4];
#pragma unroll
  for (int i = 0; i < 4; ++i) {
    int rbase = m0 + mw*64 + i*16 + lg*4;
#pragma unroll
    for (int r = 0; r < 4; ++r)
      prow[i][r] = (unsigned int)(rbase + r) / 20u - pbase;
  }
#pragma unroll
  for (int j = 0; j < 4; ++j) {
    int colL = nw*64 + j*16 + lr;
    int col = n0 + colL;
    float b3v = b3[col];
    float sumv = 0.f, sqv = 0.f;
#pragma unroll
    for (int i = 0; i < 4; ++i) {
      int rbase = m0 + mw*64 + i*16 + lg*4;
#pragma unroll
      for (int r = 0; r < 4; ++r) {
        float v = acc[i][j][r] + b3v + Plds[prow[i][r]][colL];
        h3[(size_t)(rbase + r)*512 + col] = f2bf(v);
        sumv += v; sqv = fmaf(v, v, sqv);
      }
    }
    sumv += __shfl_xor(sumv, 16); sumv += __shfl_xor(sumv, 32);
    sqv  += __shfl_xor(sqv, 16);  sqv  += __shfl_xor(sqv, 32);
    if (lg == 0) {
      atomicAdd(&ssum[colL], sumv);
      atomicAdd(&ssq[colL], sqv);
    }
  }
  __syncthreads();
  if (tid < 128) {
    int bkt = (bid & 63) * 1024;
    atomicAdd(&s3buck[bkt + n0 + tid], ssum[tid]);
    atomicAdd(&s3buck[bkt + 512 + n0 + tid], ssq[tid]);
  }
}

__global__ void bn_prep3(const float* __restrict__ g3, const float* __restrict__ be3,
                         const float* __restrict__ s3buck, float* __restrict__ misc) {
  int c = threadIdx.x;  // 512
  float s = 0.f, q = 0.f;
  for (int b = 0; b < 64; ++b) { s += s3buck[b*1024 + c]; q += s3buck[b*1024 + 512 + c]; }
  const float inv = 1.0f / (float)NSAMP;
  float mu = s * inv;
  float var = q * inv - mu * mu;
  float a = g3[c] / sqrtf(var + 1e-5f);
  misc[256 + c] = a;
  misc[768 + c] = be3[c] - mu * a;
}

// ============================================================
// K7: MFMA GEMM: h4 = relu(a3*h3+d3) @ W4 (+b4), fused max-pool over K=20.
// 512 thr / 8 waves; Bs XOR swizzle; As stride-40 pad; A reg-prefetch +
// dequant; B global_load_lds. Pool aliases staging LDS.
// ============================================================
__global__ __launch_bounds__(512) void gemm4_kernel(const unsigned short* __restrict__ h3,
                                                    const unsigned short* __restrict__ W4T,
                                                    const float* __restrict__ b4,
                                                    const float* __restrict__ misc,
                                                    float* __restrict__ outf) {
  int bm = blockIdx.x;              // 2048 blocks: 4 points each
  int m0 = bm * 80;
  int tid = threadIdx.x;
  int lane = tid & 63, w = tid >> 6;     // w = column wave 0..7
  int lr = lane & 15, lg = lane >> 4;
  __shared__ __align__(16) char smem[35072];
  unsigned short (*As)[40] = (unsigned short (*)[40])smem;            // 80*80  = 6400 B (padded)
  unsigned short (*Bs)[32] = (unsigned short (*)[32])(smem + 6400);   // 384*64 = 24576 B
  float (*pool)[392] = (float (*)[392])smem;                          // 31360 B (alias)
  float* af = (float*)(smem + 30976);                                 // 512 f32
  float* df = af + 512;                                               // 512 f32  -> ends 35072
  if (tid < 512) {
    af[tid] = misc[256 + tid];
    df[tid] = misc[768 + tid];
  }
  __syncthreads();
  f32x4 acc[5][3] = {};

  // A prefetch: 320 uint4 over 512 threads (tid < 320)
  uint4 aR;
  int arow = tid >> 2, akg = tid & 3;
  if (tid < 320)
    aR = *(const uint4*)(h3 + (size_t)(m0 + arow)*512 + (akg << 3));
  int swz4 = (lr >> 1) & 3;

  for (int kc = 0; kc < 512; kc += 32) {
    // --- stage B: async global->LDS with XOR swizzle, 3 rounds ---
#pragma unroll
    for (int l = 0; l < 3; ++l) {
      int id = tid + (l << 9);
      int row = id >> 2, kgs = id & 3;
      int kg = kgs ^ ((row >> 1) & 3);
      gl_lds16(W4T + (size_t)row*512 + kc + (kg << 3), &Bs[row][kgs << 3]);
    }
    // --- stage A: dequant BN3 affine + relu, repack bf16 ---
    if (tid < 320) {
      int kb = kc + (akg << 3);
      unsigned int o[4];
#pragma unroll
      for (int q = 0; q < 4; ++q) {
        unsigned int u = ((const unsigned int*)&aR)[q];
        float lo = bf2f((unsigned short)(u & 0xffffu));
        float hi = bf2f((unsigned short)(u >> 16));
        int k0 = kb + q*2;
        lo = fmaxf(fmaf(af[k0],   lo, df[k0]),   0.f);
        hi = fmaxf(fmaf(af[k0+1], hi, df[k0+1]), 0.f);
        o[q] = (unsigned int)f2bf(lo) | ((unsigned int)f2bf(hi) << 16);
      }
      *(uint4*)&As[arow][akg << 3] = *(const uint4*)o;
    }
    __syncthreads();
    // --- prefetch next A ---
    int kn = kc + 32;
    if (kn < 512 && tid < 320)
      aR = *(const uint4*)(h3 + (size_t)(m0 + arow)*512 + kn + (akg << 3));
    // --- fragments + MFMA ---
    bf16x8 a[5], b[3];
#pragma unroll
    for (int t = 0; t < 5; ++t)
      a[t] = *(const bf16x8*)&As[t*16 + lr][lg << 3];
#pragma unroll
    for (int t = 0; t < 3; ++t)
      b[t] = *(const bf16x8*)&Bs[w*48 + t*16 + lr][(lg ^ swz4) << 3];
#pragma unroll
    for (int i = 0; i < 5; ++i)
#pragma unroll
      for (int j = 0; j < 3; ++j)
        acc[i][j] = __builtin_amdgcn_mfma_f32_16x16x32_bf16(a[i], b[j], acc[i][j], 0, 0, 0);
    __syncthreads();
  }

  // fused max-pool: per-lane reg-max (4 rows, point-pure since 4|20)
#pragma unroll
  for (int i = 0; i < 5; ++i)
#pragma unroll
    for (int j = 0; j < 3; ++j) {
      float m = fmaxf(fmaxf(acc[i][j][0], acc[i][j][1]),
                      fmaxf(acc[i][j][2], acc[i][j][3]));
      pool[i*4 + lg][w*48 + j*16 + lr] = m;
    }
  __syncthreads();
#pragma unroll
  for (int l = 0; l < 3; ++l) {
    int id = tid + (l << 9);            // 0..1535 : 4 points x 384 cols
    int q = id / 384, c = id - q*384;
    float v = pool[q*5][c];
#pragma unroll
    for (int u = 1; u < 5; ++u) v = fmaxf(v, pool[q*5 + u][c]);
    outf[(size_t)(bm*4 + q)*384 + c] = v + b4[c];
  }
}

// ============================================================
// Workspace layout:
//   0x0000000  idx        640 KB
//   0x00A0000  misc       1280 f32
//   0x00A2000  mbuck      16*64 f32 = 4 KB (zeroed)
//   0x00AA000  s3buck     256 KB  (zeroed)
//   0x00F0000  W3T bf16   512 KB
//   0x0170000  W4T bf16   384 KB
//   0x01D0000  W2T bf16   64 KB
//   0x0200000  gmax bf16  4 MB
//   0x0600000  h2   bf16  80 MB
//   0x5600000  h3   bf16  160 MB  -> end 0xF600000
// ============================================================
extern "C" void kernel_launch(void* const* d_in, const int* in_sizes, int n_in,
                              void* d_out, int out_size, void* d_ws, size_t ws_size,
                              hipStream_t stream) {
  const float* xyz = (const float*)d_in[0];
  const float* W1  = (const float*)d_in[1];
  const float* b1  = (const float*)d_in[2];
  const float* g1  = (const float*)d_in[3];
  const float* be1 = (const float*)d_in[4];
  const float* W2  = (const float*)d_in[5];
  const float* b2  = (const float*)d_in[6];
  const float* W3  = (const float*)d_in[7];
  const float* b3  = (const float*)d_in[8];
  const float* g3  = (const float*)d_in[9];
  const float* be3 = (const float*)d_in[10];
  const float* W4  = (const float*)d_in[11];
  const float* b4  = (const float*)d_in[12];

  char* ws = (char*)d_ws;
  int*            idx    = (int*)ws;
  float*          misc   = (float*)(ws + 0xA0000);
  float*          mbuck  = (float*)(ws + 0xA2000);
  float*          s3buck = (float*)(ws + 0xAA000);
  unsigned short* W3T    = (unsigned short*)(ws + 0xF0000);
  unsigned short* W4T    = (unsigned short*)(ws + 0x170000);
  unsigned short* W2T    = (unsigned short*)(ws + 0x1D0000);
  unsigned short* gmax   = (unsigned short*)(ws + 0x200000);
  unsigned short* h2     = (unsigned short*)(ws + 0x600000);
  unsigned short* h3     = (unsigned short*)(ws + 0x5600000ULL);

  float* ofp   = (float*)d_out;
  float* oxyz  = ofp;             // 24576 fp32
  float* ofeat = ofp + 24576;     // 8192*384 fp32

  hipMemsetAsync(ws + 0xA2000, 0, 0x48000, stream);   // zero mbuck + s3buck

  wprep_kernel<<<(512*512 + 384*512 + 256*128)/256, 256, 0, stream>>>(W3, W4, W2, W3T, W4T, W2T);
  knn_kernel<<<NPTS, 256, 0, stream>>>(xyz, idx, oxyz);
  h1_moments_kernel<<<NSAMP/512, 256, 0, stream>>>(xyz, idx, mbuck);
  bn_prep1<<<1, 128, 0, stream>>>(W1, b1, g1, be1, mbuck, misc);
  h2_kernel<<<NPTS/4, 256, 0, stream>>>(xyz, idx, W1, b1, W2T, b2, misc, h2, gmax);
  gemm3_kernel<<<(NSAMP/128)*4, 256, 0, stream>>>(h2, gmax, W3T, b3, h3, s3buck);
  bn_prep3<<<1, 512, 0, stream>>>(g3, be3, s3buck, misc);
  gemm4_kernel<<<NPTS/4, 512, 0, stream>>>(h3, W4T, b4, misc, ofeat);
}

// Round 14
// 418.746 us; speedup vs baseline: 1.8861x; 1.0557x over previous
//
#include <hip/hip_runtime.h>
#include <float.h>

// Problem constants: B=2, N=4096, K=20, H=384
// Inputs: fp32 arrays (values bf16-quantized by harness). Output: fp32.
#define NPTS_B 4096
#define NPTS 8192            // B*N
#define KNN 20
#define NSAMP (NPTS*KNN)     // 163840

typedef __attribute__((ext_vector_type(8))) short bf16x8;
typedef __attribute__((ext_vector_type(4))) float f32x4;

// -------- bf16 helpers (internal staging only) --------
static __device__ __forceinline__ float bf2f(unsigned short u) {
  return __uint_as_float(((unsigned int)u) << 16);
}
static __device__ __forceinline__ unsigned short f2bf(float f) {
  unsigned int u = __float_as_uint(f);
  u += 0x7fffu + ((u >> 16) & 1u);
  return (unsigned short)(u >> 16);
}
static __device__ __forceinline__ unsigned long long u64min(unsigned long long a,
                                                           unsigned long long b) {
  return a < b ? a : b;
}
static __device__ __forceinline__ unsigned long long shflx64(unsigned long long v, int m) {
  int lo = __shfl_xor((int)(unsigned int)(v & 0xffffffffull), m);
  int hi = __shfl_xor((int)(unsigned int)(v >> 32), m);
  return ((unsigned long long)(unsigned int)hi << 32) | (unsigned int)lo;
}
// async global->LDS 16B: wave-uniform LDS base + lane*16.
static __device__ __forceinline__ void gl_lds16(const void* g, void* l) {
  __builtin_amdgcn_global_load_lds(
      (const __attribute__((address_space(1))) unsigned int*)g,
      (__attribute__((address_space(3))) unsigned int*)l, 16, 0, 0);
}

// ============================================================
// K0: weight prep — W3 -> W3T bf16 [n][k]; W4 -> W4T bf16 [n][k];
// W2 (128x256) -> W2T bf16 [n=256][k=128]. All values bf16-grid -> EXACT.
// ============================================================
__global__ __launch_bounds__(256) void wprep_kernel(const float* __restrict__ W3,
                                                    const float* __restrict__ W4,
                                                    const float* __restrict__ W2,
                                                    unsigned short* __restrict__ W3T,
                                                    unsigned short* __restrict__ W4T,
                                                    unsigned short* __restrict__ W2T) {
  int id = blockIdx.x * 256 + threadIdx.x;
  if (id < 512*512) {
    int n = id >> 9, k = id & 511;
    W3T[id] = f2bf(W3[k*512 + n]);
  } else if (id < 512*512 + 384*512) {
    int id2 = id - 512*512;
    int n = id2 >> 9, k = id2 & 511;
    W4T[id2] = f2bf(W4[k*384 + n]);
  } else {
    int id2 = id - (512*512 + 384*512);   // < 256*128
    int n = id2 >> 7, k = id2 & 127;
    W2T[id2] = f2bf(W2[k*256 + n]);
  }
}

// ============================================================
// K1: KNN (one block per point). u64-packed (d2_bits<<32|j) extract-min,
// incremental cached minima, one barrier per round.
// ============================================================
__global__ __launch_bounds__(256) void knn_kernel(const float* __restrict__ xyz,
                                                  int* __restrict__ idx,
                                                  float* __restrict__ out_xyz) {
#pragma clang fp contract(off)
  int p = blockIdx.x;            // 0..8191
  int base = p & ~4095;          // batch base row
  int tid = threadIdx.x;
  int wv = tid >> 6;
  int ln = tid & 63;
  const float* xb = xyz + (size_t)base * 3;
  float xi0 = xyz[p*3+0], xi1 = xyz[p*3+1], xi2 = xyz[p*3+2];
  float sqi = (xi0*xi0 + xi1*xi1) + xi2*xi2;

  unsigned long long cand[16];
#pragma unroll
  for (int u = 0; u < 16; ++u) {
    int j = tid + (u << 8);
    float a0 = xb[j*3+0], a1 = xb[j*3+1], a2 = xb[j*3+2];
    float sqj = (a0*a0 + a1*a1) + a2*a2;
    float dt  = (xi0*a0 + xi1*a1) + xi2*a2;
    float d2  = (sqi + sqj) - 2.0f*dt;
    cand[u] = ((unsigned long long)__float_as_uint(d2) << 32) | (unsigned int)j;
  }
  unsigned long long myloc;
  {
    unsigned long long t[8];
#pragma unroll
    for (int u = 0; u < 8; ++u) t[u] = u64min(cand[u], cand[u + 8]);
#pragma unroll
    for (int u = 0; u < 4; ++u) t[u] = u64min(t[u], t[u + 4]);
    t[0] = u64min(t[0], t[2]); t[1] = u64min(t[1], t[3]);
    myloc = u64min(t[0], t[1]);
  }
  unsigned long long wmreg = myloc;
#pragma unroll
  for (int off = 1; off < 64; off <<= 1) wmreg = u64min(wmreg, shflx64(wmreg, off));

  __shared__ __align__(16) unsigned long long wbuf[2][4];
  __shared__ int outbuf[20];
  if (ln == 0) wbuf[0][wv] = wmreg;
  __syncthreads();

  for (int r = 0; r < 20; ++r) {
    int cur = r & 1;
    unsigned long long w0 = wbuf[cur][0], w1 = wbuf[cur][1];
    unsigned long long w2 = wbuf[cur][2], w3 = wbuf[cur][3];
    unsigned long long g = u64min(u64min(w0, w1), u64min(w2, w3));
    int wj = (int)(unsigned int)(g & 0xffffffffu);
    if (tid == (wj & 255)) {
      outbuf[r] = base + wj;
      unsigned long long m = ~0ull;
#pragma unroll
      for (int u = 0; u < 16; ++u) {
        if (cand[u] == g) cand[u] = ~0ull;
        m = u64min(m, cand[u]);
      }
      myloc = m;
    }
    if (wv == ((wj >> 6) & 3)) {
      unsigned long long t = myloc;
#pragma unroll
      for (int off = 1; off < 64; off <<= 1) t = u64min(t, shflx64(t, off));
      wmreg = t;
    }
    if (ln == 0) wbuf[cur ^ 1][wv] = wmreg;
    __syncthreads();
  }
  if (tid < 20) idx[p*20 + tid] = outbuf[tid];
  if (tid < 3) out_xyz[p*3 + tid] = xyz[p*3 + tid];   // exact fp32 copy
}

// ============================================================
// K2: BN1 stats via 6-dim edge moments (affine trick).
// ============================================================
__global__ __launch_bounds__(256) void h1_moments_kernel(const float* __restrict__ xyz,
                                                         const int* __restrict__ idx,
                                                         float* __restrict__ mbuck) {
  int tid = threadIdx.x, blk = blockIdx.x;   // 320 blocks x 512 samples
  float A[33] = {};
#pragma unroll
  for (int u = 0; u < 2; ++u) {
    int s = blk*512 + (u << 8) + tid;
    unsigned int p = (unsigned int)s / 20u;
    int jg = idx[s];
    float c0 = xyz[p*3+0], c1 = xyz[p*3+1], c2 = xyz[p*3+2];
    float e[6];
    e[0] = xyz[jg*3+0] - c0; e[1] = xyz[jg*3+1] - c1; e[2] = xyz[jg*3+2] - c2;
    e[3] = c0; e[4] = c1; e[5] = c2;
    int k = 6;
#pragma unroll
    for (int d = 0; d < 6; ++d) {
      A[d] += e[d];
#pragma unroll
      for (int d2 = d; d2 < 6; ++d2) { A[k] = fmaf(e[d], e[d2], A[k]); ++k; }
    }
  }
#pragma unroll
  for (int off = 1; off < 64; off <<= 1) {
#pragma unroll
    for (int i = 0; i < 33; ++i) A[i] += __shfl_xor(A[i], off);
  }
  if ((tid & 63) == 0) {
    int b = ((blk << 2) | (tid >> 6)) & 15;
    for (int i = 0; i < 33; ++i) atomicAdd(&mbuck[b*64 + i], A[i]);
  }
}

__global__ void bn_prep1(const float* __restrict__ W1, const float* __restrict__ b1,
                         const float* __restrict__ g1, const float* __restrict__ be1,
                         const float* __restrict__ mbuck, float* __restrict__ misc) {
  __shared__ float red[33];
  int tid = threadIdx.x;  // 128
  if (tid < 33) {
    float s = 0.f;
    for (int b = 0; b < 16; ++b) s += mbuck[b*64 + tid];
    red[tid] = s;
  }
  __syncthreads();
  int c = tid;
  float w[6];
#pragma unroll
  for (int d = 0; d < 6; ++d) w[d] = W1[d*128 + c];
  const float inv = 1.0f / (float)NSAMP;
  float t = 0.f;
#pragma unroll
  for (int d = 0; d < 6; ++d) t = fmaf(w[d], red[d], t);
  t *= inv;
  float Q = 0.f;
  int k = 6;
#pragma unroll
  for (int d = 0; d < 6; ++d) {
#pragma unroll
    for (int d2 = d; d2 < 6; ++d2) {
      float coef = (d == d2) ? w[d]*w[d] : 2.f*w[d]*w[d2];
      Q = fmaf(coef, red[k], Q); ++k;
    }
  }
  Q *= inv;
  float var = Q - t*t;
  float mu = b1[c] + t;
  float a = g1[c] / sqrtf(var + 1e-5f);
  misc[c] = a;
  misc[128 + c] = be1[c] - mu*a;
}

// ============================================================
// K4: MFMA h2: per block of 4 points (M=80): edge -> h1 (BN1+ReLU, bf16
// into LDS A-tile) -> h2 = h1 @ W2T via MFMA (N=256, K=128) -> +b2 ->
// h2 bf16 store + fused per-point gmax.
// ============================================================
__global__ __launch_bounds__(256) void h2_kernel(const float* __restrict__ xyz,
                                                 const int* __restrict__ idx,
                                                 const float* __restrict__ W1,
                                                 const float* __restrict__ b1,
                                                 const unsigned short* __restrict__ W2T,
                                                 const float* __restrict__ b2,
                                                 const float* __restrict__ misc,
                                                 unsigned short* __restrict__ h2out,
                                                 unsigned short* __restrict__ gmaxout) {
  int p0 = blockIdx.x << 2;          // 4 points
  int tid = threadIdx.x;
  int w = tid >> 6, lane = tid & 63;
  int lr = lane & 15, lg = lane >> 4;
  __shared__ float e[80][6];
  __shared__ __align__(16) unsigned short As[80][136];
  __shared__ float pool[20][264];

  bf16x8 bfr[4][4];
#pragma unroll
  for (int j = 0; j < 4; ++j)
#pragma unroll
    for (int kk = 0; kk < 4; ++kk)
      bfr[j][kk] = *(const bf16x8*)(W2T + (size_t)(w*64 + j*16 + lr)*128 + kk*32 + lg*8);

  if (tid < 80) {
    int pl = (unsigned int)tid / 20u;
    int p = p0 + pl;
    int jg = idx[p0*20 + tid];
    float xi0 = xyz[p*3+0], xi1 = xyz[p*3+1], xi2 = xyz[p*3+2];
    e[tid][0] = xyz[jg*3+0] - xi0;
    e[tid][1] = xyz[jg*3+1] - xi1;
    e[tid][2] = xyz[jg*3+2] - xi2;
    e[tid][3] = xi0; e[tid][4] = xi1; e[tid][5] = xi2;
  }
  __syncthreads();

  {
    int c = tid & 127, half = tid >> 7;
    float w1v[6];
#pragma unroll
    for (int d = 0; d < 6; ++d) w1v[d] = W1[d*128 + c];
    float b1v = b1[c], a1 = misc[c], d1 = misc[128 + c];
#pragma unroll
    for (int u = 0; u < 40; ++u) {
      int row = (u << 1) | half;
      float v = b1v;
#pragma unroll
      for (int d = 0; d < 6; ++d) v = fmaf(e[row][d], w1v[d], v);
      v = fmaxf(fmaf(a1, v, d1), 0.f);
      As[row][c] = f2bf(v);
    }
  }
  __syncthreads();

  f32x4 acc[5][4] = {};
#pragma unroll
  for (int kk = 0; kk < 4; ++kk) {
    bf16x8 a[5];
#pragma unroll
    for (int i = 0; i < 5; ++i)
      a[i] = *(const bf16x8*)&As[i*16 + lr][kk*32 + lg*8];
#pragma unroll
    for (int i = 0; i < 5; ++i)
#pragma unroll
      for (int j = 0; j < 4; ++j)
        acc[i][j] = __builtin_amdgcn_mfma_f32_16x16x32_bf16(a[i], bfr[j][kk], acc[i][j], 0, 0, 0);
  }

  float b2v[4];
#pragma unroll
  for (int j = 0; j < 4; ++j) b2v[j] = b2[w*64 + j*16 + lr];
#pragma unroll
  for (int i = 0; i < 5; ++i) {
    int rbase = p0*20 + i*16 + lg*4;
#pragma unroll
    for (int j = 0; j < 4; ++j) {
      int col = w*64 + j*16 + lr;
      float v0 = acc[i][j][0] + b2v[j];
      float v1 = acc[i][j][1] + b2v[j];
      float v2 = acc[i][j][2] + b2v[j];
      float v3 = acc[i][j][3] + b2v[j];
      h2out[(size_t)(rbase+0)*256 + col] = f2bf(v0);
      h2out[(size_t)(rbase+1)*256 + col] = f2bf(v1);
      h2out[(size_t)(rbase+2)*256 + col] = f2bf(v2);
      h2out[(size_t)(rbase+3)*256 + col] = f2bf(v3);
      pool[i*4 + lg][col] = fmaxf(fmaxf(v0, v1), fmaxf(v2, v3));
    }
  }
  __syncthreads();
#pragma unroll
  for (int l = 0; l < 4; ++l) {
    int id = tid + (l << 8);        // 0..1023 : 4 points x 256 cols
    int q = id >> 8, col = id & 255;
    float v = pool[q*5][col];
#pragma unroll
    for (int u = 1; u < 5; ++u) v = fmaxf(v, pool[q*5 + u][col]);
    gmaxout[(size_t)(p0 + q)*256 + col] = f2bf(v);
  }
}

// ============================================================
// K5: MFMA GEMM: h3 = [gmax | h2] @ W3 + b3 (163840x512x512), bf16 MFMA.
// R14: 512 threads / 8 waves (2m x 4n), N=256 per block (2 siblings
// instead of 4 -> halves h2 A-refetch), XCD pairing (siblings 8 apart in
// blockIdx -> same XCD L2). Factored gmax P-phase (R13) + BK=64 XOR
// swizzle (R12) retained. LDS 58 KB -> 2 blocks/CU (barrier overlap).
// ============================================================
__global__ __launch_bounds__(512) void gemm3_kernel(const unsigned short* __restrict__ h2,
                                                    const unsigned short* __restrict__ gmax,
                                                    const unsigned short* __restrict__ W3T,
                                                    const float* __restrict__ b3,
                                                    unsigned short* __restrict__ h3,
                                                    float* __restrict__ s3buck) {
  int bid = blockIdx.x;               // 2560 = 160 grp * (2 bn * 8 x)
  int grp = bid >> 4, rem = bid & 15;
  int bn = rem >> 3;                  // 0..1
  int bm = (grp << 3) | (rem & 7);    // 0..1279
  int m0 = bm << 7, n0 = bn << 8;
  unsigned int pbase = (unsigned int)m0 / 20u;
  int tid = threadIdx.x;
  int lane = tid & 63, w = tid >> 6;  // 8 waves
  int mw = w >> 2, nw = w & 3;        // 2m x 4n
  int lr = lane & 15, lg = lane >> 4;
  __shared__ __align__(16) unsigned short As[128][64];   // 16 KB
  __shared__ __align__(16) unsigned short Bs[256][64];   // 32 KB
  __shared__ float Plds[8][260];                         // 8.3 KB
  __shared__ float ssum[256], ssq[256];                  // 2 KB

  // staging coords: id = tid + l*512; row=id>>3, kgs=id&7,
  // source kg = kgs ^ ((row>>1)&7) = kgs ^ ((id>>4)&7)
  int rS[4], kgS[4], ksS[4];
#pragma unroll
  for (int l = 0; l < 4; ++l) {
    int id = tid + (l << 9);
    rS[l] = id >> 3;
    ksS[l] = id & 7;
    kgS[l] = ksS[l] ^ ((id >> 4) & 7);
  }
  int swz = lr >> 1;

  // ---- Phase 1: P = gmax(16 rows, 8 valid) @ W3a, cols n0..n0+255 ----
  f32x4 accP[4] = {};
  int par = tid >> 3, paks = tid & 7;           // tid<128: 16 rows x 8 chunks
  int pakg = paks ^ ((tid >> 4) & 7);
  for (int kc = 0; kc < 256; kc += 64) {
    if (tid < 128)
      gl_lds16(gmax + (size_t)(pbase + par)*256 + kc + (pakg << 3), &As[par][paks << 3]);
#pragma unroll
    for (int l = 0; l < 4; ++l)
      gl_lds16(W3T + (size_t)(n0 + rS[l])*512 + kc + (kgS[l] << 3), &Bs[rS[l]][ksS[l] << 3]);
    __syncthreads();
#pragma unroll
    for (int h = 0; h < 2; ++h) {
      int ch = ((h << 2) | lg) ^ swz;
      bf16x8 a = *(const bf16x8*)&As[lr][ch << 3];
#pragma unroll
      for (int j = 0; j < 4; ++j) {
        bf16x8 b = *(const bf16x8*)&Bs[nw*64 + j*16 + lr][ch << 3];
        accP[j] = __builtin_amdgcn_mfma_f32_16x16x32_bf16(a, b, accP[j], 0, 0, 0);
      }
    }
    __syncthreads();
  }
  if (mw == 0 && lg < 2) {                       // rows 0..7 valid
#pragma unroll
    for (int j = 0; j < 4; ++j)
#pragma unroll
      for (int r = 0; r < 4; ++r)
        Plds[lg*4 + r][nw*64 + j*16 + lr] = accP[j][r];
  }

  // ---- Phase 2: h3-partial = h2 @ W3b (K = 256..511) ----
  f32x4 acc[4][4] = {};
  for (int kc = 0; kc < 256; kc += 64) {
#pragma unroll
    for (int l = 0; l < 2; ++l)
      gl_lds16(h2 + (size_t)(m0 + rS[l])*256 + kc + (kgS[l] << 3), &As[rS[l]][ksS[l] << 3]);
#pragma unroll
    for (int l = 0; l < 4; ++l)
      gl_lds16(W3T + (size_t)(n0 + rS[l])*512 + (kc + 256) + (kgS[l] << 3), &Bs[rS[l]][ksS[l] << 3]);
    __syncthreads();
#pragma unroll
    for (int h = 0; h < 2; ++h) {
      int ch = ((h << 2) | lg) ^ swz;
      bf16x8 a[4], b[4];
#pragma unroll
      for (int t = 0; t < 4; ++t)
        a[t] = *(const bf16x8*)&As[mw*64 + t*16 + lr][ch << 3];
#pragma unroll
      for (int t = 0; t < 4; ++t)
        b[t] = *(const bf16x8*)&Bs[nw*64 + t*16 + lr][ch << 3];
#pragma unroll
      for (int i = 0; i < 4; ++i)
#pragma unroll
        for (int j = 0; j < 4; ++j)
          acc[i][j] = __builtin_amdgcn_mfma_f32_16x16x32_bf16(a[i], b[j], acc[i][j], 0, 0, 0);
    }
    __syncthreads();
  }

  // epilogue: v = acc + b3[col] + P[row/20 - pbase][colL]; bf16 store; stats
  if (tid < 256) { ssum[tid] = 0.f; ssq[tid] = 0.f; }
  __syncthreads();
  unsigned int prow[4][4];
#pragma unroll
  for (int i = 0; i < 4; ++i) {
    int rbase = m0 + mw*64 + i*16 + lg*4;
#pragma unroll
    for (int r = 0; r < 4; ++r)
      prow[i][r] = (unsigned int)(rbase + r) / 20u - pbase;
  }
#pragma unroll
  for (int j = 0; j < 4; ++j) {
    int colL = nw*64 + j*16 + lr;
    int col = n0 + colL;
    float b3v = b3[col];
    float sumv = 0.f, sqv = 0.f;
#pragma unroll
    for (int i = 0; i < 4; ++i) {
      int rbase = m0 + mw*64 + i*16 + lg*4;
#pragma unroll
      for (int r = 0; r < 4; ++r) {
        float v = acc[i][j][r] + b3v + Plds[prow[i][r]][colL];
        h3[(size_t)(rbase + r)*512 + col] = f2bf(v);
        sumv += v; sqv = fmaf(v, v, sqv);
      }
    }
    sumv += __shfl_xor(sumv, 16); sumv += __shfl_xor(sumv, 32);
    sqv  += __shfl_xor(sqv, 16);  sqv  += __shfl_xor(sqv, 32);
    if (lg == 0) {
      atomicAdd(&ssum[colL], sumv);
      atomicAdd(&ssq[colL], sqv);
    }
  }
  __syncthreads();
  if (tid < 256) {
    int bkt = (bid & 63) * 1024;
    atomicAdd(&s3buck[bkt + n0 + tid], ssum[tid]);
    atomicAdd(&s3buck[bkt + 512 + n0 + tid], ssq[tid]);
  }
}

__global__ void bn_prep3(const float* __restrict__ g3, const float* __restrict__ be3,
                         const float* __restrict__ s3buck, float* __restrict__ misc) {
  int c = threadIdx.x;  // 512
  float s = 0.f, q = 0.f;
  for (int b = 0; b < 64; ++b) { s += s3buck[b*1024 + c]; q += s3buck[b*1024 + 512 + c]; }
  const float inv = 1.0f / (float)NSAMP;
  float mu = s * inv;
  float var = q * inv - mu * mu;
  float a = g3[c] / sqrtf(var + 1e-5f);
  misc[256 + c] = a;
  misc[768 + c] = be3[c] - mu * a;
}

// ============================================================
// K7: MFMA GEMM: h4 = relu(a3*h3+d3) @ W4 (+b4), fused max-pool over K=20.
// 512 thr / 8 waves; Bs XOR swizzle; As stride-40 pad; A reg-prefetch +
// dequant; B global_load_lds. Pool aliases staging LDS.
// ============================================================
__global__ __launch_bounds__(512) void gemm4_kernel(const unsigned short* __restrict__ h3,
                                                    const unsigned short* __restrict__ W4T,
                                                    const float* __restrict__ b4,
                                                    const float* __restrict__ misc,
                                                    float* __restrict__ outf) {
  int bm = blockIdx.x;              // 2048 blocks: 4 points each
  int m0 = bm * 80;
  int tid = threadIdx.x;
  int lane = tid & 63, w = tid >> 6;     // w = column wave 0..7
  int lr = lane & 15, lg = lane >> 4;
  __shared__ __align__(16) char smem[35072];
  unsigned short (*As)[40] = (unsigned short (*)[40])smem;            // 80*80  = 6400 B (padded)
  unsigned short (*Bs)[32] = (unsigned short (*)[32])(smem + 6400);   // 384*64 = 24576 B
  float (*pool)[392] = (float (*)[392])smem;                          // 31360 B (alias)
  float* af = (float*)(smem + 30976);                                 // 512 f32
  float* df = af + 512;                                               // 512 f32  -> ends 35072
  if (tid < 512) {
    af[tid] = misc[256 + tid];
    df[tid] = misc[768 + tid];
  }
  __syncthreads();
  f32x4 acc[5][3] = {};

  // A prefetch: 320 uint4 over 512 threads (tid < 320)
  uint4 aR;
  int arow = tid >> 2, akg = tid & 3;
  if (tid < 320)
    aR = *(const uint4*)(h3 + (size_t)(m0 + arow)*512 + (akg << 3));
  int swz4 = (lr >> 1) & 3;

  for (int kc = 0; kc < 512; kc += 32) {
    // --- stage B: async global->LDS with XOR swizzle, 3 rounds ---
#pragma unroll
    for (int l = 0; l < 3; ++l) {
      int id = tid + (l << 9);
      int row = id >> 2, kgs = id & 3;
      int kg = kgs ^ ((row >> 1) & 3);
      gl_lds16(W4T + (size_t)row*512 + kc + (kg << 3), &Bs[row][kgs << 3]);
    }
    // --- stage A: dequant BN3 affine + relu, repack bf16 ---
    if (tid < 320) {
      int kb = kc + (akg << 3);
      unsigned int o[4];
#pragma unroll
      for (int q = 0; q < 4; ++q) {
        unsigned int u = ((const unsigned int*)&aR)[q];
        float lo = bf2f((unsigned short)(u & 0xffffu));
        float hi = bf2f((unsigned short)(u >> 16));
        int k0 = kb + q*2;
        lo = fmaxf(fmaf(af[k0],   lo, df[k0]),   0.f);
        hi = fmaxf(fmaf(af[k0+1], hi, df[k0+1]), 0.f);
        o[q] = (unsigned int)f2bf(lo) | ((unsigned int)f2bf(hi) << 16);
      }
      *(uint4*)&As[arow][akg << 3] = *(const uint4*)o;
    }
    __syncthreads();
    // --- prefetch next A ---
    int kn = kc + 32;
    if (kn < 512 && tid < 320)
      aR = *(const uint4*)(h3 + (size_t)(m0 + arow)*512 + kn + (akg << 3));
    // --- fragments + MFMA ---
    bf16x8 a[5], b[3];
#pragma unroll
    for (int t = 0; t < 5; ++t)
      a[t] = *(const bf16x8*)&As[t*16 + lr][lg << 3];
#pragma unroll
    for (int t = 0; t < 3; ++t)
      b[t] = *(const bf16x8*)&Bs[w*48 + t*16 + lr][(lg ^ swz4) << 3];
#pragma unroll
    for (int i = 0; i < 5; ++i)
#pragma unroll
      for (int j = 0; j < 3; ++j)
        acc[i][j] = __builtin_amdgcn_mfma_f32_16x16x32_bf16(a[i], b[j], acc[i][j], 0, 0, 0);
    __syncthreads();
  }

  // fused max-pool: per-lane reg-max (4 rows, point-pure since 4|20)
#pragma unroll
  for (int i = 0; i < 5; ++i)
#pragma unroll
    for (int j = 0; j < 3; ++j) {
      float m = fmaxf(fmaxf(acc[i][j][0], acc[i][j][1]),
                      fmaxf(acc[i][j][2], acc[i][j][3]));
      pool[i*4 + lg][w*48 + j*16 + lr] = m;
    }
  __syncthreads();
#pragma unroll
  for (int l = 0; l < 3; ++l) {
    int id = tid + (l << 9);            // 0..1535 : 4 points x 384 cols
    int q = id / 384, c = id - q*384;
    float v = pool[q*5][c];
#pragma unroll
    for (int u = 1; u < 5; ++u) v = fmaxf(v, pool[q*5 + u][c]);
    outf[(size_t)(bm*4 + q)*384 + c] = v + b4[c];
  }
}

// ============================================================
// Workspace layout:
//   0x0000000  idx        640 KB
//   0x00A0000  misc       1280 f32
//   0x00A2000  mbuck      16*64 f32 = 4 KB (zeroed)
//   0x00AA000  s3buck     256 KB  (zeroed)
//   0x00F0000  W3T bf16   512 KB
//   0x0170000  W4T bf16   384 KB
//   0x01D0000  W2T bf16   64 KB
//   0x0200000  gmax bf16  4 MB
//   0x0600000  h2   bf16  80 MB
//   0x5600000  h3   bf16  160 MB  -> end 0xF600000
// ============================================================
extern "C" void kernel_launch(void* const* d_in, const int* in_sizes, int n_in,
                              void* d_out, int out_size, void* d_ws, size_t ws_size,
                              hipStream_t stream) {
  const float* xyz = (const float*)d_in[0];
  const float* W1  = (const float*)d_in[1];
  const float* b1  = (const float*)d_in[2];
  const float* g1  = (const float*)d_in[3];
  const float* be1 = (const float*)d_in[4];
  const float* W2  = (const float*)d_in[5];
  const float* b2  = (const float*)d_in[6];
  const float* W3  = (const float*)d_in[7];
  const float* b3  = (const float*)d_in[8];
  const float* g3  = (const float*)d_in[9];
  const float* be3 = (const float*)d_in[10];
  const float* W4  = (const float*)d_in[11];
  const float* b4  = (const float*)d_in[12];

  char* ws = (char*)d_ws;
  int*            idx    = (int*)ws;
  float*          misc   = (float*)(ws + 0xA0000);
  float*          mbuck  = (float*)(ws + 0xA2000);
  float*          s3buck = (float*)(ws + 0xAA000);
  unsigned short* W3T    = (unsigned short*)(ws + 0xF0000);
  unsigned short* W4T    = (unsigned short*)(ws + 0x170000);
  unsigned short* W2T    = (unsigned short*)(ws + 0x1D0000);
  unsigned short* gmax   = (unsigned short*)(ws + 0x200000);
  unsigned short* h2     = (unsigned short*)(ws + 0x600000);
  unsigned short* h3     = (unsigned short*)(ws + 0x5600000ULL);

  float* ofp   = (float*)d_out;
  float* oxyz  = ofp;             // 24576 fp32
  float* ofeat = ofp + 24576;     // 8192*384 fp32

  hipMemsetAsync(ws + 0xA2000, 0, 0x48000, stream);   // zero mbuck + s3buck

  wprep_kernel<<<(512*512 + 384*512 + 256*128)/256, 256, 0, stream>>>(W3, W4, W2, W3T, W4T, W2T);
  knn_kernel<<<NPTS, 256, 0, stream>>>(xyz, idx, oxyz);
  h1_moments_kernel<<<NSAMP/512, 256, 0, stream>>>(xyz, idx, mbuck);
  bn_prep1<<<1, 128, 0, stream>>>(W1, b1, g1, be1, mbuck, misc);
  h2_kernel<<<NPTS/4, 256, 0, stream>>>(xyz, idx, W1, b1, W2T, b2, misc, h2, gmax);
  gemm3_kernel<<<(NSAMP/128)*2, 512, 0, stream>>>(h2, gmax, W3T, b3, h3, s3buck);
  bn_prep3<<<1, 512, 0, stream>>>(g3, be3, s3buck, misc);
  gemm4_kernel<<<NPTS/4, 512, 0, stream>>>(h3, W4T, b4, misc, ofeat);
}

// Round 15
// 414.690 us; speedup vs baseline: 1.9045x; 1.0098x over previous
//
#include <hip/hip_runtime.h>
#include <float.h>

// Problem constants: B=2, N=4096, K=20, H=384
// Inputs: fp32 arrays (values bf16-quantized by harness). Output: fp32.
#define NPTS_B 4096
#define NPTS 8192            // B*N
#define KNN 20
#define NSAMP (NPTS*KNN)     // 163840

typedef __attribute__((ext_vector_type(8))) short bf16x8;
typedef __attribute__((ext_vector_type(4))) float f32x4;

// -------- bf16 helpers (internal staging only) --------
static __device__ __forceinline__ float bf2f(unsigned short u) {
  return __uint_as_float(((unsigned int)u) << 16);
}
static __device__ __forceinline__ unsigned short f2bf(float f) {
  unsigned int u = __float_as_uint(f);
  u += 0x7fffu + ((u >> 16) & 1u);
  return (unsigned short)(u >> 16);
}
static __device__ __forceinline__ unsigned long long u64min(unsigned long long a,
                                                           unsigned long long b) {
  return a < b ? a : b;
}
static __device__ __forceinline__ unsigned long long shflx64(unsigned long long v, int m) {
  int lo = __shfl_xor((int)(unsigned int)(v & 0xffffffffull), m);
  int hi = __shfl_xor((int)(unsigned int)(v >> 32), m);
  return ((unsigned long long)(unsigned int)hi << 32) | (unsigned int)lo;
}
// async global->LDS 16B: wave-uniform LDS base + lane*16.
static __device__ __forceinline__ void gl_lds16(const void* g, void* l) {
  __builtin_amdgcn_global_load_lds(
      (const __attribute__((address_space(1))) unsigned int*)g,
      (__attribute__((address_space(3))) unsigned int*)l, 16, 0, 0);
}

// ============================================================
// K0: weight prep — W3 -> W3T bf16 [n][k]; W4 -> W4T bf16 [n][k];
// W2 (128x256) -> W2T bf16 [n=256][k=128]. All values bf16-grid -> EXACT.
// ============================================================
__global__ __launch_bounds__(256) void wprep_kernel(const float* __restrict__ W3,
                                                    const float* __restrict__ W4,
                                                    const float* __restrict__ W2,
                                                    unsigned short* __restrict__ W3T,
                                                    unsigned short* __restrict__ W4T,
                                                    unsigned short* __restrict__ W2T) {
  int id = blockIdx.x * 256 + threadIdx.x;
  if (id < 512*512) {
    int n = id >> 9, k = id & 511;
    W3T[id] = f2bf(W3[k*512 + n]);
  } else if (id < 512*512 + 384*512) {
    int id2 = id - 512*512;
    int n = id2 >> 9, k = id2 & 511;
    W4T[id2] = f2bf(W4[k*384 + n]);
  } else {
    int id2 = id - (512*512 + 384*512);   // < 256*128
    int n = id2 >> 7, k = id2 & 127;
    W2T[id2] = f2bf(W2[k*256 + n]);
  }
}

// ============================================================
// K1: KNN (one block per point). u64-packed (d2_bits<<32|j) extract-min,
// incremental cached minima, one barrier per round.
// ============================================================
__global__ __launch_bounds__(256) void knn_kernel(const float* __restrict__ xyz,
                                                  int* __restrict__ idx,
                                                  float* __restrict__ out_xyz) {
#pragma clang fp contract(off)
  int p = blockIdx.x;            // 0..8191
  int base = p & ~4095;          // batch base row
  int tid = threadIdx.x;
  int wv = tid >> 6;
  int ln = tid & 63;
  const float* xb = xyz + (size_t)base * 3;
  float xi0 = xyz[p*3+0], xi1 = xyz[p*3+1], xi2 = xyz[p*3+2];
  float sqi = (xi0*xi0 + xi1*xi1) + xi2*xi2;

  unsigned long long cand[16];
#pragma unroll
  for (int u = 0; u < 16; ++u) {
    int j = tid + (u << 8);
    float a0 = xb[j*3+0], a1 = xb[j*3+1], a2 = xb[j*3+2];
    float sqj = (a0*a0 + a1*a1) + a2*a2;
    float dt  = (xi0*a0 + xi1*a1) + xi2*a2;
    float d2  = (sqi + sqj) - 2.0f*dt;
    cand[u] = ((unsigned long long)__float_as_uint(d2) << 32) | (unsigned int)j;
  }
  unsigned long long myloc;
  {
    unsigned long long t[8];
#pragma unroll
    for (int u = 0; u < 8; ++u) t[u] = u64min(cand[u], cand[u + 8]);
#pragma unroll
    for (int u = 0; u < 4; ++u) t[u] = u64min(t[u], t[u + 4]);
    t[0] = u64min(t[0], t[2]); t[1] = u64min(t[1], t[3]);
    myloc = u64min(t[0], t[1]);
  }
  unsigned long long wmreg = myloc;
#pragma unroll
  for (int off = 1; off < 64; off <<= 1) wmreg = u64min(wmreg, shflx64(wmreg, off));

  __shared__ __align__(16) unsigned long long wbuf[2][4];
  __shared__ int outbuf[20];
  if (ln == 0) wbuf[0][wv] = wmreg;
  __syncthreads();

  for (int r = 0; r < 20; ++r) {
    int cur = r & 1;
    unsigned long long w0 = wbuf[cur][0], w1 = wbuf[cur][1];
    unsigned long long w2 = wbuf[cur][2], w3 = wbuf[cur][3];
    unsigned long long g = u64min(u64min(w0, w1), u64min(w2, w3));
    int wj = (int)(unsigned int)(g & 0xffffffffu);
    if (tid == (wj & 255)) {
      outbuf[r] = base + wj;
      unsigned long long m = ~0ull;
#pragma unroll
      for (int u = 0; u < 16; ++u) {
        if (cand[u] == g) cand[u] = ~0ull;
        m = u64min(m, cand[u]);
      }
      myloc = m;
    }
    if (wv == ((wj >> 6) & 3)) {
      unsigned long long t = myloc;
#pragma unroll
      for (int off = 1; off < 64; off <<= 1) t = u64min(t, shflx64(t, off));
      wmreg = t;
    }
    if (ln == 0) wbuf[cur ^ 1][wv] = wmreg;
    __syncthreads();
  }
  if (tid < 20) idx[p*20 + tid] = outbuf[tid];
  if (tid < 3) out_xyz[p*3 + tid] = xyz[p*3 + tid];   // exact fp32 copy
}

// ============================================================
// K2: BN1 stats via 6-dim edge moments (affine trick).
// ============================================================
__global__ __launch_bounds__(256) void h1_moments_kernel(const float* __restrict__ xyz,
                                                         const int* __restrict__ idx,
                                                         float* __restrict__ mbuck) {
  int tid = threadIdx.x, blk = blockIdx.x;   // 320 blocks x 512 samples
  float A[33] = {};
#pragma unroll
  for (int u = 0; u < 2; ++u) {
    int s = blk*512 + (u << 8) + tid;
    unsigned int p = (unsigned int)s / 20u;
    int jg = idx[s];
    float c0 = xyz[p*3+0], c1 = xyz[p*3+1], c2 = xyz[p*3+2];
    float e[6];
    e[0] = xyz[jg*3+0] - c0; e[1] = xyz[jg*3+1] - c1; e[2] = xyz[jg*3+2] - c2;
    e[3] = c0; e[4] = c1; e[5] = c2;
    int k = 6;
#pragma unroll
    for (int d = 0; d < 6; ++d) {
      A[d] += e[d];
#pragma unroll
      for (int d2 = d; d2 < 6; ++d2) { A[k] = fmaf(e[d], e[d2], A[k]); ++k; }
    }
  }
#pragma unroll
  for (int off = 1; off < 64; off <<= 1) {
#pragma unroll
    for (int i = 0; i < 33; ++i) A[i] += __shfl_xor(A[i], off);
  }
  if ((tid & 63) == 0) {
    int b = ((blk << 2) | (tid >> 6)) & 15;
    for (int i = 0; i < 33; ++i) atomicAdd(&mbuck[b*64 + i], A[i]);
  }
}

__global__ void bn_prep1(const float* __restrict__ W1, const float* __restrict__ b1,
                         const float* __restrict__ g1, const float* __restrict__ be1,
                         const float* __restrict__ mbuck, float* __restrict__ misc) {
  __shared__ float red[33];
  int tid = threadIdx.x;  // 128
  if (tid < 33) {
    float s = 0.f;
    for (int b = 0; b < 16; ++b) s += mbuck[b*64 + tid];
    red[tid] = s;
  }
  __syncthreads();
  int c = tid;
  float w[6];
#pragma unroll
  for (int d = 0; d < 6; ++d) w[d] = W1[d*128 + c];
  const float inv = 1.0f / (float)NSAMP;
  float t = 0.f;
#pragma unroll
  for (int d = 0; d < 6; ++d) t = fmaf(w[d], red[d], t);
  t *= inv;
  float Q = 0.f;
  int k = 6;
#pragma unroll
  for (int d = 0; d < 6; ++d) {
#pragma unroll
    for (int d2 = d; d2 < 6; ++d2) {
      float coef = (d == d2) ? w[d]*w[d] : 2.f*w[d]*w[d2];
      Q = fmaf(coef, red[k], Q); ++k;
    }
  }
  Q *= inv;
  float var = Q - t*t;
  float mu = b1[c] + t;
  float a = g1[c] / sqrtf(var + 1e-5f);
  misc[c] = a;
  misc[128 + c] = be1[c] - mu*a;
}

// ============================================================
// K4: MFMA h2: per block of 4 points (M=80): edge -> h1 (BN1+ReLU, bf16
// into LDS A-tile) -> h2 = h1 @ W2T via MFMA (N=256, K=128) -> +b2 ->
// h2 bf16 store + fused per-point gmax.
// ============================================================
__global__ __launch_bounds__(256) void h2_kernel(const float* __restrict__ xyz,
                                                 const int* __restrict__ idx,
                                                 const float* __restrict__ W1,
                                                 const float* __restrict__ b1,
                                                 const unsigned short* __restrict__ W2T,
                                                 const float* __restrict__ b2,
                                                 const float* __restrict__ misc,
                                                 unsigned short* __restrict__ h2out,
                                                 unsigned short* __restrict__ gmaxout) {
  int p0 = blockIdx.x << 2;          // 4 points
  int tid = threadIdx.x;
  int w = tid >> 6, lane = tid & 63;
  int lr = lane & 15, lg = lane >> 4;
  __shared__ float e[80][6];
  __shared__ __align__(16) unsigned short As[80][136];
  __shared__ float pool[20][264];

  bf16x8 bfr[4][4];
#pragma unroll
  for (int j = 0; j < 4; ++j)
#pragma unroll
    for (int kk = 0; kk < 4; ++kk)
      bfr[j][kk] = *(const bf16x8*)(W2T + (size_t)(w*64 + j*16 + lr)*128 + kk*32 + lg*8);

  if (tid < 80) {
    int pl = (unsigned int)tid / 20u;
    int p = p0 + pl;
    int jg = idx[p0*20 + tid];
    float xi0 = xyz[p*3+0], xi1 = xyz[p*3+1], xi2 = xyz[p*3+2];
    e[tid][0] = xyz[jg*3+0] - xi0;
    e[tid][1] = xyz[jg*3+1] - xi1;
    e[tid][2] = xyz[jg*3+2] - xi2;
    e[tid][3] = xi0; e[tid][4] = xi1; e[tid][5] = xi2;
  }
  __syncthreads();

  {
    int c = tid & 127, half = tid >> 7;
    float w1v[6];
#pragma unroll
    for (int d = 0; d < 6; ++d) w1v[d] = W1[d*128 + c];
    float b1v = b1[c], a1 = misc[c], d1 = misc[128 + c];
#pragma unroll
    for (int u = 0; u < 40; ++u) {
      int row = (u << 1) | half;
      float v = b1v;
#pragma unroll
      for (int d = 0; d < 6; ++d) v = fmaf(e[row][d], w1v[d], v);
      v = fmaxf(fmaf(a1, v, d1), 0.f);
      As[row][c] = f2bf(v);
    }
  }
  __syncthreads();

  f32x4 acc[5][4] = {};
#pragma unroll
  for (int kk = 0; kk < 4; ++kk) {
    bf16x8 a[5];
#pragma unroll
    for (int i = 0; i < 5; ++i)
      a[i] = *(const bf16x8*)&As[i*16 + lr][kk*32 + lg*8];
#pragma unroll
    for (int i = 0; i < 5; ++i)
#pragma unroll
      for (int j = 0; j < 4; ++j)
        acc[i][j] = __builtin_amdgcn_mfma_f32_16x16x32_bf16(a[i], bfr[j][kk], acc[i][j], 0, 0, 0);
  }

  float b2v[4];
#pragma unroll
  for (int j = 0; j < 4; ++j) b2v[j] = b2[w*64 + j*16 + lr];
#pragma unroll
  for (int i = 0; i < 5; ++i) {
    int rbase = p0*20 + i*16 + lg*4;
#pragma unroll
    for (int j = 0; j < 4; ++j) {
      int col = w*64 + j*16 + lr;
      float v0 = acc[i][j][0] + b2v[j];
      float v1 = acc[i][j][1] + b2v[j];
      float v2 = acc[i][j][2] + b2v[j];
      float v3 = acc[i][j][3] + b2v[j];
      h2out[(size_t)(rbase+0)*256 + col] = f2bf(v0);
      h2out[(size_t)(rbase+1)*256 + col] = f2bf(v1);
      h2out[(size_t)(rbase+2)*256 + col] = f2bf(v2);
      h2out[(size_t)(rbase+3)*256 + col] = f2bf(v3);
      pool[i*4 + lg][col] = fmaxf(fmaxf(v0, v1), fmaxf(v2, v3));
    }
  }
  __syncthreads();
#pragma unroll
  for (int l = 0; l < 4; ++l) {
    int id = tid + (l << 8);        // 0..1023 : 4 points x 256 cols
    int q = id >> 8, col = id & 255;
    float v = pool[q*5][col];
#pragma unroll
    for (int u = 1; u < 5; ++u) v = fmaxf(v, pool[q*5 + u][col]);
    gmaxout[(size_t)(p0 + q)*256 + col] = f2bf(v);
  }
}

// ============================================================
// K5: MFMA GEMM: h3 = [gmax | h2] @ W3 + b3 (163840x512x512), bf16 MFMA.
// R14: 512 thr / 8 waves, N=256/block, XCD pairing, factored gmax P-phase,
// BK=64 XOR swizzle. R15: COALESCED h3 store — R14 PMC showed WRITE_SIZE
// 269 MB vs 160 MB data (partial-line scalar ushort stores -> L2 RMW).
// Epilogue now routes acc through Cs LDS (aliases dead As/Bs, stride-264
// pad -> fragment scatter conflict-free), then 512 threads write full
// 64 B lines (uint4).
// ============================================================
__global__ __launch_bounds__(512) void gemm3_kernel(const unsigned short* __restrict__ h2,
                                                    const unsigned short* __restrict__ gmax,
                                                    const unsigned short* __restrict__ W3T,
                                                    const float* __restrict__ b3,
                                                    unsigned short* __restrict__ h3,
                                                    float* __restrict__ s3buck) {
  int bid = blockIdx.x;               // 2560 = 160 grp * (2 bn * 8 x)
  int grp = bid >> 4, rem = bid & 15;
  int bn = rem >> 3;                  // 0..1
  int bm = (grp << 3) | (rem & 7);    // 0..1279
  int m0 = bm << 7, n0 = bn << 8;
  unsigned int pbase = (unsigned int)m0 / 20u;
  int tid = threadIdx.x;
  int lane = tid & 63, w = tid >> 6;  // 8 waves
  int mw = w >> 2, nw = w & 3;        // 2m x 4n
  int lr = lane & 15, lg = lane >> 4;
  __shared__ __align__(16) char smem[59520];
  unsigned short (*As)[64] = (unsigned short (*)[64])smem;              // 16384 B
  unsigned short (*Bs)[64] = (unsigned short (*)[64])(smem + 16384);    // 32768 B
  float (*Plds)[260] = (float (*)[260])(smem + 49152);                  // 8320 B
  float* ssum = (float*)(smem + 49152 + 8320);                          // 1024 B
  float* ssq  = ssum + 256;                                             // 1024 B
  unsigned short (*Cs)[264] = (unsigned short (*)[264])smem;            // 33792 B (aliases As+Bs)

  // staging coords: id = tid + l*512; row=id>>3, kgs=id&7,
  // source kg = kgs ^ ((row>>1)&7) = kgs ^ ((id>>4)&7)
  int rS[4], kgS[4], ksS[4];
#pragma unroll
  for (int l = 0; l < 4; ++l) {
    int id = tid + (l << 9);
    rS[l] = id >> 3;
    ksS[l] = id & 7;
    kgS[l] = ksS[l] ^ ((id >> 4) & 7);
  }
  int swz = lr >> 1;

  // ---- Phase 1: P = gmax(16 rows, 8 valid) @ W3a, cols n0..n0+255 ----
  f32x4 accP[4] = {};
  int par = tid >> 3, paks = tid & 7;           // tid<128: 16 rows x 8 chunks
  int pakg = paks ^ ((tid >> 4) & 7);
  for (int kc = 0; kc < 256; kc += 64) {
    if (tid < 128)
      gl_lds16(gmax + (size_t)(pbase + par)*256 + kc + (pakg << 3), &As[par][paks << 3]);
#pragma unroll
    for (int l = 0; l < 4; ++l)
      gl_lds16(W3T + (size_t)(n0 + rS[l])*512 + kc + (kgS[l] << 3), &Bs[rS[l]][ksS[l] << 3]);
    __syncthreads();
#pragma unroll
    for (int h = 0; h < 2; ++h) {
      int ch = ((h << 2) | lg) ^ swz;
      bf16x8 a = *(const bf16x8*)&As[lr][ch << 3];
#pragma unroll
      for (int j = 0; j < 4; ++j) {
        bf16x8 b = *(const bf16x8*)&Bs[nw*64 + j*16 + lr][ch << 3];
        accP[j] = __builtin_amdgcn_mfma_f32_16x16x32_bf16(a, b, accP[j], 0, 0, 0);
      }
    }
    __syncthreads();
  }
  if (mw == 0 && lg < 2) {                       // rows 0..7 valid
#pragma unroll
    for (int j = 0; j < 4; ++j)
#pragma unroll
      for (int r = 0; r < 4; ++r)
        Plds[lg*4 + r][nw*64 + j*16 + lr] = accP[j][r];
  }

  // ---- Phase 2: h3-partial = h2 @ W3b (K = 256..511) ----
  f32x4 acc[4][4] = {};
  for (int kc = 0; kc < 256; kc += 64) {
#pragma unroll
    for (int l = 0; l < 2; ++l)
      gl_lds16(h2 + (size_t)(m0 + rS[l])*256 + kc + (kgS[l] << 3), &As[rS[l]][ksS[l] << 3]);
#pragma unroll
    for (int l = 0; l < 4; ++l)
      gl_lds16(W3T + (size_t)(n0 + rS[l])*512 + (kc + 256) + (kgS[l] << 3), &Bs[rS[l]][ksS[l] << 3]);
    __syncthreads();
#pragma unroll
    for (int h = 0; h < 2; ++h) {
      int ch = ((h << 2) | lg) ^ swz;
      bf16x8 a[4], b[4];
#pragma unroll
      for (int t = 0; t < 4; ++t)
        a[t] = *(const bf16x8*)&As[mw*64 + t*16 + lr][ch << 3];
#pragma unroll
      for (int t = 0; t < 4; ++t)
        b[t] = *(const bf16x8*)&Bs[nw*64 + t*16 + lr][ch << 3];
#pragma unroll
      for (int i = 0; i < 4; ++i)
#pragma unroll
        for (int j = 0; j < 4; ++j)
          acc[i][j] = __builtin_amdgcn_mfma_f32_16x16x32_bf16(a[i], b[j], acc[i][j], 0, 0, 0);
    }
    __syncthreads();
  }

  // ---- Epilogue: v = acc + b3 + P; stats; COALESCED store via Cs ----
  if (tid < 256) { ssum[tid] = 0.f; ssq[tid] = 0.f; }
  __syncthreads();
  unsigned int prow[4][4];
#pragma unroll
  for (int i = 0; i < 4; ++i) {
    int rbase = m0 + mw*64 + i*16 + lg*4;
#pragma unroll
    for (int r = 0; r < 4; ++r)
      prow[i][r] = (unsigned int)(rbase + r) / 20u - pbase;
  }
#pragma unroll
  for (int half = 0; half < 2; ++half) {
    if (mw == half) {
#pragma unroll
      for (int j = 0; j < 4; ++j) {
        int colL = nw*64 + j*16 + lr;
        float b3v = b3[n0 + colL];
        float sumv = 0.f, sqv = 0.f;
#pragma unroll
        for (int i = 0; i < 4; ++i) {
#pragma unroll
          for (int r = 0; r < 4; ++r) {
            float v = acc[i][j][r] + b3v + Plds[prow[i][r]][colL];
            Cs[i*16 + lg*4 + r][colL] = f2bf(v);
            sumv += v; sqv = fmaf(v, v, sqv);
          }
        }
        sumv += __shfl_xor(sumv, 16); sumv += __shfl_xor(sumv, 32);
        sqv  += __shfl_xor(sqv, 16);  sqv  += __shfl_xor(sqv, 32);
        if (lg == 0) {
          atomicAdd(&ssum[colL], sumv);
          atomicAdd(&ssq[colL], sqv);
        }
      }
    }
    __syncthreads();
    // all 512 threads: 64 rows x 512 B, full-line uint4 stores
#pragma unroll
    for (int l = 0; l < 4; ++l) {
      int id = tid + (l << 9);          // 0..2047 : row = id>>5, chunk = id&31
      int row = id >> 5, ch = id & 31;
      *(uint4*)(h3 + (size_t)(m0 + half*64 + row)*512 + n0 + (ch << 3)) =
          *(const uint4*)&Cs[row][ch << 3];
    }
    __syncthreads();
  }
  if (tid < 256) {
    int bkt = (bid & 63) * 1024;
    atomicAdd(&s3buck[bkt + n0 + tid], ssum[tid]);
    atomicAdd(&s3buck[bkt + 512 + n0 + tid], ssq[tid]);
  }
}

__global__ void bn_prep3(const float* __restrict__ g3, const float* __restrict__ be3,
                         const float* __restrict__ s3buck, float* __restrict__ misc) {
  int c = threadIdx.x;  // 512
  float s = 0.f, q = 0.f;
  for (int b = 0; b < 64; ++b) { s += s3buck[b*1024 + c]; q += s3buck[b*1024 + 512 + c]; }
  const float inv = 1.0f / (float)NSAMP;
  float mu = s * inv;
  float var = q * inv - mu * mu;
  float a = g3[c] / sqrtf(var + 1e-5f);
  misc[256 + c] = a;
  misc[768 + c] = be3[c] - mu * a;
}

// ============================================================
// K7: MFMA GEMM: h4 = relu(a3*h3+d3) @ W4 (+b4), fused max-pool over K=20.
// 512 thr / 8 waves; Bs XOR swizzle; As stride-40 pad; A reg-prefetch +
// dequant; B global_load_lds. Pool aliases staging LDS.
// ============================================================
__global__ __launch_bounds__(512) void gemm4_kernel(const unsigned short* __restrict__ h3,
                                                    const unsigned short* __restrict__ W4T,
                                                    const float* __restrict__ b4,
                                                    const float* __restrict__ misc,
                                                    float* __restrict__ outf) {
  int bm = blockIdx.x;              // 2048 blocks: 4 points each
  int m0 = bm * 80;
  int tid = threadIdx.x;
  int lane = tid & 63, w = tid >> 6;     // w = column wave 0..7
  int lr = lane & 15, lg = lane >> 4;
  __shared__ __align__(16) char smem[35072];
  unsigned short (*As)[40] = (unsigned short (*)[40])smem;            // 80*80  = 6400 B (padded)
  unsigned short (*Bs)[32] = (unsigned short (*)[32])(smem + 6400);   // 384*64 = 24576 B
  float (*pool)[392] = (float (*)[392])smem;                          // 31360 B (alias)
  float* af = (float*)(smem + 30976);                                 // 512 f32
  float* df = af + 512;                                               // 512 f32  -> ends 35072
  if (tid < 512) {
    af[tid] = misc[256 + tid];
    df[tid] = misc[768 + tid];
  }
  __syncthreads();
  f32x4 acc[5][3] = {};

  // A prefetch: 320 uint4 over 512 threads (tid < 320)
  uint4 aR;
  int arow = tid >> 2, akg = tid & 3;
  if (tid < 320)
    aR = *(const uint4*)(h3 + (size_t)(m0 + arow)*512 + (akg << 3));
  int swz4 = (lr >> 1) & 3;

  for (int kc = 0; kc < 512; kc += 32) {
    // --- stage B: async global->LDS with XOR swizzle, 3 rounds ---
#pragma unroll
    for (int l = 0; l < 3; ++l) {
      int id = tid + (l << 9);
      int row = id >> 2, kgs = id & 3;
      int kg = kgs ^ ((row >> 1) & 3);
      gl_lds16(W4T + (size_t)row*512 + kc + (kg << 3), &Bs[row][kgs << 3]);
    }
    // --- stage A: dequant BN3 affine + relu, repack bf16 ---
    if (tid < 320) {
      int kb = kc + (akg << 3);
      unsigned int o[4];
#pragma unroll
      for (int q = 0; q < 4; ++q) {
        unsigned int u = ((const unsigned int*)&aR)[q];
        float lo = bf2f((unsigned short)(u & 0xffffu));
        float hi = bf2f((unsigned short)(u >> 16));
        int k0 = kb + q*2;
        lo = fmaxf(fmaf(af[k0],   lo, df[k0]),   0.f);
        hi = fmaxf(fmaf(af[k0+1], hi, df[k0+1]), 0.f);
        o[q] = (unsigned int)f2bf(lo) | ((unsigned int)f2bf(hi) << 16);
      }
      *(uint4*)&As[arow][akg << 3] = *(const uint4*)o;
    }
    __syncthreads();
    // --- prefetch next A ---
    int kn = kc + 32;
    if (kn < 512 && tid < 320)
      aR = *(const uint4*)(h3 + (size_t)(m0 + arow)*512 + kn + (akg << 3));
    // --- fragments + MFMA ---
    bf16x8 a[5], b[3];
#pragma unroll
    for (int t = 0; t < 5; ++t)
      a[t] = *(const bf16x8*)&As[t*16 + lr][lg << 3];
#pragma unroll
    for (int t = 0; t < 3; ++t)
      b[t] = *(const bf16x8*)&Bs[w*48 + t*16 + lr][(lg ^ swz4) << 3];
#pragma unroll
    for (int i = 0; i < 5; ++i)
#pragma unroll
      for (int j = 0; j < 3; ++j)
        acc[i][j] = __builtin_amdgcn_mfma_f32_16x16x32_bf16(a[i], b[j], acc[i][j], 0, 0, 0);
    __syncthreads();
  }

  // fused max-pool: per-lane reg-max (4 rows, point-pure since 4|20)
#pragma unroll
  for (int i = 0; i < 5; ++i)
#pragma unroll
    for (int j = 0; j < 3; ++j) {
      float m = fmaxf(fmaxf(acc[i][j][0], acc[i][j][1]),
                      fmaxf(acc[i][j][2], acc[i][j][3]));
      pool[i*4 + lg][w*48 + j*16 + lr] = m;
    }
  __syncthreads();
#pragma unroll
  for (int l = 0; l < 3; ++l) {
    int id = tid + (l << 9);            // 0..1535 : 4 points x 384 cols
    int q = id / 384, c = id - q*384;
    float v = pool[q*5][c];
#pragma unroll
    for (int u = 1; u < 5; ++u) v = fmaxf(v, pool[q*5 + u][c]);
    outf[(size_t)(bm*4 + q)*384 + c] = v + b4[c];
  }
}

// ============================================================
// Workspace layout:
//   0x0000000  idx        640 KB
//   0x00A0000  misc       1280 f32
//   0x00A2000  mbuck      16*64 f32 = 4 KB (zeroed)
//   0x00AA000  s3buck     256 KB  (zeroed)
//   0x00F0000  W3T bf16   512 KB
//   0x0170000  W4T bf16   384 KB
//   0x01D0000  W2T bf16   64 KB
//   0x0200000  gmax bf16  4 MB
//   0x0600000  h2   bf16  80 MB
//   0x5600000  h3   bf16  160 MB  -> end 0xF600000
// ============================================================
extern "C" void kernel_launch(void* const* d_in, const int* in_sizes, int n_in,
                              void* d_out, int out_size, void* d_ws, size_t ws_size,
                              hipStream_t stream) {
  const float* xyz = (const float*)d_in[0];
  const float* W1  = (const float*)d_in[1];
  const float* b1  = (const float*)d_in[2];
  const float* g1  = (const float*)d_in[3];
  const float* be1 = (const float*)d_in[4];
  const float* W2  = (const float*)d_in[5];
  const float* b2  = (const float*)d_in[6];
  const float* W3  = (const float*)d_in[7];
  const float* b3  = (const float*)d_in[8];
  const float* g3  = (const float*)d_in[9];
  const float* be3 = (const float*)d_in[10];
  const float* W4  = (const float*)d_in[11];
  const float* b4  = (const float*)d_in[12];

  char* ws = (char*)d_ws;
  int*            idx    = (int*)ws;
  float*          misc   = (float*)(ws + 0xA0000);
  float*          mbuck  = (float*)(ws + 0xA2000);
  float*          s3buck = (float*)(ws + 0xAA000);
  unsigned short* W3T    = (unsigned short*)(ws + 0xF0000);
  unsigned short* W4T    = (unsigned short*)(ws + 0x170000);
  unsigned short* W2T    = (unsigned short*)(ws + 0x1D0000);
  unsigned short* gmax   = (unsigned short*)(ws + 0x200000);
  unsigned short* h2     = (unsigned short*)(ws + 0x600000);
  unsigned short* h3     = (unsigned short*)(ws + 0x5600000ULL);

  float* ofp   = (float*)d_out;
  float* oxyz  = ofp;             // 24576 fp32
  float* ofeat = ofp + 24576;     // 8192*384 fp32

  hipMemsetAsync(ws + 0xA2000, 0, 0x48000, stream);   // zero mbuck + s3buck

  wprep_kernel<<<(512*512 + 384*512 + 256*128)/256, 256, 0, stream>>>(W3, W4, W2, W3T, W4T, W2T);
  knn_kernel<<<NPTS, 256, 0, stream>>>(xyz, idx, oxyz);
  h1_moments_kernel<<<NSAMP/512, 256, 0, stream>>>(xyz, idx, mbuck);
  bn_prep1<<<1, 128, 0, stream>>>(W1, b1, g1, be1, mbuck, misc);
  h2_kernel<<<NPTS/4, 256, 0, stream>>>(xyz, idx, W1, b1, W2T, b2, misc, h2, gmax);
  gemm3_kernel<<<(NSAMP/128)*2, 512, 0, stream>>>(h2, gmax, W3T, b3, h3, s3buck);
  bn_prep3<<<1, 512, 0, stream>>>(g3, be3, s3buck, misc);
  gemm4_kernel<<<NPTS/4, 512, 0, stream>>>(h3, W4T, b4, misc, ofeat);
}